// Round 6
// baseline (910.313 us; speedup 1.0000x reference)
//
#include <hip/hip_runtime.h>

#define HD   2048
#define FD   1024
#define NEXP 32
#define TOPK 6
#define TT   2048
#define SDIM 2048
#define NPAIR (TT*TOPK)
#define BSTR 40     // fallback-path B-tile LDS row stride (ushorts)
#define TLMAX 128

typedef __bf16 bf16x8 __attribute__((ext_vector_type(8)));
typedef float  f32x4  __attribute__((ext_vector_type(4)));

#define GLOAD_LDS16(g, l) __builtin_amdgcn_global_load_lds( \
    (const __attribute__((address_space(1))) void*)(g),     \
    (__attribute__((address_space(3))) void*)(l), 16, 0, 0)

#define WAIT_VM0  asm volatile("s_waitcnt vmcnt(0)" ::: "memory")

__device__ __forceinline__ ushort f2b(float f) {
  __bf16 h = (__bf16)f;
  union { __bf16 h; ushort u; } v; v.h = h;
  return v.u;
}

__device__ __forceinline__ int prow(int r) {   // fallback path
  return (r & ~3) | ((r + (r >> 2)) & 3);
}

// ---------------- gating (fp32 exact) ----------------
__device__ __forceinline__ void argmax32(float &v, int &i) {
  #pragma unroll
  for (int m = 16; m >= 1; m >>= 1) {
    float ov = __shfl_xor(v, m, 32);
    int   oi = __shfl_xor(i, m, 32);
    if (ov > v || (ov == v && oi < i)) { v = ov; i = oi; }
  }
}

__global__ __launch_bounds__(64) void gating_kernel(
    const float* __restrict__ x, const float* __restrict__ wgate,
    int* __restrict__ topk_idx, float* __restrict__ topk_w, int* __restrict__ cnt)
{
  int t = blockIdx.x;
  int l = threadIdx.x;
  int e = l & 31;
  int half = l >> 5;
  const float* xr = x + (size_t)t * HD + half * (HD/2);
  const float* wr = wgate + (size_t)e * HD + half * (HD/2);
  float acc = 0.f;
  for (int i = 0; i < HD/2; i += 4) {
    float4 a = *(const float4*)(xr + i);
    float4 b = *(const float4*)(wr + i);
    acc += a.x*b.x + a.y*b.y + a.z*b.z + a.w*b.w;
  }
  acc += __shfl_xor(acc, 32);
  float logit = acc;
  float mx = logit;
  #pragma unroll
  for (int m = 16; m >= 1; m >>= 1) mx = fmaxf(mx, __shfl_xor(mx, m, 32));
  float p = __expf(logit - mx);
  float s = p;
  #pragma unroll
  for (int m = 16; m >= 1; m >>= 1) s += __shfl_xor(s, m, 32);
  float score = p / s;
  float gs = score;
  gs = fmaxf(gs, __shfl_xor(gs, 1, 32));
  gs = fmaxf(gs, __shfl_xor(gs, 2, 32));
  int g = e >> 2;
  float gw = gs;
  bool ingroup = false;
  for (int r = 0; r < 3; ++r) {
    float v = gw; int gi = g;
    argmax32(v, gi);
    if (g == gi) { ingroup = true; gw = -1.f; }
  }
  float ms = ingroup ? score : 0.f;
  int myrank = -1;
  float denom = 1e-20f;
  float mw = ms;
  for (int r = 0; r < 6; ++r) {
    float v = mw; int ei = e;
    argmax32(v, ei);
    denom += v;
    if (e == ei) { myrank = r; mw = -1.f; }
  }
  if (l < 32 && myrank >= 0) {
    topk_idx[t*TOPK + myrank] = e;
    topk_w  [t*TOPK + myrank] = score / denom;
    atomicAdd(&cnt[e], 1);
  }
}

__global__ void scan_kernel(const int* __restrict__ cnt, int* __restrict__ offs,
                            int* __restrict__ tl_e, int* __restrict__ tl_m, int* __restrict__ ntl) {
  if (threadIdx.x == 0) {
    int o = 0, nt = 0;
    for (int e = 0; e < NEXP; ++e) {
      offs[e] = o;
      for (int m = 0; m < cnt[e]; m += 128) { tl_e[nt] = e; tl_m[nt] = m; ++nt; }
      o += cnt[e];
    }
    ntl[0] = nt;
  }
}

__global__ void fill_kernel(const int* __restrict__ topk_idx, const float* __restrict__ topk_w,
                            const int* __restrict__ offs, int* __restrict__ cur,
                            int* __restrict__ pair_tok, float* __restrict__ pair_w)
{
  int idx = blockIdx.x * blockDim.x + threadIdx.x;
  if (idx >= NPAIR) return;
  int e = topk_idx[idx];
  int p = offs[e] + atomicAdd(&cur[e], 1);
  pair_tok[p] = idx / TOPK;
  pair_w[p]   = topk_w[idx];
}

__global__ void cvt_kernel(const float* __restrict__ x, ushort* __restrict__ xb) {
  int i = blockIdx.x * blockDim.x + threadIdx.x;
  float4 v = ((const float4*)x)[i];
  ((ushort4*)xb)[i] = make_ushort4(f2b(v.x), f2b(v.y), f2b(v.z), f2b(v.w));
}

// flat fp32 -> bf16 convert (k-contiguous weights)
__global__ __launch_bounds__(256) void fconv(const float* __restrict__ in, ushort* __restrict__ out) {
  int i = blockIdx.x * blockDim.x + threadIdx.x;
  float4 v = ((const float4*)in)[i];
  ((ushort4*)out)[i] = make_ushort4(f2b(v.x), f2b(v.y), f2b(v.z), f2b(v.w));
}

// transpose-convert: in [R][C] fp32 (row-major) -> out [C][R] bf16. 64x64 tiles.
#define TSTR 76
__global__ __launch_bounds__(256) void tconv(const float* __restrict__ in, ushort* __restrict__ out,
                                             int R, int C) {
  __shared__ ushort T[64*TSTR];
  int tiles_c = C >> 6;
  int bt = blockIdx.x;
  int r0 = (bt / tiles_c) << 6;
  int c0 = (bt % tiles_c) << 6;
  const float* src = in + (size_t)blockIdx.y * R * C;
  ushort* dst = out + (size_t)blockIdx.y * R * C;
  int t = threadIdx.x;
  int row = (t >> 4) << 2;      // 0..60 step 4
  int col4 = (t & 15) << 2;     // 0..60 step 4
  float vv[4][4];
  #pragma unroll
  for (int i = 0; i < 4; ++i) {
    float4 v = *(const float4*)(src + (size_t)(r0 + row + i) * C + c0 + col4);
    vv[i][0] = v.x; vv[i][1] = v.y; vv[i][2] = v.z; vv[i][3] = v.w;
  }
  #pragma unroll
  for (int cc = 0; cc < 4; ++cc)
    *(ushort4*)&T[(col4 + cc)*TSTR + row] =
      make_ushort4(f2b(vv[0][cc]), f2b(vv[1][cc]), f2b(vv[2][cc]), f2b(vv[3][cc]));
  __syncthreads();
  int oc = t >> 2;              // 0..63
  int ok = (t & 3) << 4;        // 0,16,32,48
  ushort4 a0 = *(const ushort4*)&T[oc*TSTR + ok];
  ushort4 a1 = *(const ushort4*)&T[oc*TSTR + ok + 4];
  ushort4 a2 = *(const ushort4*)&T[oc*TSTR + ok + 8];
  ushort4 a3 = *(const ushort4*)&T[oc*TSTR + ok + 12];
  ushort* d = dst + (size_t)(c0 + oc) * R + r0 + ok;
  *(ushort4*)(d)     = a0;
  *(ushort4*)(d + 4) = a1;
  *(ushort4*)(d + 8) = a2;
  *(ushort4*)(d + 12) = a3;
}

// ================= PATH A: all-bf16 GEMMs (m97 structure) =================

// routed gate+up: BM=128 BN=64(x2) BK=32
__global__ __launch_bounds__(256) void gu_routed_b(
    const ushort* __restrict__ xb, const ushort* __restrict__ wgt, const ushort* __restrict__ wut,
    const int* __restrict__ pair_tok, const float* __restrict__ pair_w,
    const int* __restrict__ cnt, const int* __restrict__ offs,
    const int* __restrict__ tl_e, const int* __restrict__ tl_m, const int* __restrict__ ntl,
    ushort* __restrict__ act)
{
  __shared__ ushort A[2][128*32];
  __shared__ ushort Bg[2][64*32];
  __shared__ ushort Bu[2][64*32];

  int bid = blockIdx.x;
  int wid = (bid & 7) * 256 + (bid >> 3);
  int tile = wid >> 4;
  if (tile >= ntl[0]) return;
  int nt = wid & 15;
  int e  = tl_e[tile];
  int m0 = tl_m[tile];
  int ce = cnt[e];
  int oe = offs[e];
  int n0 = nt * 64;
  int tid = threadIdx.x, lane = tid & 63, w = tid >> 6;

  int csrc = (lane & 3) ^ ((lane >> 3) & 3);
  const ushort* asrc[2];
  #pragma unroll
  for (int j = 0; j < 2; ++j) {
    int r = (2*w + j)*16 + (lane >> 2);
    int pi = min(m0 + r, ce - 1);
    asrc[j] = xb + (size_t)pair_tok[oe + pi] * HD + csrc * 8;
  }
  int brow = w*16 + (lane >> 2);
  const ushort* bgsrc = wgt + ((size_t)e * FD + n0 + brow) * HD + csrc * 8;
  const ushort* busrc = wut + ((size_t)e * FD + n0 + brow) * HD + csrc * 8;

  int lm = lane & 15, lg = lane >> 4;
  int wr = w >> 1, wc = w & 1;
  int asw = (lm >> 1) & 3;

  f32x4 accg[4][2], accu[4][2];
  #pragma unroll
  for (int m = 0; m < 4; ++m)
    #pragma unroll
    for (int n = 0; n < 2; ++n) { accg[m][n] = f32x4{0,0,0,0}; accu[m][n] = f32x4{0,0,0,0}; }

  #define GUB_ISSUE(T, BUF) do { \
    GLOAD_LDS16(asrc[0] + (T)*32, &A[BUF][(2*w)*512]); \
    GLOAD_LDS16(asrc[1] + (T)*32, &A[BUF][(2*w+1)*512]); \
    GLOAD_LDS16(bgsrc + (T)*32, &Bg[BUF][w*512]); \
    GLOAD_LDS16(busrc + (T)*32, &Bu[BUF][w*512]); \
  } while (0)

  GUB_ISSUE(0, 0);
  WAIT_VM0;
  __syncthreads();
  int cur = 0;
  for (int t = 0; t < 64; ++t) {
    if (t + 1 < 64) GUB_ISSUE(t + 1, cur ^ 1);
    bf16x8 a[4], bg[2], bu[2];
    #pragma unroll
    for (int m = 0; m < 4; ++m)
      a[m] = *(const bf16x8*)&A[cur][(wr*64 + m*16 + lm)*32 + (lg ^ asw)*8];
    #pragma unroll
    for (int n = 0; n < 2; ++n) {
      int row = wc*32 + n*16 + lm;
      bg[n] = *(const bf16x8*)&Bg[cur][row*32 + (lg ^ asw)*8];
      bu[n] = *(const bf16x8*)&Bu[cur][row*32 + (lg ^ asw)*8];
    }
    __builtin_amdgcn_s_setprio(1);
    #pragma unroll
    for (int m = 0; m < 4; ++m)
      #pragma unroll
      for (int n = 0; n < 2; ++n) {
        accg[m][n] = __builtin_amdgcn_mfma_f32_16x16x32_bf16(a[m], bg[n], accg[m][n], 0, 0, 0);
        accu[m][n] = __builtin_amdgcn_mfma_f32_16x16x32_bf16(a[m], bu[n], accu[m][n], 0, 0, 0);
      }
    __builtin_amdgcn_s_setprio(0);
    if (t + 1 < 64) WAIT_VM0;
    __syncthreads();
    cur ^= 1;
  }
  #undef GUB_ISSUE

  #pragma unroll
  for (int m = 0; m < 4; ++m) {
    #pragma unroll
    for (int j = 0; j < 4; ++j) {
      int rl = wr*64 + m*16 + lg*4 + j;
      int pi = m0 + rl;
      if (pi >= ce) continue;
      float pwv = pair_w[oe + pi];
      size_t base = (size_t)(oe + pi) * FD + n0 + wc*32;
      #pragma unroll
      for (int n = 0; n < 2; ++n) {
        float gv = accg[m][n][j];
        float uv = accu[m][n][j];
        float sv = gv / (1.f + __expf(-gv));
        act[base + n*16 + lm] = f2b(sv * uv * pwv);
      }
    }
  }
}

// routed down: BM=128 BN=128 BK=32, atomic scatter
__global__ __launch_bounds__(256) void down_routed_b(
    const ushort* __restrict__ act, const ushort* __restrict__ wdt,
    const int* __restrict__ pair_tok, const int* __restrict__ cnt, const int* __restrict__ offs,
    const int* __restrict__ tl_e, const int* __restrict__ tl_m, const int* __restrict__ ntl,
    float* __restrict__ y)
{
  __shared__ ushort A[2][128*32];
  __shared__ ushort Bd[2][128*32];

  int bid = blockIdx.x;
  int wid = (bid & 7) * 256 + (bid >> 3);
  int tile = wid >> 4;
  if (tile >= ntl[0]) return;
  int nt = wid & 15;
  int e  = tl_e[tile];
  int m0 = tl_m[tile];
  int ce = cnt[e];
  int oe = offs[e];
  int n0 = nt * 128;
  int tid = threadIdx.x, lane = tid & 63, w = tid >> 6;

  int csrc = (lane & 3) ^ ((lane >> 3) & 3);
  const ushort* asrc[2];
  const ushort* bsrc[2];
  #pragma unroll
  for (int j = 0; j < 2; ++j) {
    int r = (2*w + j)*16 + (lane >> 2);
    int pi = min(m0 + r, ce - 1);
    asrc[j] = act + (size_t)(oe + pi) * FD + csrc * 8;
    bsrc[j] = wdt + ((size_t)e * HD + n0 + r) * FD + csrc * 8;
  }

  int lm = lane & 15, lg = lane >> 4;
  int wr = w >> 1, wc = w & 1;
  int asw = (lm >> 1) & 3;

  f32x4 acc[4][4];
  #pragma unroll
  for (int m = 0; m < 4; ++m)
    #pragma unroll
    for (int n = 0; n < 4; ++n) acc[m][n] = f32x4{0,0,0,0};

  #define DNB_ISSUE(T, BUF) do { \
    GLOAD_LDS16(asrc[0] + (T)*32, &A[BUF][(2*w)*512]); \
    GLOAD_LDS16(asrc[1] + (T)*32, &A[BUF][(2*w+1)*512]); \
    GLOAD_LDS16(bsrc[0] + (T)*32, &Bd[BUF][(2*w)*512]); \
    GLOAD_LDS16(bsrc[1] + (T)*32, &Bd[BUF][(2*w+1)*512]); \
  } while (0)

  DNB_ISSUE(0, 0);
  WAIT_VM0;
  __syncthreads();
  int cur = 0;
  for (int t = 0; t < 32; ++t) {
    if (t + 1 < 32) DNB_ISSUE(t + 1, cur ^ 1);
    bf16x8 a[4], b[4];
    #pragma unroll
    for (int m = 0; m < 4; ++m)
      a[m] = *(const bf16x8*)&A[cur][(wr*64 + m*16 + lm)*32 + (lg ^ asw)*8];
    #pragma unroll
    for (int n = 0; n < 4; ++n) {
      int row = wc*64 + n*16 + lm;
      b[n] = *(const bf16x8*)&Bd[cur][row*32 + (lg ^ asw)*8];
    }
    __builtin_amdgcn_s_setprio(1);
    #pragma unroll
    for (int m = 0; m < 4; ++m)
      #pragma unroll
      for (int n = 0; n < 4; ++n)
        acc[m][n] = __builtin_amdgcn_mfma_f32_16x16x32_bf16(a[m], b[n], acc[m][n], 0, 0, 0);
    __builtin_amdgcn_s_setprio(0);
    if (t + 1 < 32) WAIT_VM0;
    __syncthreads();
    cur ^= 1;
  }
  #undef DNB_ISSUE

  #pragma unroll
  for (int m = 0; m < 4; ++m) {
    #pragma unroll
    for (int j = 0; j < 4; ++j) {
      int rl = wr*64 + m*16 + lg*4 + j;
      int pi = m0 + rl;
      if (pi >= ce) continue;
      int tok = pair_tok[oe + pi];
      size_t base = (size_t)tok * HD + n0 + wc*64;
      #pragma unroll
      for (int n = 0; n < 4; ++n)
        atomicAdd(&y[base + n*16 + lm], acc[m][n][j]);
    }
  }
}

// shared gate+up
__global__ __launch_bounds__(256) void shared_gu_b(
    const ushort* __restrict__ xb, const ushort* __restrict__ sgb, const ushort* __restrict__ sub,
    ushort* __restrict__ sact)
{
  __shared__ ushort A[2][128*32];
  __shared__ ushort Bg[2][64*32];
  __shared__ ushort Bu[2][64*32];

  int bid = blockIdx.x;
  int wid = (bid & 7) * 64 + (bid >> 3);
  int mt = wid & 15;
  int nt = wid >> 4;
  int m0 = mt * 128;
  int n0 = nt * 64;
  int tid = threadIdx.x, lane = tid & 63, w = tid >> 6;

  int csrc = (lane & 3) ^ ((lane >> 3) & 3);
  const ushort* asrc[2];
  #pragma unroll
  for (int j = 0; j < 2; ++j) {
    int r = (2*w + j)*16 + (lane >> 2);
    asrc[j] = xb + (size_t)(m0 + r) * HD + csrc * 8;
  }
  int brow = w*16 + (lane >> 2);
  const ushort* bgsrc = sgb + (size_t)(n0 + brow) * HD + csrc * 8;
  const ushort* busrc = sub + (size_t)(n0 + brow) * HD + csrc * 8;

  int lm = lane & 15, lg = lane >> 4;
  int wr = w >> 1, wc = w & 1;
  int asw = (lm >> 1) & 3;

  f32x4 accg[4][2], accu[4][2];
  #pragma unroll
  for (int m = 0; m < 4; ++m)
    #pragma unroll
    for (int n = 0; n < 2; ++n) { accg[m][n] = f32x4{0,0,0,0}; accu[m][n] = f32x4{0,0,0,0}; }

  #define SGB_ISSUE(T, BUF) do { \
    GLOAD_LDS16(asrc[0] + (T)*32, &A[BUF][(2*w)*512]); \
    GLOAD_LDS16(asrc[1] + (T)*32, &A[BUF][(2*w+1)*512]); \
    GLOAD_LDS16(bgsrc + (T)*32, &Bg[BUF][w*512]); \
    GLOAD_LDS16(busrc + (T)*32, &Bu[BUF][w*512]); \
  } while (0)

  SGB_ISSUE(0, 0);
  WAIT_VM0;
  __syncthreads();
  int cur = 0;
  for (int t = 0; t < 64; ++t) {
    if (t + 1 < 64) SGB_ISSUE(t + 1, cur ^ 1);
    bf16x8 a[4], bg[2], bu[2];
    #pragma unroll
    for (int m = 0; m < 4; ++m)
      a[m] = *(const bf16x8*)&A[cur][(wr*64 + m*16 + lm)*32 + (lg ^ asw)*8];
    #pragma unroll
    for (int n = 0; n < 2; ++n) {
      int row = wc*32 + n*16 + lm;
      bg[n] = *(const bf16x8*)&Bg[cur][row*32 + (lg ^ asw)*8];
      bu[n] = *(const bf16x8*)&Bu[cur][row*32 + (lg ^ asw)*8];
    }
    __builtin_amdgcn_s_setprio(1);
    #pragma unroll
    for (int m = 0; m < 4; ++m)
      #pragma unroll
      for (int n = 0; n < 2; ++n) {
        accg[m][n] = __builtin_amdgcn_mfma_f32_16x16x32_bf16(a[m], bg[n], accg[m][n], 0, 0, 0);
        accu[m][n] = __builtin_amdgcn_mfma_f32_16x16x32_bf16(a[m], bu[n], accu[m][n], 0, 0, 0);
      }
    __builtin_amdgcn_s_setprio(0);
    if (t + 1 < 64) WAIT_VM0;
    __syncthreads();
    cur ^= 1;
  }
  #undef SGB_ISSUE

  #pragma unroll
  for (int m = 0; m < 4; ++m) {
    #pragma unroll
    for (int j = 0; j < 4; ++j) {
      int rl = wr*64 + m*16 + lg*4 + j;
      size_t base = (size_t)(m0 + rl) * SDIM + n0 + wc*32;
      #pragma unroll
      for (int n = 0; n < 2; ++n) {
        float gv = accg[m][n][j];
        float uv = accu[m][n][j];
        float sv = gv / (1.f + __expf(-gv));
        sact[base + n*16 + lm] = f2b(sv * uv);
      }
    }
  }
}

// shared down (y +=)
__global__ __launch_bounds__(256) void shared_down_b(
    const ushort* __restrict__ sact, const ushort* __restrict__ sdb, float* __restrict__ y)
{
  __shared__ ushort A[2][128*32];
  __shared__ ushort Bd[2][128*32];

  int bid = blockIdx.x;
  int wid = (bid & 7) * 32 + (bid >> 3);
  int mt = wid & 15;
  int nt = wid >> 4;
  int m0 = mt * 128;
  int n0 = nt * 128;
  int tid = threadIdx.x, lane = tid & 63, w = tid >> 6;

  int csrc = (lane & 3) ^ ((lane >> 3) & 3);
  const ushort* asrc[2];
  const ushort* bsrc[2];
  #pragma unroll
  for (int j = 0; j < 2; ++j) {
    int r = (2*w + j)*16 + (lane >> 2);
    asrc[j] = sact + (size_t)(m0 + r) * SDIM + csrc * 8;
    bsrc[j] = sdb + (size_t)(n0 + r) * SDIM + csrc * 8;
  }

  int lm = lane & 15, lg = lane >> 4;
  int wr = w >> 1, wc = w & 1;
  int asw = (lm >> 1) & 3;

  f32x4 acc[4][4];
  #pragma unroll
  for (int m = 0; m < 4; ++m)
    #pragma unroll
    for (int n = 0; n < 4; ++n) acc[m][n] = f32x4{0,0,0,0};

  #define SDB_ISSUE(T, BUF) do { \
    GLOAD_LDS16(asrc[0] + (T)*32, &A[BUF][(2*w)*512]); \
    GLOAD_LDS16(asrc[1] + (T)*32, &A[BUF][(2*w+1)*512]); \
    GLOAD_LDS16(bsrc[0] + (T)*32, &Bd[BUF][(2*w)*512]); \
    GLOAD_LDS16(bsrc[1] + (T)*32, &Bd[BUF][(2*w+1)*512]); \
  } while (0)

  SDB_ISSUE(0, 0);
  WAIT_VM0;
  __syncthreads();
  int cur = 0;
  for (int t = 0; t < 64; ++t) {
    if (t + 1 < 64) SDB_ISSUE(t + 1, cur ^ 1);
    bf16x8 a[4], b[4];
    #pragma unroll
    for (int m = 0; m < 4; ++m)
      a[m] = *(const bf16x8*)&A[cur][(wr*64 + m*16 + lm)*32 + (lg ^ asw)*8];
    #pragma unroll
    for (int n = 0; n < 4; ++n) {
      int row = wc*64 + n*16 + lm;
      b[n] = *(const bf16x8*)&Bd[cur][row*32 + (lg ^ asw)*8];
    }
    __builtin_amdgcn_s_setprio(1);
    #pragma unroll
    for (int m = 0; m < 4; ++m)
      #pragma unroll
      for (int n = 0; n < 4; ++n)
        acc[m][n] = __builtin_amdgcn_mfma_f32_16x16x32_bf16(a[m], b[n], acc[m][n], 0, 0, 0);
    __builtin_amdgcn_s_setprio(0);
    if (t + 1 < 64) WAIT_VM0;
    __syncthreads();
    cur ^= 1;
  }
  #undef SDB_ISSUE

  #pragma unroll
  for (int m = 0; m < 4; ++m) {
    #pragma unroll
    for (int j = 0; j < 4; ++j) {
      int rl = wr*64 + m*16 + lg*4 + j;
      size_t base = (size_t)(m0 + rl) * HD + n0 + wc*64;
      #pragma unroll
      for (int n = 0; n < 4; ++n)
        y[base + n*16 + lm] += acc[m][n][j];
    }
  }
}

// ================= PATH B (fallback, R4 proven): inline fp32 B =================

__global__ __launch_bounds__(256) void gu_routed_f(
    const ushort* __restrict__ xb, const float* __restrict__ wg, const float* __restrict__ wu,
    const int* __restrict__ pair_tok, const float* __restrict__ pair_w,
    const int* __restrict__ cnt, const int* __restrict__ offs,
    ushort* __restrict__ act)
{
  __shared__ ushort A[2][128*32];
  __shared__ ushort Bg[2][64*BSTR];
  __shared__ ushort Bu[2][64*BSTR];

  int bid = blockIdx.x;
  int wid = (bid & 7) * 1024 + (bid >> 3);
  int mt = wid & 15;
  int nt = (wid >> 4) & 15;
  int e  = wid >> 8;
  int ce = cnt[e];
  int m0 = mt * 128;
  if (m0 >= ce) return;
  int oe = offs[e];
  int n0 = nt * 64;
  int tid = threadIdx.x, lane = tid & 63, w = tid >> 6;

  int csrc = (lane & 3) ^ ((lane >> 3) & 3);
  const ushort* asrc[2];
  #pragma unroll
  for (int j = 0; j < 2; ++j) {
    int r = (2*w + j)*16 + (lane >> 2);
    int pi = min(m0 + r, ce - 1);
    asrc[j] = xb + (size_t)pair_tok[oe + pi] * HD + csrc * 8;
  }
  int tsel = tid >> 7;
  int ttb = tid & 127;
  int fg = ttb & 15, hg = ttb >> 4;
  const float* wsrc = (tsel ? wu : wg) + (size_t)e * HD * FD + (size_t)hg*4*FD + n0 + fg*4;

  int lm = lane & 15, lg = lane >> 4;
  int wr = w >> 1, wc = w & 1;
  int asw = (lm >> 1) & 3;

  f32x4 accg[4][2], accu[4][2];
  #pragma unroll
  for (int m = 0; m < 4; ++m)
    #pragma unroll
    for (int n = 0; n < 2; ++n) { accg[m][n] = f32x4{0,0,0,0}; accu[m][n] = f32x4{0,0,0,0}; }

  float4 rB[4];
  #define GU_ISSUE(T, BUF) do { \
    _Pragma("unroll") \
    for (int j = 0; j < 2; ++j) \
      GLOAD_LDS16(asrc[j] + (T)*32, &A[BUF][(2*w+j)*512]); \
    const float* p = wsrc + (size_t)(T)*32*FD; \
    rB[0] = *(const float4*)(p); \
    rB[1] = *(const float4*)(p + FD); \
    rB[2] = *(const float4*)(p + 2*FD); \
    rB[3] = *(const float4*)(p + 3*FD); \
  } while (0)
  #define GU_WRITE(BUF) do { \
    ushort* dst = tsel ? &Bu[BUF][0] : &Bg[BUF][0]; \
    _Pragma("unroll") \
    for (int c = 0; c < 4; ++c) { \
      int row = fg*4 + ((c + fg) & 3); \
      *(ushort4*)&dst[row*BSTR + hg*4] = \
        make_ushort4(f2b(rB[0][c]), f2b(rB[1][c]), f2b(rB[2][c]), f2b(rB[3][c])); \
    } \
  } while (0)

  GU_ISSUE(0, 0);
  WAIT_VM0;
  GU_WRITE(0);
  __syncthreads();

  int cur = 0;
  for (int t = 0; t < HD/32; ++t) {
    if (t + 1 < HD/32) GU_ISSUE(t + 1, cur ^ 1);
    bf16x8 a[4], bg[2], bu[2];
    #pragma unroll
    for (int m = 0; m < 4; ++m)
      a[m] = *(const bf16x8*)&A[cur][(wr*64 + m*16 + lm)*32 + (lg ^ asw)*8];
    #pragma unroll
    for (int n = 0; n < 2; ++n) {
      int row = prow(wc*32 + n*16 + lm);
      bg[n] = *(const bf16x8*)&Bg[cur][row*BSTR + lg*8];
      bu[n] = *(const bf16x8*)&Bu[cur][row*BSTR + lg*8];
    }
    #pragma unroll
    for (int m = 0; m < 4; ++m)
      #pragma unroll
      for (int n = 0; n < 2; ++n) {
        accg[m][n] = __builtin_amdgcn_mfma_f32_16x16x32_bf16(a[m], bg[n], accg[m][n], 0, 0, 0);
        accu[m][n] = __builtin_amdgcn_mfma_f32_16x16x32_bf16(a[m], bu[n], accu[m][n], 0, 0, 0);
      }
    if (t + 1 < HD/32) {
      WAIT_VM0;
      GU_WRITE(cur ^ 1);
    }
    __syncthreads();
    cur ^= 1;
  }
  #undef GU_ISSUE
  #undef GU_WRITE

  #pragma unroll
  for (int m = 0; m < 4; ++m) {
    #pragma unroll
    for (int j = 0; j < 4; ++j) {
      int rl = wr*64 + m*16 + lg*4 + j;
      int pi = m0 + rl;
      if (pi >= ce) continue;
      float pwv = pair_w[oe + pi];
      size_t base = (size_t)(oe + pi) * FD + n0 + wc*32;
      #pragma unroll
      for (int n = 0; n < 2; ++n) {
        float gv = accg[m][n][j];
        float uv = accu[m][n][j];
        float sv = gv / (1.f + __expf(-gv));
        act[base + n*16 + lm] = f2b(sv * uv * pwv);
      }
    }
  }
}

__global__ __launch_bounds__(256) void down_routed_f(
    const ushort* __restrict__ act, const float* __restrict__ wd,
    const int* __restrict__ pair_tok, const int* __restrict__ cnt, const int* __restrict__ offs,
    float* __restrict__ y)
{
  __shared__ ushort A[2][128*32];
  __shared__ ushort Bd[2][128*BSTR];

  int bid = blockIdx.x;
  int wid = (bid & 7) * 1024 + (bid >> 3);
  int mt = wid & 15;
  int nt = (wid >> 4) & 15;
  int e  = wid >> 8;
  int ce = cnt[e];
  int m0 = mt * 128;
  if (m0 >= ce) return;
  int oe = offs[e];
  int n0 = nt * 128;
  int tid = threadIdx.x, lane = tid & 63, w = tid >> 6;

  int csrc = (lane & 3) ^ ((lane >> 3) & 3);
  const ushort* asrc[2];
  #pragma unroll
  for (int j = 0; j < 2; ++j) {
    int r = (2*w + j)*16 + (lane >> 2);
    int pi = min(m0 + r, ce - 1);
    asrc[j] = act + (size_t)(oe + pi) * FD + csrc * 8;
  }
  int fg = tid & 31, hg = tid >> 5;
  const float* wsrc = wd + (size_t)e * FD * HD + (size_t)hg*4*HD + n0 + fg*4;

  int lm = lane & 15, lg = lane >> 4;
  int wr = w >> 1, wc = w & 1;
  int asw = (lm >> 1) & 3;

  f32x4 acc[4][4];
  #pragma unroll
  for (int m = 0; m < 4; ++m)
    #pragma unroll
    for (int n = 0; n < 4; ++n) acc[m][n] = f32x4{0,0,0,0};

  float4 rB[4];
  #define DN_ISSUE(T, BUF) do { \
    _Pragma("unroll") \
    for (int j = 0; j < 2; ++j) \
      GLOAD_LDS16(asrc[j] + (T)*32, &A[BUF][(2*w+j)*512]); \
    const float* p = wsrc + (size_t)(T)*32*HD; \
    rB[0] = *(const float4*)(p); \
    rB[1] = *(const float4*)(p + HD); \
    rB[2] = *(const float4*)(p + 2*HD); \
    rB[3] = *(const float4*)(p + 3*HD); \
  } while (0)
  #define DN_WRITE(BUF) do { \
    _Pragma("unroll") \
    for (int c = 0; c < 4; ++c) { \
      int row = fg*4 + ((c + fg) & 3); \
      *(ushort4*)&Bd[BUF][row*BSTR + hg*4] = \
        make_ushort4(f2b(rB[0][c]), f2b(rB[1][c]), f2b(rB[2][c]), f2b(rB[3][c])); \
    } \
  } while (0)

  DN_ISSUE(0, 0);
  WAIT_VM0;
  DN_WRITE(0);
  __syncthreads();

  int cur = 0;
  for (int t = 0; t < FD/32; ++t) {
    if (t + 1 < FD/32) DN_ISSUE(t + 1, cur ^ 1);
    bf16x8 a[4], b[4];
    #pragma unroll
    for (int m = 0; m < 4; ++m)
      a[m] = *(const bf16x8*)&A[cur][(wr*64 + m*16 + lm)*32 + (lg ^ asw)*8];
    #pragma unroll
    for (int n = 0; n < 4; ++n) {
      int row = prow(wc*64 + n*16 + lm);
      b[n] = *(const bf16x8*)&Bd[cur][row*BSTR + lg*8];
    }
    #pragma unroll
    for (int m = 0; m < 4; ++m)
      #pragma unroll
      for (int n = 0; n < 4; ++n)
        acc[m][n] = __builtin_amdgcn_mfma_f32_16x16x32_bf16(a[m], b[n], acc[m][n], 0, 0, 0);
    if (t + 1 < FD/32) {
      WAIT_VM0;
      DN_WRITE(cur ^ 1);
    }
    __syncthreads();
    cur ^= 1;
  }
  #undef DN_ISSUE
  #undef DN_WRITE

  #pragma unroll
  for (int m = 0; m < 4; ++m) {
    #pragma unroll
    for (int j = 0; j < 4; ++j) {
      int rl = wr*64 + m*16 + lg*4 + j;
      int pi = m0 + rl;
      if (pi >= ce) continue;
      int tok = pair_tok[oe + pi];
      size_t base = (size_t)tok * HD + n0 + wc*64;
      #pragma unroll
      for (int n = 0; n < 4; ++n)
        atomicAdd(&y[base + n*16 + lm], acc[m][n][j]);
    }
  }
}

__global__ __launch_bounds__(256) void shared_gu_f(
    const ushort* __restrict__ xb, const float* __restrict__ sg, const float* __restrict__ su,
    ushort* __restrict__ sact)
{
  __shared__ ushort A[2][128*32];
  __shared__ ushort Bg[2][64*BSTR];
  __shared__ ushort Bu[2][64*BSTR];

  int bid = blockIdx.x;
  int wid = (bid & 7) * 64 + (bid >> 3);
  int mt = wid & 15;
  int nt = wid >> 4;
  int m0 = mt * 128;
  int n0 = nt * 64;
  int tid = threadIdx.x, lane = tid & 63, w = tid >> 6;

  int csrc = (lane & 3) ^ ((lane >> 3) & 3);
  const ushort* asrc[2];
  #pragma unroll
  for (int j = 0; j < 2; ++j) {
    int r = (2*w + j)*16 + (lane >> 2);
    asrc[j] = xb + (size_t)(m0 + r) * HD + csrc * 8;
  }
  int tsel = tid >> 7;
  int ttb = tid & 127;
  int bn = ttb >> 1, bsub = ttb & 1;
  const float* bsrc = (tsel ? su : sg) + (size_t)(n0 + bn) * HD + bsub * 16;

  int lm = lane & 15, lg = lane >> 4;
  int wr = w >> 1, wc = w & 1;
  int asw = (lm >> 1) & 3;

  f32x4 accg[4][2], accu[4][2];
  #pragma unroll
  for (int m = 0; m < 4; ++m)
    #pragma unroll
    for (int n = 0; n < 2; ++n) { accg[m][n] = f32x4{0,0,0,0}; accu[m][n] = f32x4{0,0,0,0}; }

  float4 rB[4];
  #define SG_ISSUE(T, BUF) do { \
    _Pragma("unroll") \
    for (int j = 0; j < 2; ++j) \
      GLOAD_LDS16(asrc[j] + (T)*32, &A[BUF][(2*w+j)*512]); \
    const float* p = bsrc + (T)*32; \
    rB[0] = *(const float4*)(p); \
    rB[1] = *(const float4*)(p + 4); \
    rB[2] = *(const float4*)(p + 8); \
    rB[3] = *(const float4*)(p + 12); \
  } while (0)
  #define SG_WRITE(BUF) do { \
    ushort* dst = (tsel ? &Bu[BUF][0] : &Bg[BUF][0]) + bn*BSTR + bsub*16; \
    dst[0]=f2b(rB[0][0]); dst[1]=f2b(rB[0][1]); dst[2]=f2b(rB[0][2]); dst[3]=f2b(rB[0][3]); \
    dst[4]=f2b(rB[1][0]); dst[5]=f2b(rB[1][1]); dst[6]=f2b(rB[1][2]); dst[7]=f2b(rB[1][3]); \
    dst[8]=f2b(rB[2][0]); dst[9]=f2b(rB[2][1]); dst[10]=f2b(rB[2][2]); dst[11]=f2b(rB[2][3]); \
    dst[12]=f2b(rB[3][0]); dst[13]=f2b(rB[3][1]); dst[14]=f2b(rB[3][2]); dst[15]=f2b(rB[3][3]); \
  } while (0)

  SG_ISSUE(0, 0);
  WAIT_VM0;
  SG_WRITE(0);
  __syncthreads();

  int cur = 0;
  for (int t = 0; t < HD/32; ++t) {
    if (t + 1 < HD/32) SG_ISSUE(t + 1, cur ^ 1);
    bf16x8 a[4], bg[2], bu[2];
    #pragma unroll
    for (int m = 0; m < 4; ++m)
      a[m] = *(const bf16x8*)&A[cur][(wr*64 + m*16 + lm)*32 + (lg ^ asw)*8];
    #pragma unroll
    for (int n = 0; n < 2; ++n) {
      int row = wc*32 + n*16 + lm;
      bg[n] = *(const bf16x8*)&Bg[cur][row*BSTR + lg*8];
      bu[n] = *(const bf16x8*)&Bu[cur][row*BSTR + lg*8];
    }
    #pragma unroll
    for (int m = 0; m < 4; ++m)
      #pragma unroll
      for (int n = 0; n < 2; ++n) {
        accg[m][n] = __builtin_amdgcn_mfma_f32_16x16x32_bf16(a[m], bg[n], accg[m][n], 0, 0, 0);
        accu[m][n] = __builtin_amdgcn_mfma_f32_16x16x32_bf16(a[m], bu[n], accu[m][n], 0, 0, 0);
      }
    if (t + 1 < HD/32) {
      WAIT_VM0;
      SG_WRITE(cur ^ 1);
    }
    __syncthreads();
    cur ^= 1;
  }
  #undef SG_ISSUE
  #undef SG_WRITE

  #pragma unroll
  for (int m = 0; m < 4; ++m) {
    #pragma unroll
    for (int j = 0; j < 4; ++j) {
      int rl = wr*64 + m*16 + lg*4 + j;
      size_t base = (size_t)(m0 + rl) * SDIM + n0 + wc*32;
      #pragma unroll
      for (int n = 0; n < 2; ++n) {
        float gv = accg[m][n][j];
        float uv = accu[m][n][j];
        float sv = gv / (1.f + __expf(-gv));
        sact[base + n*16 + lm] = f2b(sv * uv);
      }
    }
  }
}

__global__ __launch_bounds__(256) void shared_down_f(
    const ushort* __restrict__ sact, const float* __restrict__ sd, float* __restrict__ y)
{
  __shared__ ushort A[2][128*32];
  __shared__ ushort Bd[2][128*BSTR];

  int bid = blockIdx.x;
  int wid = (bid & 7) * 32 + (bid >> 3);
  int mt = wid & 15;
  int nt = wid >> 4;
  int m0 = mt * 128;
  int n0 = nt * 128;
  int tid = threadIdx.x, lane = tid & 63, w = tid >> 6;

  int csrc = (lane & 3) ^ ((lane >> 3) & 3);
  const ushort* asrc[2];
  #pragma unroll
  for (int j = 0; j < 2; ++j) {
    int r = (2*w + j)*16 + (lane >> 2);
    asrc[j] = sact + (size_t)(m0 + r) * SDIM + csrc * 8;
  }
  int bn = tid >> 1, bsub = tid & 1;
  const float* bsrc = sd + (size_t)(n0 + bn) * SDIM + bsub * 16;

  int lm = lane & 15, lg = lane >> 4;
  int wr = w >> 1, wc = w & 1;
  int asw = (lm >> 1) & 3;

  f32x4 acc[4][4];
  #pragma unroll
  for (int m = 0; m < 4; ++m)
    #pragma unroll
    for (int n = 0; n < 4; ++n) acc[m][n] = f32x4{0,0,0,0};

  float4 rB[4];
  #define SD_ISSUE(T, BUF) do { \
    _Pragma("unroll") \
    for (int j = 0; j < 2; ++j) \
      GLOAD_LDS16(asrc[j] + (T)*32, &A[BUF][(2*w+j)*512]); \
    const float* p = bsrc + (T)*32; \
    rB[0] = *(const float4*)(p); \
    rB[1] = *(const float4*)(p + 4); \
    rB[2] = *(const float4*)(p + 8); \
    rB[3] = *(const float4*)(p + 12); \
  } while (0)
  #define SD_WRITE(BUF) do { \
    ushort* dst = &Bd[BUF][bn*BSTR + bsub*16]; \
    dst[0]=f2b(rB[0][0]); dst[1]=f2b(rB[0][1]); dst[2]=f2b(rB[0][2]); dst[3]=f2b(rB[0][3]); \
    dst[4]=f2b(rB[1][0]); dst[5]=f2b(rB[1][1]); dst[6]=f2b(rB[1][2]); dst[7]=f2b(rB[1][3]); \
    dst[8]=f2b(rB[2][0]); dst[9]=f2b(rB[2][1]); dst[10]=f2b(rB[2][2]); dst[11]=f2b(rB[2][3]); \
    dst[12]=f2b(rB[3][0]); dst[13]=f2b(rB[3][1]); dst[14]=f2b(rB[3][2]); dst[15]=f2b(rB[3][3]); \
  } while (0)

  SD_ISSUE(0, 0);
  WAIT_VM0;
  SD_WRITE(0);
  __syncthreads();

  int cur = 0;
  for (int t = 0; t < SDIM/32; ++t) {
    if (t + 1 < SDIM/32) SD_ISSUE(t + 1, cur ^ 1);
    bf16x8 a[4], b[4];
    #pragma unroll
    for (int m = 0; m < 4; ++m)
      a[m] = *(const bf16x8*)&A[cur][(wr*64 + m*16 + lm)*32 + (lg ^ asw)*8];
    #pragma unroll
    for (int n = 0; n < 4; ++n) {
      int row = wc*64 + n*16 + lm;
      b[n] = *(const bf16x8*)&Bd[cur][row*BSTR + lg*8];
    }
    #pragma unroll
    for (int m = 0; m < 4; ++m)
      #pragma unroll
      for (int n = 0; n < 4; ++n)
        acc[m][n] = __builtin_amdgcn_mfma_f32_16x16x32_bf16(a[m], b[n], acc[m][n], 0, 0, 0);
    if (t + 1 < SDIM/32) {
      WAIT_VM0;
      SD_WRITE(cur ^ 1);
    }
    __syncthreads();
    cur ^= 1;
  }
  #undef SD_ISSUE
  #undef SD_WRITE

  #pragma unroll
  for (int m = 0; m < 4; ++m) {
    #pragma unroll
    for (int j = 0; j < 4; ++j) {
      int rl = wr*64 + m*16 + lg*4 + j;
      size_t base = (size_t)(m0 + rl) * HD + n0 + wc*64;
      #pragma unroll
      for (int n = 0; n < 4; ++n)
        y[base + n*16 + lm] += acc[m][n][j];
    }
  }
}

// ---------------- launch ----------------
extern "C" void kernel_launch(void* const* d_in, const int* in_sizes, int n_in,
                              void* d_out, int out_size, void* d_ws, size_t ws_size,
                              hipStream_t stream) {
  const float* x     = (const float*)d_in[0];
  const float* wgate = (const float*)d_in[1];
  const float* wg    = (const float*)d_in[2];
  const float* wu    = (const float*)d_in[3];
  const float* wd    = (const float*)d_in[4];
  const float* sg    = (const float*)d_in[5];
  const float* su    = (const float*)d_in[6];
  const float* sd    = (const float*)d_in[7];
  float* y = (float*)d_out;
  char* ws = (char*)d_ws;

  ushort* xb   = (ushort*)(ws + 0);
  ushort* act  = (ushort*)(ws + 8388608);
  ushort* sact = (ushort*)(ws + 33554432);
  int*    tidx = (int*)  (ws + 41943040);
  float*  tw   = (float*)(ws + 41992192);
  int*    ptok = (int*)  (ws + 42041344);
  float*  pw   = (float*)(ws + 42090496);
  int*    cnt  = (int*)  (ws + 42139648);
  int*    curc = (int*)  (ws + 42139776);
  int*    offs = (int*)  (ws + 42139904);
  int*    tl_e = (int*)  (ws + 42140160);
  int*    tl_m = (int*)  (ws + 42140672);
  int*    ntl  = (int*)  (ws + 42141184);
  ushort* wgt  = (ushort*)(ws + 50331648);    // 128 MB [E][F][H]
  ushort* wut  = (ushort*)(ws + 184549376);   // 128 MB
  ushort* wdt  = (ushort*)(ws + 318767104);   // 128 MB [E][H][F]
  ushort* sgb  = (ushort*)(ws + 452984832);   // 8 MB
  ushort* sub  = (ushort*)(ws + 461373440);
  ushort* sdb  = (ushort*)(ws + 469762048);
  const size_t WS_NEED = 478150656ULL;

  hipMemsetAsync(cnt, 0, 512, stream);
  hipMemsetAsync(d_out, 0, (size_t)TT * HD * 4, stream);

  cvt_kernel<<<dim3(4096), dim3(256), 0, stream>>>(x, xb);
  gating_kernel<<<dim3(TT), dim3(64), 0, stream>>>(x, wgate, tidx, tw, cnt);
  scan_kernel<<<dim3(1), dim3(64), 0, stream>>>(cnt, offs, tl_e, tl_m, ntl);
  fill_kernel<<<dim3(48), dim3(256), 0, stream>>>(tidx, tw, offs, curc, ptok, pw);

  if (ws_size >= WS_NEED) {
    // Path A: pre-convert weights to bf16 (transposed where k-strided)
    tconv<<<dim3(512, NEXP), dim3(256), 0, stream>>>(wg, wgt, HD, FD);   // [H][F] -> [F][H]
    tconv<<<dim3(512, NEXP), dim3(256), 0, stream>>>(wu, wut, HD, FD);
    tconv<<<dim3(512, NEXP), dim3(256), 0, stream>>>(wd, wdt, FD, HD);   // [F][H] -> [H][F]
    fconv<<<dim3(4096), dim3(256), 0, stream>>>(sg, sgb);
    fconv<<<dim3(4096), dim3(256), 0, stream>>>(su, sub);
    fconv<<<dim3(4096), dim3(256), 0, stream>>>(sd, sdb);

    gu_routed_b<<<dim3(2048), dim3(256), 0, stream>>>(xb, wgt, wut, ptok, pw, cnt, offs,
                                                      tl_e, tl_m, ntl, act);
    down_routed_b<<<dim3(2048), dim3(256), 0, stream>>>(act, wdt, ptok, cnt, offs,
                                                        tl_e, tl_m, ntl, y);
    shared_gu_b<<<dim3(512), dim3(256), 0, stream>>>(xb, sgb, sub, sact);
    shared_down_b<<<dim3(256), dim3(256), 0, stream>>>(sact, sdb, y);
  } else {
    // Path B fallback: inline fp32 B staging (R4-proven)
    gu_routed_f<<<dim3(8192), dim3(256), 0, stream>>>(xb, wg, wu, ptok, pw, cnt, offs, act);
    down_routed_f<<<dim3(8192), dim3(256), 0, stream>>>(act, wd, ptok, cnt, offs, y);
    shared_gu_f<<<dim3(512), dim3(256), 0, stream>>>(xb, sg, su, sact);
    shared_down_f<<<dim3(256), dim3(256), 0, stream>>>(sact, sd, y);
  }
}

// Round 7
// 875.079 us; speedup vs baseline: 1.0403x; 1.0403x over previous
//
#include <hip/hip_runtime.h>

#define HD   2048
#define FD   1024
#define NEXP 32
#define TOPK 6
#define TT   2048
#define SDIM 2048
#define NPAIR (TT*TOPK)
#define BSTR 40     // fallback-path B-tile LDS row stride (ushorts)

typedef __bf16 bf16x8 __attribute__((ext_vector_type(8)));
typedef float  f32x4  __attribute__((ext_vector_type(4)));

#define GLOAD_LDS16(g, l) __builtin_amdgcn_global_load_lds( \
    (const __attribute__((address_space(1))) void*)(g),     \
    (__attribute__((address_space(3))) void*)(l), 16, 0, 0)

#define WAIT_VM0  asm volatile("s_waitcnt vmcnt(0)" ::: "memory")

__device__ __forceinline__ ushort f2b(float f) {
  __bf16 h = (__bf16)f;
  union { __bf16 h; ushort u; } v; v.h = h;
  return v.u;
}

__device__ __forceinline__ int prow(int r) {   // fallback path
  return (r & ~3) | ((r + (r >> 2)) & 3);
}

// bijective XCD swizzle over nact active blocks (m204): block bid (XCD = bid&7)
// gets a wid from a contiguous per-XCD chunk. Requires bid < nact.
__device__ __forceinline__ int xcd_swz(int bid, int nact) {
  int xcd = bid & 7, i = bid >> 3;
  int q = nact >> 3, r = nact & 7;
  int base = (xcd < r) ? xcd * (q + 1) : r * (q + 1) + (xcd - r) * q;
  return base + i;
}

// ---------------- gating (fp32 exact) ----------------
__device__ __forceinline__ void argmax32(float &v, int &i) {
  #pragma unroll
  for (int m = 16; m >= 1; m >>= 1) {
    float ov = __shfl_xor(v, m, 32);
    int   oi = __shfl_xor(i, m, 32);
    if (ov > v || (ov == v && oi < i)) { v = ov; i = oi; }
  }
}

__global__ __launch_bounds__(64) void gating_kernel(
    const float* __restrict__ x, const float* __restrict__ wgate,
    int* __restrict__ topk_idx, float* __restrict__ topk_w, int* __restrict__ cnt)
{
  int t = blockIdx.x;
  int l = threadIdx.x;
  int e = l & 31;
  int half = l >> 5;
  const float* xr = x + (size_t)t * HD + half * (HD/2);
  const float* wr = wgate + (size_t)e * HD + half * (HD/2);
  float acc = 0.f;
  for (int i = 0; i < HD/2; i += 4) {
    float4 a = *(const float4*)(xr + i);
    float4 b = *(const float4*)(wr + i);
    acc += a.x*b.x + a.y*b.y + a.z*b.z + a.w*b.w;
  }
  acc += __shfl_xor(acc, 32);
  float logit = acc;
  float mx = logit;
  #pragma unroll
  for (int m = 16; m >= 1; m >>= 1) mx = fmaxf(mx, __shfl_xor(mx, m, 32));
  float p = __expf(logit - mx);
  float s = p;
  #pragma unroll
  for (int m = 16; m >= 1; m >>= 1) s += __shfl_xor(s, m, 32);
  float score = p / s;
  float gs = score;
  gs = fmaxf(gs, __shfl_xor(gs, 1, 32));
  gs = fmaxf(gs, __shfl_xor(gs, 2, 32));
  int g = e >> 2;
  float gw = gs;
  bool ingroup = false;
  for (int r = 0; r < 3; ++r) {
    float v = gw; int gi = g;
    argmax32(v, gi);
    if (g == gi) { ingroup = true; gw = -1.f; }
  }
  float ms = ingroup ? score : 0.f;
  int myrank = -1;
  float denom = 1e-20f;
  float mw = ms;
  for (int r = 0; r < 6; ++r) {
    float v = mw; int ei = e;
    argmax32(v, ei);
    denom += v;
    if (e == ei) { myrank = r; mw = -1.f; }
  }
  if (l < 32 && myrank >= 0) {
    topk_idx[t*TOPK + myrank] = e;
    topk_w  [t*TOPK + myrank] = score / denom;
    atomicAdd(&cnt[e], 1);
  }
}

__global__ void scan_kernel(const int* __restrict__ cnt, int* __restrict__ offs,
                            int* __restrict__ tl_e, int* __restrict__ tl_m, int* __restrict__ ntl) {
  if (threadIdx.x == 0) {
    int o = 0, nt = 0;
    for (int e = 0; e < NEXP; ++e) {
      offs[e] = o;
      for (int m = 0; m < cnt[e]; m += 128) { tl_e[nt] = e; tl_m[nt] = m; ++nt; }
      o += cnt[e];
    }
    ntl[0] = nt;
  }
}

__global__ void fill_kernel(const int* __restrict__ topk_idx, const float* __restrict__ topk_w,
                            const int* __restrict__ offs, int* __restrict__ cur,
                            int* __restrict__ pair_tok, float* __restrict__ pair_w)
{
  int idx = blockIdx.x * blockDim.x + threadIdx.x;
  if (idx >= NPAIR) return;
  int e = topk_idx[idx];
  int p = offs[e] + atomicAdd(&cur[e], 1);
  pair_tok[p] = idx / TOPK;
  pair_w[p]   = topk_w[idx];
}

__global__ void cvt_kernel(const float* __restrict__ x, ushort* __restrict__ xb) {
  int i = blockIdx.x * blockDim.x + threadIdx.x;
  float4 v = ((const float4*)x)[i];
  ((ushort4*)xb)[i] = make_ushort4(f2b(v.x), f2b(v.y), f2b(v.z), f2b(v.w));
}

// flat fp32 -> bf16 convert (k-contiguous weights)
__global__ __launch_bounds__(256) void fconv(const float* __restrict__ in, ushort* __restrict__ out) {
  int i = blockIdx.x * blockDim.x + threadIdx.x;
  float4 v = ((const float4*)in)[i];
  ((ushort4*)out)[i] = make_ushort4(f2b(v.x), f2b(v.y), f2b(v.z), f2b(v.w));
}

// transpose-convert: in [R][C] fp32 (row-major) -> out [C][R] bf16. 64x64 tiles.
#define TSTR 76
__global__ __launch_bounds__(256) void tconv(const float* __restrict__ in, ushort* __restrict__ out,
                                             int R, int C) {
  __shared__ ushort T[64*TSTR];
  int tiles_c = C >> 6;
  int bt = blockIdx.x;
  int r0 = (bt / tiles_c) << 6;
  int c0 = (bt % tiles_c) << 6;
  const float* src = in + (size_t)blockIdx.y * R * C;
  ushort* dst = out + (size_t)blockIdx.y * R * C;
  int t = threadIdx.x;
  int row = (t >> 4) << 2;
  int col4 = (t & 15) << 2;
  float vv[4][4];
  #pragma unroll
  for (int i = 0; i < 4; ++i) {
    float4 v = *(const float4*)(src + (size_t)(r0 + row + i) * C + c0 + col4);
    vv[i][0] = v.x; vv[i][1] = v.y; vv[i][2] = v.z; vv[i][3] = v.w;
  }
  #pragma unroll
  for (int cc = 0; cc < 4; ++cc)
    *(ushort4*)&T[(col4 + cc)*TSTR + row] =
      make_ushort4(f2b(vv[0][cc]), f2b(vv[1][cc]), f2b(vv[2][cc]), f2b(vv[3][cc]));
  __syncthreads();
  int oc = t >> 2;
  int ok = (t & 3) << 4;
  ushort4 a0 = *(const ushort4*)&T[oc*TSTR + ok];
  ushort4 a1 = *(const ushort4*)&T[oc*TSTR + ok + 4];
  ushort4 a2 = *(const ushort4*)&T[oc*TSTR + ok + 8];
  ushort4 a3 = *(const ushort4*)&T[oc*TSTR + ok + 12];
  ushort* d = dst + (size_t)(c0 + oc) * R + r0 + ok;
  *(ushort4*)(d)      = a0;
  *(ushort4*)(d + 4)  = a1;
  *(ushort4*)(d + 8)  = a2;
  *(ushort4*)(d + 12) = a3;
}

// ================= PATH A: all-bf16 GEMMs (m97 structure) =================

// routed gate+up: BM=128 BN=64(x2) BK=32
__global__ __launch_bounds__(256) void gu_routed_b(
    const ushort* __restrict__ xb, const ushort* __restrict__ wgt, const ushort* __restrict__ wut,
    const int* __restrict__ pair_tok, const float* __restrict__ pair_w,
    const int* __restrict__ cnt, const int* __restrict__ offs,
    const int* __restrict__ tl_e, const int* __restrict__ tl_m, const int* __restrict__ ntl,
    ushort* __restrict__ act)
{
  __shared__ ushort A[2][128*32];
  __shared__ ushort Bg[2][64*32];
  __shared__ ushort Bu[2][64*32];

  int nact = ntl[0] * 16;
  int bid = blockIdx.x;
  if (bid >= nact) return;
  int wid = xcd_swz(bid, nact);
  int tile = wid >> 4;
  int nt = wid & 15;
  int e  = tl_e[tile];
  int m0 = tl_m[tile];
  int ce = cnt[e];
  int oe = offs[e];
  int n0 = nt * 64;
  int tid = threadIdx.x, lane = tid & 63, w = tid >> 6;

  int csrc = (lane & 3) ^ ((lane >> 3) & 3);
  const ushort* asrc[2];
  #pragma unroll
  for (int j = 0; j < 2; ++j) {
    int r = (2*w + j)*16 + (lane >> 2);
    int pi = min(m0 + r, ce - 1);
    asrc[j] = xb + (size_t)pair_tok[oe + pi] * HD + csrc * 8;
  }
  int brow = w*16 + (lane >> 2);
  const ushort* bgsrc = wgt + ((size_t)e * FD + n0 + brow) * HD + csrc * 8;
  const ushort* busrc = wut + ((size_t)e * FD + n0 + brow) * HD + csrc * 8;

  int lm = lane & 15, lg = lane >> 4;
  int wr = w >> 1, wc = w & 1;
  int asw = (lm >> 1) & 3;

  f32x4 accg[4][2], accu[4][2];
  #pragma unroll
  for (int m = 0; m < 4; ++m)
    #pragma unroll
    for (int n = 0; n < 2; ++n) { accg[m][n] = f32x4{0,0,0,0}; accu[m][n] = f32x4{0,0,0,0}; }

  #define GUB_ISSUE(T, BUF) do { \
    GLOAD_LDS16(asrc[0] + (T)*32, &A[BUF][(2*w)*512]); \
    GLOAD_LDS16(asrc[1] + (T)*32, &A[BUF][(2*w+1)*512]); \
    GLOAD_LDS16(bgsrc + (T)*32, &Bg[BUF][w*512]); \
    GLOAD_LDS16(busrc + (T)*32, &Bu[BUF][w*512]); \
  } while (0)

  GUB_ISSUE(0, 0);
  WAIT_VM0;
  __syncthreads();
  int cur = 0;
  for (int t = 0; t < 64; ++t) {
    if (t + 1 < 64) GUB_ISSUE(t + 1, cur ^ 1);
    bf16x8 a[4], bg[2], bu[2];
    #pragma unroll
    for (int m = 0; m < 4; ++m)
      a[m] = *(const bf16x8*)&A[cur][(wr*64 + m*16 + lm)*32 + (lg ^ asw)*8];
    #pragma unroll
    for (int n = 0; n < 2; ++n) {
      int row = wc*32 + n*16 + lm;
      bg[n] = *(const bf16x8*)&Bg[cur][row*32 + (lg ^ asw)*8];
      bu[n] = *(const bf16x8*)&Bu[cur][row*32 + (lg ^ asw)*8];
    }
    __builtin_amdgcn_s_setprio(1);
    #pragma unroll
    for (int m = 0; m < 4; ++m)
      #pragma unroll
      for (int n = 0; n < 2; ++n) {
        accg[m][n] = __builtin_amdgcn_mfma_f32_16x16x32_bf16(a[m], bg[n], accg[m][n], 0, 0, 0);
        accu[m][n] = __builtin_amdgcn_mfma_f32_16x16x32_bf16(a[m], bu[n], accu[m][n], 0, 0, 0);
      }
    __builtin_amdgcn_s_setprio(0);
    if (t + 1 < 64) WAIT_VM0;
    __syncthreads();
    cur ^= 1;
  }
  #undef GUB_ISSUE

  #pragma unroll
  for (int m = 0; m < 4; ++m) {
    #pragma unroll
    for (int j = 0; j < 4; ++j) {
      int rl = wr*64 + m*16 + lg*4 + j;
      int pi = m0 + rl;
      if (pi >= ce) continue;
      float pwv = pair_w[oe + pi];
      size_t base = (size_t)(oe + pi) * FD + n0 + wc*32;
      #pragma unroll
      for (int n = 0; n < 2; ++n) {
        float gv = accg[m][n][j];
        float uv = accu[m][n][j];
        float sv = gv / (1.f + __expf(-gv));
        act[base + n*16 + lm] = f2b(sv * uv * pwv);
      }
    }
  }
}

// routed down: BM=128 BN=128 BK=32, atomic scatter (y pre-seeded with shared output)
__global__ __launch_bounds__(256) void down_routed_b(
    const ushort* __restrict__ act, const ushort* __restrict__ wdt,
    const int* __restrict__ pair_tok, const int* __restrict__ cnt, const int* __restrict__ offs,
    const int* __restrict__ tl_e, const int* __restrict__ tl_m, const int* __restrict__ ntl,
    float* __restrict__ y)
{
  __shared__ ushort A[2][128*32];
  __shared__ ushort Bd[2][128*32];

  int nact = ntl[0] * 16;
  int bid = blockIdx.x;
  if (bid >= nact) return;
  int wid = xcd_swz(bid, nact);
  int tile = wid >> 4;
  int nt = wid & 15;
  int e  = tl_e[tile];
  int m0 = tl_m[tile];
  int ce = cnt[e];
  int oe = offs[e];
  int n0 = nt * 128;
  int tid = threadIdx.x, lane = tid & 63, w = tid >> 6;

  int csrc = (lane & 3) ^ ((lane >> 3) & 3);
  const ushort* asrc[2];
  const ushort* bsrc[2];
  #pragma unroll
  for (int j = 0; j < 2; ++j) {
    int r = (2*w + j)*16 + (lane >> 2);
    int pi = min(m0 + r, ce - 1);
    asrc[j] = act + (size_t)(oe + pi) * FD + csrc * 8;
    bsrc[j] = wdt + ((size_t)e * HD + n0 + r) * FD + csrc * 8;
  }

  int lm = lane & 15, lg = lane >> 4;
  int wr = w >> 1, wc = w & 1;
  int asw = (lm >> 1) & 3;

  f32x4 acc[4][4];
  #pragma unroll
  for (int m = 0; m < 4; ++m)
    #pragma unroll
    for (int n = 0; n < 4; ++n) acc[m][n] = f32x4{0,0,0,0};

  #define DNB_ISSUE(T, BUF) do { \
    GLOAD_LDS16(asrc[0] + (T)*32, &A[BUF][(2*w)*512]); \
    GLOAD_LDS16(asrc[1] + (T)*32, &A[BUF][(2*w+1)*512]); \
    GLOAD_LDS16(bsrc[0] + (T)*32, &Bd[BUF][(2*w)*512]); \
    GLOAD_LDS16(bsrc[1] + (T)*32, &Bd[BUF][(2*w+1)*512]); \
  } while (0)

  DNB_ISSUE(0, 0);
  WAIT_VM0;
  __syncthreads();
  int cur = 0;
  for (int t = 0; t < 32; ++t) {
    if (t + 1 < 32) DNB_ISSUE(t + 1, cur ^ 1);
    bf16x8 a[4], b[4];
    #pragma unroll
    for (int m = 0; m < 4; ++m)
      a[m] = *(const bf16x8*)&A[cur][(wr*64 + m*16 + lm)*32 + (lg ^ asw)*8];
    #pragma unroll
    for (int n = 0; n < 4; ++n) {
      int row = wc*64 + n*16 + lm;
      b[n] = *(const bf16x8*)&Bd[cur][row*32 + (lg ^ asw)*8];
    }
    __builtin_amdgcn_s_setprio(1);
    #pragma unroll
    for (int m = 0; m < 4; ++m)
      #pragma unroll
      for (int n = 0; n < 4; ++n)
        acc[m][n] = __builtin_amdgcn_mfma_f32_16x16x32_bf16(a[m], b[n], acc[m][n], 0, 0, 0);
    __builtin_amdgcn_s_setprio(0);
    if (t + 1 < 32) WAIT_VM0;
    __syncthreads();
    cur ^= 1;
  }
  #undef DNB_ISSUE

  #pragma unroll
  for (int m = 0; m < 4; ++m) {
    #pragma unroll
    for (int j = 0; j < 4; ++j) {
      int rl = wr*64 + m*16 + lg*4 + j;
      int pi = m0 + rl;
      if (pi >= ce) continue;
      int tok = pair_tok[oe + pi];
      size_t base = (size_t)tok * HD + n0 + wc*64;
      #pragma unroll
      for (int n = 0; n < 4; ++n)
        atomicAdd(&y[base + n*16 + lm], acc[m][n][j]);
    }
  }
}

// shared gate+up
__global__ __launch_bounds__(256) void shared_gu_b(
    const ushort* __restrict__ xb, const ushort* __restrict__ sgb, const ushort* __restrict__ sub,
    ushort* __restrict__ sact)
{
  __shared__ ushort A[2][128*32];
  __shared__ ushort Bg[2][64*32];
  __shared__ ushort Bu[2][64*32];

  int bid = blockIdx.x;
  int wid = (bid & 7) * 64 + (bid >> 3);
  int mt = wid & 15;
  int nt = wid >> 4;
  int m0 = mt * 128;
  int n0 = nt * 64;
  int tid = threadIdx.x, lane = tid & 63, w = tid >> 6;

  int csrc = (lane & 3) ^ ((lane >> 3) & 3);
  const ushort* asrc[2];
  #pragma unroll
  for (int j = 0; j < 2; ++j) {
    int r = (2*w + j)*16 + (lane >> 2);
    asrc[j] = xb + (size_t)(m0 + r) * HD + csrc * 8;
  }
  int brow = w*16 + (lane >> 2);
  const ushort* bgsrc = sgb + (size_t)(n0 + brow) * HD + csrc * 8;
  const ushort* busrc = sub + (size_t)(n0 + brow) * HD + csrc * 8;

  int lm = lane & 15, lg = lane >> 4;
  int wr = w >> 1, wc = w & 1;
  int asw = (lm >> 1) & 3;

  f32x4 accg[4][2], accu[4][2];
  #pragma unroll
  for (int m = 0; m < 4; ++m)
    #pragma unroll
    for (int n = 0; n < 2; ++n) { accg[m][n] = f32x4{0,0,0,0}; accu[m][n] = f32x4{0,0,0,0}; }

  #define SGB_ISSUE(T, BUF) do { \
    GLOAD_LDS16(asrc[0] + (T)*32, &A[BUF][(2*w)*512]); \
    GLOAD_LDS16(asrc[1] + (T)*32, &A[BUF][(2*w+1)*512]); \
    GLOAD_LDS16(bgsrc + (T)*32, &Bg[BUF][w*512]); \
    GLOAD_LDS16(busrc + (T)*32, &Bu[BUF][w*512]); \
  } while (0)

  SGB_ISSUE(0, 0);
  WAIT_VM0;
  __syncthreads();
  int cur = 0;
  for (int t = 0; t < 64; ++t) {
    if (t + 1 < 64) SGB_ISSUE(t + 1, cur ^ 1);
    bf16x8 a[4], bg[2], bu[2];
    #pragma unroll
    for (int m = 0; m < 4; ++m)
      a[m] = *(const bf16x8*)&A[cur][(wr*64 + m*16 + lm)*32 + (lg ^ asw)*8];
    #pragma unroll
    for (int n = 0; n < 2; ++n) {
      int row = wc*32 + n*16 + lm;
      bg[n] = *(const bf16x8*)&Bg[cur][row*32 + (lg ^ asw)*8];
      bu[n] = *(const bf16x8*)&Bu[cur][row*32 + (lg ^ asw)*8];
    }
    __builtin_amdgcn_s_setprio(1);
    #pragma unroll
    for (int m = 0; m < 4; ++m)
      #pragma unroll
      for (int n = 0; n < 2; ++n) {
        accg[m][n] = __builtin_amdgcn_mfma_f32_16x16x32_bf16(a[m], bg[n], accg[m][n], 0, 0, 0);
        accu[m][n] = __builtin_amdgcn_mfma_f32_16x16x32_bf16(a[m], bu[n], accu[m][n], 0, 0, 0);
      }
    __builtin_amdgcn_s_setprio(0);
    if (t + 1 < 64) WAIT_VM0;
    __syncthreads();
    cur ^= 1;
  }
  #undef SGB_ISSUE

  #pragma unroll
  for (int m = 0; m < 4; ++m) {
    #pragma unroll
    for (int j = 0; j < 4; ++j) {
      int rl = wr*64 + m*16 + lg*4 + j;
      size_t base = (size_t)(m0 + rl) * SDIM + n0 + wc*32;
      #pragma unroll
      for (int n = 0; n < 2; ++n) {
        float gv = accg[m][n][j];
        float uv = accu[m][n][j];
        float sv = gv / (1.f + __expf(-gv));
        sact[base + n*16 + lm] = f2b(sv * uv);
      }
    }
  }
}

// shared down: STORES y (runs before routed down; saves memset + y read)
__global__ __launch_bounds__(256) void shared_down_b(
    const ushort* __restrict__ sact, const ushort* __restrict__ sdb, float* __restrict__ y)
{
  __shared__ ushort A[2][128*32];
  __shared__ ushort Bd[2][128*32];

  int bid = blockIdx.x;
  int wid = (bid & 7) * 32 + (bid >> 3);
  int mt = wid & 15;
  int nt = wid >> 4;
  int m0 = mt * 128;
  int n0 = nt * 128;
  int tid = threadIdx.x, lane = tid & 63, w = tid >> 6;

  int csrc = (lane & 3) ^ ((lane >> 3) & 3);
  const ushort* asrc[2];
  const ushort* bsrc[2];
  #pragma unroll
  for (int j = 0; j < 2; ++j) {
    int r = (2*w + j)*16 + (lane >> 2);
    asrc[j] = sact + (size_t)(m0 + r) * SDIM + csrc * 8;
    bsrc[j] = sdb + (size_t)(n0 + r) * SDIM + csrc * 8;
  }

  int lm = lane & 15, lg = lane >> 4;
  int wr = w >> 1, wc = w & 1;
  int asw = (lm >> 1) & 3;

  f32x4 acc[4][4];
  #pragma unroll
  for (int m = 0; m < 4; ++m)
    #pragma unroll
    for (int n = 0; n < 4; ++n) acc[m][n] = f32x4{0,0,0,0};

  #define SDB_ISSUE(T, BUF) do { \
    GLOAD_LDS16(asrc[0] + (T)*32, &A[BUF][(2*w)*512]); \
    GLOAD_LDS16(asrc[1] + (T)*32, &A[BUF][(2*w+1)*512]); \
    GLOAD_LDS16(bsrc[0] + (T)*32, &Bd[BUF][(2*w)*512]); \
    GLOAD_LDS16(bsrc[1] + (T)*32, &Bd[BUF][(2*w+1)*512]); \
  } while (0)

  SDB_ISSUE(0, 0);
  WAIT_VM0;
  __syncthreads();
  int cur = 0;
  for (int t = 0; t < 64; ++t) {
    if (t + 1 < 64) SDB_ISSUE(t + 1, cur ^ 1);
    bf16x8 a[4], b[4];
    #pragma unroll
    for (int m = 0; m < 4; ++m)
      a[m] = *(const bf16x8*)&A[cur][(wr*64 + m*16 + lm)*32 + (lg ^ asw)*8];
    #pragma unroll
    for (int n = 0; n < 4; ++n) {
      int row = wc*64 + n*16 + lm;
      b[n] = *(const bf16x8*)&Bd[cur][row*32 + (lg ^ asw)*8];
    }
    __builtin_amdgcn_s_setprio(1);
    #pragma unroll
    for (int m = 0; m < 4; ++m)
      #pragma unroll
      for (int n = 0; n < 4; ++n)
        acc[m][n] = __builtin_amdgcn_mfma_f32_16x16x32_bf16(a[m], b[n], acc[m][n], 0, 0, 0);
    __builtin_amdgcn_s_setprio(0);
    if (t + 1 < 64) WAIT_VM0;
    __syncthreads();
    cur ^= 1;
  }
  #undef SDB_ISSUE

  #pragma unroll
  for (int m = 0; m < 4; ++m) {
    #pragma unroll
    for (int j = 0; j < 4; ++j) {
      int rl = wr*64 + m*16 + lg*4 + j;
      size_t base = (size_t)(m0 + rl) * HD + n0 + wc*64;
      #pragma unroll
      for (int n = 0; n < 4; ++n)
        y[base + n*16 + lm] = acc[m][n][j];     // store, not +=
    }
  }
}

// ================= PATH B (fallback): inline fp32 B =================

__global__ __launch_bounds__(256) void gu_routed_f(
    const ushort* __restrict__ xb, const float* __restrict__ wg, const float* __restrict__ wu,
    const int* __restrict__ pair_tok, const float* __restrict__ pair_w,
    const int* __restrict__ cnt, const int* __restrict__ offs,
    ushort* __restrict__ act)
{
  __shared__ ushort A[2][128*32];
  __shared__ ushort Bg[2][64*BSTR];
  __shared__ ushort Bu[2][64*BSTR];

  int bid = blockIdx.x;
  int wid = (bid & 7) * 1024 + (bid >> 3);
  int mt = wid & 15;
  int nt = (wid >> 4) & 15;
  int e  = wid >> 8;
  int ce = cnt[e];
  int m0 = mt * 128;
  if (m0 >= ce) return;
  int oe = offs[e];
  int n0 = nt * 64;
  int tid = threadIdx.x, lane = tid & 63, w = tid >> 6;

  int csrc = (lane & 3) ^ ((lane >> 3) & 3);
  const ushort* asrc[2];
  #pragma unroll
  for (int j = 0; j < 2; ++j) {
    int r = (2*w + j)*16 + (lane >> 2);
    int pi = min(m0 + r, ce - 1);
    asrc[j] = xb + (size_t)pair_tok[oe + pi] * HD + csrc * 8;
  }
  int tsel = tid >> 7;
  int ttb = tid & 127;
  int fg = ttb & 15, hg = ttb >> 4;
  const float* wsrc = (tsel ? wu : wg) + (size_t)e * HD * FD + (size_t)hg*4*FD + n0 + fg*4;

  int lm = lane & 15, lg = lane >> 4;
  int wr = w >> 1, wc = w & 1;
  int asw = (lm >> 1) & 3;

  f32x4 accg[4][2], accu[4][2];
  #pragma unroll
  for (int m = 0; m < 4; ++m)
    #pragma unroll
    for (int n = 0; n < 2; ++n) { accg[m][n] = f32x4{0,0,0,0}; accu[m][n] = f32x4{0,0,0,0}; }

  float4 rB[4];
  #define GU_ISSUE(T, BUF) do { \
    _Pragma("unroll") \
    for (int j = 0; j < 2; ++j) \
      GLOAD_LDS16(asrc[j] + (T)*32, &A[BUF][(2*w+j)*512]); \
    const float* p = wsrc + (size_t)(T)*32*FD; \
    rB[0] = *(const float4*)(p); \
    rB[1] = *(const float4*)(p + FD); \
    rB[2] = *(const float4*)(p + 2*FD); \
    rB[3] = *(const float4*)(p + 3*FD); \
  } while (0)
  #define GU_WRITE(BUF) do { \
    ushort* dst = tsel ? &Bu[BUF][0] : &Bg[BUF][0]; \
    _Pragma("unroll") \
    for (int c = 0; c < 4; ++c) { \
      int row = fg*4 + ((c + fg) & 3); \
      *(ushort4*)&dst[row*BSTR + hg*4] = \
        make_ushort4(f2b(rB[0][c]), f2b(rB[1][c]), f2b(rB[2][c]), f2b(rB[3][c])); \
    } \
  } while (0)

  GU_ISSUE(0, 0);
  WAIT_VM0;
  GU_WRITE(0);
  __syncthreads();

  int cur = 0;
  for (int t = 0; t < HD/32; ++t) {
    if (t + 1 < HD/32) GU_ISSUE(t + 1, cur ^ 1);
    bf16x8 a[4], bg[2], bu[2];
    #pragma unroll
    for (int m = 0; m < 4; ++m)
      a[m] = *(const bf16x8*)&A[cur][(wr*64 + m*16 + lm)*32 + (lg ^ asw)*8];
    #pragma unroll
    for (int n = 0; n < 2; ++n) {
      int row = prow(wc*32 + n*16 + lm);
      bg[n] = *(const bf16x8*)&Bg[cur][row*BSTR + lg*8];
      bu[n] = *(const bf16x8*)&Bu[cur][row*BSTR + lg*8];
    }
    #pragma unroll
    for (int m = 0; m < 4; ++m)
      #pragma unroll
      for (int n = 0; n < 2; ++n) {
        accg[m][n] = __builtin_amdgcn_mfma_f32_16x16x32_bf16(a[m], bg[n], accg[m][n], 0, 0, 0);
        accu[m][n] = __builtin_amdgcn_mfma_f32_16x16x32_bf16(a[m], bu[n], accu[m][n], 0, 0, 0);
      }
    if (t + 1 < HD/32) {
      WAIT_VM0;
      GU_WRITE(cur ^ 1);
    }
    __syncthreads();
    cur ^= 1;
  }
  #undef GU_ISSUE
  #undef GU_WRITE

  #pragma unroll
  for (int m = 0; m < 4; ++m) {
    #pragma unroll
    for (int j = 0; j < 4; ++j) {
      int rl = wr*64 + m*16 + lg*4 + j;
      int pi = m0 + rl;
      if (pi >= ce) continue;
      float pwv = pair_w[oe + pi];
      size_t base = (size_t)(oe + pi) * FD + n0 + wc*32;
      #pragma unroll
      for (int n = 0; n < 2; ++n) {
        float gv = accg[m][n][j];
        float uv = accu[m][n][j];
        float sv = gv / (1.f + __expf(-gv));
        act[base + n*16 + lm] = f2b(sv * uv * pwv);
      }
    }
  }
}

__global__ __launch_bounds__(256) void down_routed_f(
    const ushort* __restrict__ act, const float* __restrict__ wd,
    const int* __restrict__ pair_tok, const int* __restrict__ cnt, const int* __restrict__ offs,
    float* __restrict__ y)
{
  __shared__ ushort A[2][128*32];
  __shared__ ushort Bd[2][128*BSTR];

  int bid = blockIdx.x;
  int wid = (bid & 7) * 1024 + (bid >> 3);
  int mt = wid & 15;
  int nt = (wid >> 4) & 15;
  int e  = wid >> 8;
  int ce = cnt[e];
  int m0 = mt * 128;
  if (m0 >= ce) return;
  int oe = offs[e];
  int n0 = nt * 128;
  int tid = threadIdx.x, lane = tid & 63, w = tid >> 6;

  int csrc = (lane & 3) ^ ((lane >> 3) & 3);
  const ushort* asrc[2];
  #pragma unroll
  for (int j = 0; j < 2; ++j) {
    int r = (2*w + j)*16 + (lane >> 2);
    int pi = min(m0 + r, ce - 1);
    asrc[j] = act + (size_t)(oe + pi) * FD + csrc * 8;
  }
  int fg = tid & 31, hg = tid >> 5;
  const float* wsrc = wd + (size_t)e * FD * HD + (size_t)hg*4*HD + n0 + fg*4;

  int lm = lane & 15, lg = lane >> 4;
  int wr = w >> 1, wc = w & 1;
  int asw = (lm >> 1) & 3;

  f32x4 acc[4][4];
  #pragma unroll
  for (int m = 0; m < 4; ++m)
    #pragma unroll
    for (int n = 0; n < 4; ++n) acc[m][n] = f32x4{0,0,0,0};

  float4 rB[4];
  #define DN_ISSUE(T, BUF) do { \
    _Pragma("unroll") \
    for (int j = 0; j < 2; ++j) \
      GLOAD_LDS16(asrc[j] + (T)*32, &A[BUF][(2*w+j)*512]); \
    const float* p = wsrc + (size_t)(T)*32*HD; \
    rB[0] = *(const float4*)(p); \
    rB[1] = *(const float4*)(p + HD); \
    rB[2] = *(const float4*)(p + 2*HD); \
    rB[3] = *(const float4*)(p + 3*HD); \
  } while (0)
  #define DN_WRITE(BUF) do { \
    _Pragma("unroll") \
    for (int c = 0; c < 4; ++c) { \
      int row = fg*4 + ((c + fg) & 3); \
      *(ushort4*)&Bd[BUF][row*BSTR + hg*4] = \
        make_ushort4(f2b(rB[0][c]), f2b(rB[1][c]), f2b(rB[2][c]), f2b(rB[3][c])); \
    } \
  } while (0)

  DN_ISSUE(0, 0);
  WAIT_VM0;
  DN_WRITE(0);
  __syncthreads();

  int cur = 0;
  for (int t = 0; t < FD/32; ++t) {
    if (t + 1 < FD/32) DN_ISSUE(t + 1, cur ^ 1);
    bf16x8 a[4], b[4];
    #pragma unroll
    for (int m = 0; m < 4; ++m)
      a[m] = *(const bf16x8*)&A[cur][(wr*64 + m*16 + lm)*32 + (lg ^ asw)*8];
    #pragma unroll
    for (int n = 0; n < 4; ++n) {
      int row = prow(wc*64 + n*16 + lm);
      b[n] = *(const bf16x8*)&Bd[cur][row*BSTR + lg*8];
    }
    #pragma unroll
    for (int m = 0; m < 4; ++m)
      #pragma unroll
      for (int n = 0; n < 4; ++n)
        acc[m][n] = __builtin_amdgcn_mfma_f32_16x16x32_bf16(a[m], b[n], acc[m][n], 0, 0, 0);
    if (t + 1 < FD/32) {
      WAIT_VM0;
      DN_WRITE(cur ^ 1);
    }
    __syncthreads();
    cur ^= 1;
  }
  #undef DN_ISSUE
  #undef DN_WRITE

  #pragma unroll
  for (int m = 0; m < 4; ++m) {
    #pragma unroll
    for (int j = 0; j < 4; ++j) {
      int rl = wr*64 + m*16 + lg*4 + j;
      int pi = m0 + rl;
      if (pi >= ce) continue;
      int tok = pair_tok[oe + pi];
      size_t base = (size_t)tok * HD + n0 + wc*64;
      #pragma unroll
      for (int n = 0; n < 4; ++n)
        atomicAdd(&y[base + n*16 + lm], acc[m][n][j]);
    }
  }
}

__global__ __launch_bounds__(256) void shared_gu_f(
    const ushort* __restrict__ xb, const float* __restrict__ sg, const float* __restrict__ su,
    ushort* __restrict__ sact)
{
  __shared__ ushort A[2][128*32];
  __shared__ ushort Bg[2][64*BSTR];
  __shared__ ushort Bu[2][64*BSTR];

  int bid = blockIdx.x;
  int wid = (bid & 7) * 64 + (bid >> 3);
  int mt = wid & 15;
  int nt = wid >> 4;
  int m0 = mt * 128;
  int n0 = nt * 64;
  int tid = threadIdx.x, lane = tid & 63, w = tid >> 6;

  int csrc = (lane & 3) ^ ((lane >> 3) & 3);
  const ushort* asrc[2];
  #pragma unroll
  for (int j = 0; j < 2; ++j) {
    int r = (2*w + j)*16 + (lane >> 2);
    asrc[j] = xb + (size_t)(m0 + r) * HD + csrc * 8;
  }
  int tsel = tid >> 7;
  int ttb = tid & 127;
  int bn = ttb >> 1, bsub = ttb & 1;
  const float* bsrc = (tsel ? su : sg) + (size_t)(n0 + bn) * HD + bsub * 16;

  int lm = lane & 15, lg = lane >> 4;
  int wr = w >> 1, wc = w & 1;
  int asw = (lm >> 1) & 3;

  f32x4 accg[4][2], accu[4][2];
  #pragma unroll
  for (int m = 0; m < 4; ++m)
    #pragma unroll
    for (int n = 0; n < 2; ++n) { accg[m][n] = f32x4{0,0,0,0}; accu[m][n] = f32x4{0,0,0,0}; }

  float4 rB[4];
  #define SG_ISSUE(T, BUF) do { \
    _Pragma("unroll") \
    for (int j = 0; j < 2; ++j) \
      GLOAD_LDS16(asrc[j] + (T)*32, &A[BUF][(2*w+j)*512]); \
    const float* p = bsrc + (T)*32; \
    rB[0] = *(const float4*)(p); \
    rB[1] = *(const float4*)(p + 4); \
    rB[2] = *(const float4*)(p + 8); \
    rB[3] = *(const float4*)(p + 12); \
  } while (0)
  #define SG_WRITE(BUF) do { \
    ushort* dst = (tsel ? &Bu[BUF][0] : &Bg[BUF][0]) + bn*BSTR + bsub*16; \
    dst[0]=f2b(rB[0][0]); dst[1]=f2b(rB[0][1]); dst[2]=f2b(rB[0][2]); dst[3]=f2b(rB[0][3]); \
    dst[4]=f2b(rB[1][0]); dst[5]=f2b(rB[1][1]); dst[6]=f2b(rB[1][2]); dst[7]=f2b(rB[1][3]); \
    dst[8]=f2b(rB[2][0]); dst[9]=f2b(rB[2][1]); dst[10]=f2b(rB[2][2]); dst[11]=f2b(rB[2][3]); \
    dst[12]=f2b(rB[3][0]); dst[13]=f2b(rB[3][1]); dst[14]=f2b(rB[3][2]); dst[15]=f2b(rB[3][3]); \
  } while (0)

  SG_ISSUE(0, 0);
  WAIT_VM0;
  SG_WRITE(0);
  __syncthreads();

  int cur = 0;
  for (int t = 0; t < HD/32; ++t) {
    if (t + 1 < HD/32) SG_ISSUE(t + 1, cur ^ 1);
    bf16x8 a[4], bg[2], bu[2];
    #pragma unroll
    for (int m = 0; m < 4; ++m)
      a[m] = *(const bf16x8*)&A[cur][(wr*64 + m*16 + lm)*32 + (lg ^ asw)*8];
    #pragma unroll
    for (int n = 0; n < 2; ++n) {
      int row = wc*32 + n*16 + lm;
      bg[n] = *(const bf16x8*)&Bg[cur][row*BSTR + lg*8];
      bu[n] = *(const bf16x8*)&Bu[cur][row*BSTR + lg*8];
    }
    #pragma unroll
    for (int m = 0; m < 4; ++m)
      #pragma unroll
      for (int n = 0; n < 2; ++n) {
        accg[m][n] = __builtin_amdgcn_mfma_f32_16x16x32_bf16(a[m], bg[n], accg[m][n], 0, 0, 0);
        accu[m][n] = __builtin_amdgcn_mfma_f32_16x16x32_bf16(a[m], bu[n], accu[m][n], 0, 0, 0);
      }
    if (t + 1 < HD/32) {
      WAIT_VM0;
      SG_WRITE(cur ^ 1);
    }
    __syncthreads();
    cur ^= 1;
  }
  #undef SG_ISSUE
  #undef SG_WRITE

  #pragma unroll
  for (int m = 0; m < 4; ++m) {
    #pragma unroll
    for (int j = 0; j < 4; ++j) {
      int rl = wr*64 + m*16 + lg*4 + j;
      size_t base = (size_t)(m0 + rl) * SDIM + n0 + wc*32;
      #pragma unroll
      for (int n = 0; n < 2; ++n) {
        float gv = accg[m][n][j];
        float uv = accu[m][n][j];
        float sv = gv / (1.f + __expf(-gv));
        sact[base + n*16 + lm] = f2b(sv * uv);
      }
    }
  }
}

__global__ __launch_bounds__(256) void shared_down_f(
    const ushort* __restrict__ sact, const float* __restrict__ sd, float* __restrict__ y)
{
  __shared__ ushort A[2][128*32];
  __shared__ ushort Bd[2][128*BSTR];

  int bid = blockIdx.x;
  int wid = (bid & 7) * 32 + (bid >> 3);
  int mt = wid & 15;
  int nt = wid >> 4;
  int m0 = mt * 128;
  int n0 = nt * 128;
  int tid = threadIdx.x, lane = tid & 63, w = tid >> 6;

  int csrc = (lane & 3) ^ ((lane >> 3) & 3);
  const ushort* asrc[2];
  #pragma unroll
  for (int j = 0; j < 2; ++j) {
    int r = (2*w + j)*16 + (lane >> 2);
    asrc[j] = sact + (size_t)(m0 + r) * SDIM + csrc * 8;
  }
  int bn = tid >> 1, bsub = tid & 1;
  const float* bsrc = sd + (size_t)(n0 + bn) * SDIM + bsub * 16;

  int lm = lane & 15, lg = lane >> 4;
  int wr = w >> 1, wc = w & 1;
  int asw = (lm >> 1) & 3;

  f32x4 acc[4][4];
  #pragma unroll
  for (int m = 0; m < 4; ++m)
    #pragma unroll
    for (int n = 0; n < 4; ++n) acc[m][n] = f32x4{0,0,0,0};

  float4 rB[4];
  #define SD_ISSUE(T, BUF) do { \
    _Pragma("unroll") \
    for (int j = 0; j < 2; ++j) \
      GLOAD_LDS16(asrc[j] + (T)*32, &A[BUF][(2*w+j)*512]); \
    const float* p = bsrc + (T)*32; \
    rB[0] = *(const float4*)(p); \
    rB[1] = *(const float4*)(p + 4); \
    rB[2] = *(const float4*)(p + 8); \
    rB[3] = *(const float4*)(p + 12); \
  } while (0)
  #define SD_WRITE(BUF) do { \
    ushort* dst = &Bd[BUF][bn*BSTR + bsub*16]; \
    dst[0]=f2b(rB[0][0]); dst[1]=f2b(rB[0][1]); dst[2]=f2b(rB[0][2]); dst[3]=f2b(rB[0][3]); \
    dst[4]=f2b(rB[1][0]); dst[5]=f2b(rB[1][1]); dst[6]=f2b(rB[1][2]); dst[7]=f2b(rB[1][3]); \
    dst[8]=f2b(rB[2][0]); dst[9]=f2b(rB[2][1]); dst[10]=f2b(rB[2][2]); dst[11]=f2b(rB[2][3]); \
    dst[12]=f2b(rB[3][0]); dst[13]=f2b(rB[3][1]); dst[14]=f2b(rB[3][2]); dst[15]=f2b(rB[3][3]); \
  } while (0)

  SD_ISSUE(0, 0);
  WAIT_VM0;
  SD_WRITE(0);
  __syncthreads();

  int cur = 0;
  for (int t = 0; t < SDIM/32; ++t) {
    if (t + 1 < SDIM/32) SD_ISSUE(t + 1, cur ^ 1);
    bf16x8 a[4], b[4];
    #pragma unroll
    for (int m = 0; m < 4; ++m)
      a[m] = *(const bf16x8*)&A[cur][(wr*64 + m*16 + lm)*32 + (lg ^ asw)*8];
    #pragma unroll
    for (int n = 0; n < 4; ++n) {
      int row = wc*64 + n*16 + lm;
      b[n] = *(const bf16x8*)&Bd[cur][row*BSTR + lg*8];
    }
    #pragma unroll
    for (int m = 0; m < 4; ++m)
      #pragma unroll
      for (int n = 0; n < 4; ++n)
        acc[m][n] = __builtin_amdgcn_mfma_f32_16x16x32_bf16(a[m], b[n], acc[m][n], 0, 0, 0);
    if (t + 1 < SDIM/32) {
      WAIT_VM0;
      SD_WRITE(cur ^ 1);
    }
    __syncthreads();
    cur ^= 1;
  }
  #undef SD_ISSUE
  #undef SD_WRITE

  #pragma unroll
  for (int m = 0; m < 4; ++m) {
    #pragma unroll
    for (int j = 0; j < 4; ++j) {
      int rl = wr*64 + m*16 + lg*4 + j;
      size_t base = (size_t)(m0 + rl) * HD + n0 + wc*64;
      #pragma unroll
      for (int n = 0; n < 4; ++n)
        y[base + n*16 + lm] += acc[m][n][j];
    }
  }
}

// ---------------- launch ----------------
extern "C" void kernel_launch(void* const* d_in, const int* in_sizes, int n_in,
                              void* d_out, int out_size, void* d_ws, size_t ws_size,
                              hipStream_t stream) {
  const float* x     = (const float*)d_in[0];
  const float* wgate = (const float*)d_in[1];
  const float* wg    = (const float*)d_in[2];
  const float* wu    = (const float*)d_in[3];
  const float* wd    = (const float*)d_in[4];
  const float* sg    = (const float*)d_in[5];
  const float* su    = (const float*)d_in[6];
  const float* sd    = (const float*)d_in[7];
  float* y = (float*)d_out;
  char* ws = (char*)d_ws;

  ushort* xb   = (ushort*)(ws + 0);
  ushort* act  = (ushort*)(ws + 8388608);
  ushort* sact = (ushort*)(ws + 33554432);
  int*    tidx = (int*)  (ws + 41943040);
  float*  tw   = (float*)(ws + 41992192);
  int*    ptok = (int*)  (ws + 42041344);
  float*  pw   = (float*)(ws + 42090496);
  int*    cnt  = (int*)  (ws + 42139648);
  int*    curc = (int*)  (ws + 42139776);
  int*    offs = (int*)  (ws + 42139904);
  int*    tl_e = (int*)  (ws + 42140160);
  int*    tl_m = (int*)  (ws + 42140672);
  int*    ntl  = (int*)  (ws + 42141184);
  ushort* wgt  = (ushort*)(ws + 50331648);    // 128 MB [E][F][H]
  ushort* wut  = (ushort*)(ws + 184549376);   // 128 MB
  ushort* wdt  = (ushort*)(ws + 318767104);   // 128 MB [E][H][F]
  ushort* sgb  = (ushort*)(ws + 452984832);   // 8 MB
  ushort* sub  = (ushort*)(ws + 461373440);
  ushort* sdb  = (ushort*)(ws + 469762048);
  const size_t WS_NEED = 478150656ULL;

  hipMemsetAsync(cnt, 0, 512, stream);

  cvt_kernel<<<dim3(4096), dim3(256), 0, stream>>>(x, xb);
  gating_kernel<<<dim3(TT), dim3(64), 0, stream>>>(x, wgate, tidx, tw, cnt);
  scan_kernel<<<dim3(1), dim3(64), 0, stream>>>(cnt, offs, tl_e, tl_m, ntl);
  fill_kernel<<<dim3(48), dim3(256), 0, stream>>>(tidx, tw, offs, curc, ptok, pw);

  if (ws_size >= WS_NEED) {
    tconv<<<dim3(512, NEXP), dim3(256), 0, stream>>>(wg, wgt, HD, FD);   // [H][F] -> [F][H]
    tconv<<<dim3(512, NEXP), dim3(256), 0, stream>>>(wu, wut, HD, FD);
    tconv<<<dim3(512, NEXP), dim3(256), 0, stream>>>(wd, wdt, FD, HD);   // [F][H] -> [H][F]
    fconv<<<dim3(4096), dim3(256), 0, stream>>>(sg, sgb);
    fconv<<<dim3(4096), dim3(256), 0, stream>>>(su, sub);
    fconv<<<dim3(4096), dim3(256), 0, stream>>>(sd, sdb);

    // shared first: shared_down stores y, then routed down accumulates atomically
    shared_gu_b<<<dim3(512), dim3(256), 0, stream>>>(xb, sgb, sub, sact);
    shared_down_b<<<dim3(256), dim3(256), 0, stream>>>(sact, sdb, y);
    gu_routed_b<<<dim3(2048), dim3(256), 0, stream>>>(xb, wgt, wut, ptok, pw, cnt, offs,
                                                      tl_e, tl_m, ntl, act);
    down_routed_b<<<dim3(2048), dim3(256), 0, stream>>>(act, wdt, ptok, cnt, offs,
                                                        tl_e, tl_m, ntl, y);
  } else {
    hipMemsetAsync(d_out, 0, (size_t)TT * HD * 4, stream);
    gu_routed_f<<<dim3(8192), dim3(256), 0, stream>>>(xb, wg, wu, ptok, pw, cnt, offs, act);
    down_routed_f<<<dim3(8192), dim3(256), 0, stream>>>(act, wd, ptok, cnt, offs, y);
    shared_gu_f<<<dim3(512), dim3(256), 0, stream>>>(xb, sg, su, sact);
    shared_down_f<<<dim3(256), dim3(256), 0, stream>>>(sact, sd, y);
  }
}

// Round 8
// 848.018 us; speedup vs baseline: 1.0735x; 1.0319x over previous
//
#include <hip/hip_runtime.h>

#define HD   2048
#define FD   1024
#define NEXP 32
#define TOPK 6
#define TT   2048
#define SDIM 2048
#define NPAIR (TT*TOPK)

typedef __bf16 bf16x8 __attribute__((ext_vector_type(8)));
typedef float  f32x4  __attribute__((ext_vector_type(4)));

#define GLOAD_LDS16(g, l) __builtin_amdgcn_global_load_lds( \
    (const __attribute__((address_space(1))) void*)(g),     \
    (__attribute__((address_space(3))) void*)(l), 16, 0, 0)

#define WAIT_VM4  asm volatile("s_waitcnt vmcnt(4)" ::: "memory")
#define WAIT_VM0  asm volatile("s_waitcnt vmcnt(0)" ::: "memory")

__device__ __forceinline__ ushort f2b(float f) {
  __bf16 h = (__bf16)f;
  union { __bf16 h; ushort u; } v; v.h = h;
  return v.u;
}

// bijective XCD swizzle over nact active blocks (m204)
__device__ __forceinline__ int xcd_swz(int bid, int nact) {
  int xcd = bid & 7, i = bid >> 3;
  int q = nact >> 3, r = nact & 7;
  int base = (xcd < r) ? xcd * (q + 1) : r * (q + 1) + (xcd - r) * q;
  return base + i;
}

// ---------------- gating (fp32 exact) ----------------
__device__ __forceinline__ void argmax32(float &v, int &i) {
  #pragma unroll
  for (int m = 16; m >= 1; m >>= 1) {
    float ov = __shfl_xor(v, m, 32);
    int   oi = __shfl_xor(i, m, 32);
    if (ov > v || (ov == v && oi < i)) { v = ov; i = oi; }
  }
}

__global__ __launch_bounds__(64) void gating_kernel(
    const float* __restrict__ x, const float* __restrict__ wgate,
    int* __restrict__ topk_idx, float* __restrict__ topk_w, int* __restrict__ cnt)
{
  int t = blockIdx.x;
  int l = threadIdx.x;
  int e = l & 31;
  int half = l >> 5;
  const float* xr = x + (size_t)t * HD + half * (HD/2);
  const float* wr = wgate + (size_t)e * HD + half * (HD/2);
  float acc = 0.f;
  for (int i = 0; i < HD/2; i += 4) {
    float4 a = *(const float4*)(xr + i);
    float4 b = *(const float4*)(wr + i);
    acc += a.x*b.x + a.y*b.y + a.z*b.z + a.w*b.w;
  }
  acc += __shfl_xor(acc, 32);
  float logit = acc;
  float mx = logit;
  #pragma unroll
  for (int m = 16; m >= 1; m >>= 1) mx = fmaxf(mx, __shfl_xor(mx, m, 32));
  float p = __expf(logit - mx);
  float s = p;
  #pragma unroll
  for (int m = 16; m >= 1; m >>= 1) s += __shfl_xor(s, m, 32);
  float score = p / s;
  float gs = score;
  gs = fmaxf(gs, __shfl_xor(gs, 1, 32));
  gs = fmaxf(gs, __shfl_xor(gs, 2, 32));
  int g = e >> 2;
  float gw = gs;
  bool ingroup = false;
  for (int r = 0; r < 3; ++r) {
    float v = gw; int gi = g;
    argmax32(v, gi);
    if (g == gi) { ingroup = true; gw = -1.f; }
  }
  float ms = ingroup ? score : 0.f;
  int myrank = -1;
  float denom = 1e-20f;
  float mw = ms;
  for (int r = 0; r < 6; ++r) {
    float v = mw; int ei = e;
    argmax32(v, ei);
    denom += v;
    if (e == ei) { myrank = r; mw = -1.f; }
  }
  if (l < 32 && myrank >= 0) {
    topk_idx[t*TOPK + myrank] = e;
    topk_w  [t*TOPK + myrank] = score / denom;
    atomicAdd(&cnt[e], 1);
  }
}

__global__ void scan_kernel(const int* __restrict__ cnt, int* __restrict__ offs,
                            int* __restrict__ tl_e, int* __restrict__ tl_m, int* __restrict__ ntl) {
  if (threadIdx.x == 0) {
    int o = 0, nt = 0;
    for (int e = 0; e < NEXP; ++e) {
      offs[e] = o;
      for (int m = 0; m < cnt[e]; m += 128) { tl_e[nt] = e; tl_m[nt] = m; ++nt; }
      o += cnt[e];
    }
    ntl[0] = nt;
  }
}

__global__ void fill_kernel(const int* __restrict__ topk_idx, const float* __restrict__ topk_w,
                            const int* __restrict__ offs, int* __restrict__ cur,
                            int* __restrict__ pair_tok, float* __restrict__ pair_w)
{
  int idx = blockIdx.x * blockDim.x + threadIdx.x;
  if (idx >= NPAIR) return;
  int e = topk_idx[idx];
  int p = offs[e] + atomicAdd(&cur[e], 1);
  pair_tok[p] = idx / TOPK;
  pair_w[p]   = topk_w[idx];
}

__global__ void cvt_kernel(const float* __restrict__ x, ushort* __restrict__ xb) {
  int i = blockIdx.x * blockDim.x + threadIdx.x;
  float4 v = ((const float4*)x)[i];
  ((ushort4*)xb)[i] = make_ushort4(f2b(v.x), f2b(v.y), f2b(v.z), f2b(v.w));
}

__global__ __launch_bounds__(256) void fconv(const float* __restrict__ in, ushort* __restrict__ out) {
  int i = blockIdx.x * blockDim.x + threadIdx.x;
  float4 v = ((const float4*)in)[i];
  ((ushort4*)out)[i] = make_ushort4(f2b(v.x), f2b(v.y), f2b(v.z), f2b(v.w));
}

// transpose-convert: in [R][C] fp32 -> out [C][R] bf16. 64x64 tiles.
#define TSTR 76
__global__ __launch_bounds__(256) void tconv(const float* __restrict__ in, ushort* __restrict__ out,
                                             int R, int C) {
  __shared__ ushort T[64*TSTR];
  int tiles_c = C >> 6;
  int bt = blockIdx.x;
  int r0 = (bt / tiles_c) << 6;
  int c0 = (bt % tiles_c) << 6;
  const float* src = in + (size_t)blockIdx.y * R * C;
  ushort* dst = out + (size_t)blockIdx.y * R * C;
  int t = threadIdx.x;
  int row = (t >> 4) << 2;
  int col4 = (t & 15) << 2;
  float vv[4][4];
  #pragma unroll
  for (int i = 0; i < 4; ++i) {
    float4 v = *(const float4*)(src + (size_t)(r0 + row + i) * C + c0 + col4);
    vv[i][0] = v.x; vv[i][1] = v.y; vv[i][2] = v.z; vv[i][3] = v.w;
  }
  #pragma unroll
  for (int cc = 0; cc < 4; ++cc)
    *(ushort4*)&T[(col4 + cc)*TSTR + row] =
      make_ushort4(f2b(vv[0][cc]), f2b(vv[1][cc]), f2b(vv[2][cc]), f2b(vv[3][cc]));
  __syncthreads();
  int oc = t >> 2;
  int ok = (t & 3) << 4;
  ushort4 a0 = *(const ushort4*)&T[oc*TSTR + ok];
  ushort4 a1 = *(const ushort4*)&T[oc*TSTR + ok + 4];
  ushort4 a2 = *(const ushort4*)&T[oc*TSTR + ok + 8];
  ushort4 a3 = *(const ushort4*)&T[oc*TSTR + ok + 12];
  ushort* d = dst + (size_t)(c0 + oc) * R + r0 + ok;
  *(ushort4*)(d)      = a0;
  *(ushort4*)(d + 4)  = a1;
  *(ushort4*)(d + 8)  = a2;
  *(ushort4*)(d + 12) = a3;
}

// ============ all-bf16 GEMMs, depth-2 counted-vmcnt pipeline ============

// routed gate+up: BM=128 BN=64(x2) BK=32, 3-buf LDS, vmcnt(4)
__global__ __launch_bounds__(256) void gu_routed_b(
    const ushort* __restrict__ xb, const ushort* __restrict__ wgt, const ushort* __restrict__ wut,
    const int* __restrict__ pair_tok, const float* __restrict__ pair_w,
    const int* __restrict__ cnt, const int* __restrict__ offs,
    const int* __restrict__ tl_e, const int* __restrict__ tl_m, const int* __restrict__ ntl,
    ushort* __restrict__ act)
{
  __shared__ ushort A[3][128*32];
  __shared__ ushort Bg[3][64*32];
  __shared__ ushort Bu[3][64*32];

  int nact = ntl[0] * 16;
  int bid = blockIdx.x;
  if (bid >= nact) return;
  int wid = xcd_swz(bid, nact);
  int tile = wid >> 4;
  int nt = wid & 15;
  int e  = tl_e[tile];
  int m0 = tl_m[tile];
  int ce = cnt[e];
  int oe = offs[e];
  int n0 = nt * 64;
  int tid = threadIdx.x, lane = tid & 63, w = tid >> 6;

  int csrc = (lane & 3) ^ ((lane >> 3) & 3);
  const ushort* asrc[2];
  #pragma unroll
  for (int j = 0; j < 2; ++j) {
    int r = (2*w + j)*16 + (lane >> 2);
    int pi = min(m0 + r, ce - 1);
    asrc[j] = xb + (size_t)pair_tok[oe + pi] * HD + csrc * 8;
  }
  int brow = w*16 + (lane >> 2);
  const ushort* bgsrc = wgt + ((size_t)e * FD + n0 + brow) * HD + csrc * 8;
  const ushort* busrc = wut + ((size_t)e * FD + n0 + brow) * HD + csrc * 8;

  int lm = lane & 15, lg = lane >> 4;
  int wr = w >> 1, wc = w & 1;
  int asw = (lm >> 1) & 3;

  f32x4 accg[4][2], accu[4][2];
  #pragma unroll
  for (int m = 0; m < 4; ++m)
    #pragma unroll
    for (int n = 0; n < 2; ++n) { accg[m][n] = f32x4{0,0,0,0}; accu[m][n] = f32x4{0,0,0,0}; }

  #define GUB_ISSUE(T, BUF) do { \
    GLOAD_LDS16(asrc[0] + (T)*32, &A[BUF][(2*w)*512]); \
    GLOAD_LDS16(asrc[1] + (T)*32, &A[BUF][(2*w+1)*512]); \
    GLOAD_LDS16(bgsrc + (T)*32, &Bg[BUF][w*512]); \
    GLOAD_LDS16(busrc + (T)*32, &Bu[BUF][w*512]); \
  } while (0)
  #define GUB_COMPUTE(BUF) do { \
    bf16x8 a[4], bg[2], bu[2]; \
    _Pragma("unroll") \
    for (int m = 0; m < 4; ++m) \
      a[m] = *(const bf16x8*)&A[BUF][(wr*64 + m*16 + lm)*32 + (lg ^ asw)*8]; \
    _Pragma("unroll") \
    for (int n = 0; n < 2; ++n) { \
      int row = wc*32 + n*16 + lm; \
      bg[n] = *(const bf16x8*)&Bg[BUF][row*32 + (lg ^ asw)*8]; \
      bu[n] = *(const bf16x8*)&Bu[BUF][row*32 + (lg ^ asw)*8]; \
    } \
    _Pragma("unroll") \
    for (int m = 0; m < 4; ++m) \
      _Pragma("unroll") \
      for (int n = 0; n < 2; ++n) { \
        accg[m][n] = __builtin_amdgcn_mfma_f32_16x16x32_bf16(a[m], bg[n], accg[m][n], 0, 0, 0); \
        accu[m][n] = __builtin_amdgcn_mfma_f32_16x16x32_bf16(a[m], bu[n], accu[m][n], 0, 0, 0); \
      } \
  } while (0)
  #define GUB_STEP(T, CB, IB, DOISS) do { \
    if (DOISS) GUB_ISSUE((T)+2, IB); \
    GUB_COMPUTE(CB); \
    if (DOISS) { WAIT_VM4; } else { WAIT_VM0; } \
    __syncthreads(); \
  } while (0)

  GUB_ISSUE(0, 0);
  GUB_ISSUE(1, 1);
  WAIT_VM4;
  __syncthreads();

  for (int tt = 0; tt < 20; ++tt) {
    int t = tt * 3;
    GUB_STEP(t,   0, 2, 1);
    GUB_STEP(t+1, 1, 0, 1);
    GUB_STEP(t+2, 2, 1, 1);
  }
  GUB_STEP(60, 0, 2, 1);
  GUB_STEP(61, 1, 0, 1);
  GUB_STEP(62, 2, 0, 0);
  GUB_COMPUTE(0);     // t=63
  #undef GUB_ISSUE
  #undef GUB_COMPUTE
  #undef GUB_STEP

  #pragma unroll
  for (int m = 0; m < 4; ++m) {
    #pragma unroll
    for (int j = 0; j < 4; ++j) {
      int rl = wr*64 + m*16 + lg*4 + j;
      int pi = m0 + rl;
      if (pi >= ce) continue;
      float pwv = pair_w[oe + pi];
      size_t base = (size_t)(oe + pi) * FD + n0 + wc*32;
      #pragma unroll
      for (int n = 0; n < 2; ++n) {
        float gv = accg[m][n][j];
        float uv = accu[m][n][j];
        float sv = gv / (1.f + __expf(-gv));
        act[base + n*16 + lm] = f2b(sv * uv * pwv);
      }
    }
  }
}

// routed down: BM=128 BN=128 BK=32, 3-buf, atomic scatter (y pre-seeded)
__global__ __launch_bounds__(256) void down_routed_b(
    const ushort* __restrict__ act, const ushort* __restrict__ wdt,
    const int* __restrict__ pair_tok, const int* __restrict__ cnt, const int* __restrict__ offs,
    const int* __restrict__ tl_e, const int* __restrict__ tl_m, const int* __restrict__ ntl,
    float* __restrict__ y)
{
  __shared__ ushort A[3][128*32];
  __shared__ ushort Bd[3][128*32];

  int nact = ntl[0] * 16;
  int bid = blockIdx.x;
  if (bid >= nact) return;
  int wid = xcd_swz(bid, nact);
  int tile = wid >> 4;
  int nt = wid & 15;
  int e  = tl_e[tile];
  int m0 = tl_m[tile];
  int ce = cnt[e];
  int oe = offs[e];
  int n0 = nt * 128;
  int tid = threadIdx.x, lane = tid & 63, w = tid >> 6;

  int csrc = (lane & 3) ^ ((lane >> 3) & 3);
  const ushort* asrc[2];
  const ushort* bsrc[2];
  #pragma unroll
  for (int j = 0; j < 2; ++j) {
    int r = (2*w + j)*16 + (lane >> 2);
    int pi = min(m0 + r, ce - 1);
    asrc[j] = act + (size_t)(oe + pi) * FD + csrc * 8;
    bsrc[j] = wdt + ((size_t)e * HD + n0 + r) * FD + csrc * 8;
  }

  int lm = lane & 15, lg = lane >> 4;
  int wr = w >> 1, wc = w & 1;
  int asw = (lm >> 1) & 3;

  f32x4 acc[4][4];
  #pragma unroll
  for (int m = 0; m < 4; ++m)
    #pragma unroll
    for (int n = 0; n < 4; ++n) acc[m][n] = f32x4{0,0,0,0};

  #define DNB_ISSUE(T, BUF) do { \
    GLOAD_LDS16(asrc[0] + (T)*32, &A[BUF][(2*w)*512]); \
    GLOAD_LDS16(asrc[1] + (T)*32, &A[BUF][(2*w+1)*512]); \
    GLOAD_LDS16(bsrc[0] + (T)*32, &Bd[BUF][(2*w)*512]); \
    GLOAD_LDS16(bsrc[1] + (T)*32, &Bd[BUF][(2*w+1)*512]); \
  } while (0)
  #define DNB_COMPUTE(BUF) do { \
    bf16x8 a[4], b[4]; \
    _Pragma("unroll") \
    for (int m = 0; m < 4; ++m) \
      a[m] = *(const bf16x8*)&A[BUF][(wr*64 + m*16 + lm)*32 + (lg ^ asw)*8]; \
    _Pragma("unroll") \
    for (int n = 0; n < 4; ++n) { \
      int row = wc*64 + n*16 + lm; \
      b[n] = *(const bf16x8*)&Bd[BUF][row*32 + (lg ^ asw)*8]; \
    } \
    _Pragma("unroll") \
    for (int m = 0; m < 4; ++m) \
      _Pragma("unroll") \
      for (int n = 0; n < 4; ++n) \
        acc[m][n] = __builtin_amdgcn_mfma_f32_16x16x32_bf16(a[m], b[n], acc[m][n], 0, 0, 0); \
  } while (0)
  #define DNB_STEP(T, CB, IB, DOISS) do { \
    if (DOISS) DNB_ISSUE((T)+2, IB); \
    DNB_COMPUTE(CB); \
    if (DOISS) { WAIT_VM4; } else { WAIT_VM0; } \
    __syncthreads(); \
  } while (0)

  DNB_ISSUE(0, 0);
  DNB_ISSUE(1, 1);
  WAIT_VM4;
  __syncthreads();

  for (int tt = 0; tt < 10; ++tt) {
    int t = tt * 3;
    DNB_STEP(t,   0, 2, 1);
    DNB_STEP(t+1, 1, 0, 1);
    DNB_STEP(t+2, 2, 1, 1);
  }
  DNB_STEP(30, 0, 0, 0);
  DNB_COMPUTE(1);    // t=31
  #undef DNB_ISSUE
  #undef DNB_COMPUTE
  #undef DNB_STEP

  #pragma unroll
  for (int m = 0; m < 4; ++m) {
    #pragma unroll
    for (int j = 0; j < 4; ++j) {
      int rl = wr*64 + m*16 + lg*4 + j;
      int pi = m0 + rl;
      if (pi >= ce) continue;
      int tok = pair_tok[oe + pi];
      size_t base = (size_t)tok * HD + n0 + wc*64;
      #pragma unroll
      for (int n = 0; n < 4; ++n)
        atomicAdd(&y[base + n*16 + lm], acc[m][n][j]);
    }
  }
}

// shared gate+up: 3-buf depth-2
__global__ __launch_bounds__(256) void shared_gu_b(
    const ushort* __restrict__ xb, const ushort* __restrict__ sgb, const ushort* __restrict__ sub,
    ushort* __restrict__ sact)
{
  __shared__ ushort A[3][128*32];
  __shared__ ushort Bg[3][64*32];
  __shared__ ushort Bu[3][64*32];

  int bid = blockIdx.x;
  int wid = (bid & 7) * 64 + (bid >> 3);
  int mt = wid & 15;
  int nt = wid >> 4;
  int m0 = mt * 128;
  int n0 = nt * 64;
  int tid = threadIdx.x, lane = tid & 63, w = tid >> 6;

  int csrc = (lane & 3) ^ ((lane >> 3) & 3);
  const ushort* asrc[2];
  #pragma unroll
  for (int j = 0; j < 2; ++j) {
    int r = (2*w + j)*16 + (lane >> 2);
    asrc[j] = xb + (size_t)(m0 + r) * HD + csrc * 8;
  }
  int brow = w*16 + (lane >> 2);
  const ushort* bgsrc = sgb + (size_t)(n0 + brow) * HD + csrc * 8;
  const ushort* busrc = sub + (size_t)(n0 + brow) * HD + csrc * 8;

  int lm = lane & 15, lg = lane >> 4;
  int wr = w >> 1, wc = w & 1;
  int asw = (lm >> 1) & 3;

  f32x4 accg[4][2], accu[4][2];
  #pragma unroll
  for (int m = 0; m < 4; ++m)
    #pragma unroll
    for (int n = 0; n < 2; ++n) { accg[m][n] = f32x4{0,0,0,0}; accu[m][n] = f32x4{0,0,0,0}; }

  #define SGB_ISSUE(T, BUF) do { \
    GLOAD_LDS16(asrc[0] + (T)*32, &A[BUF][(2*w)*512]); \
    GLOAD_LDS16(asrc[1] + (T)*32, &A[BUF][(2*w+1)*512]); \
    GLOAD_LDS16(bgsrc + (T)*32, &Bg[BUF][w*512]); \
    GLOAD_LDS16(busrc + (T)*32, &Bu[BUF][w*512]); \
  } while (0)
  #define SGB_COMPUTE(BUF) do { \
    bf16x8 a[4], bg[2], bu[2]; \
    _Pragma("unroll") \
    for (int m = 0; m < 4; ++m) \
      a[m] = *(const bf16x8*)&A[BUF][(wr*64 + m*16 + lm)*32 + (lg ^ asw)*8]; \
    _Pragma("unroll") \
    for (int n = 0; n < 2; ++n) { \
      int row = wc*32 + n*16 + lm; \
      bg[n] = *(const bf16x8*)&Bg[BUF][row*32 + (lg ^ asw)*8]; \
      bu[n] = *(const bf16x8*)&Bu[BUF][row*32 + (lg ^ asw)*8]; \
    } \
    _Pragma("unroll") \
    for (int m = 0; m < 4; ++m) \
      _Pragma("unroll") \
      for (int n = 0; n < 2; ++n) { \
        accg[m][n] = __builtin_amdgcn_mfma_f32_16x16x32_bf16(a[m], bg[n], accg[m][n], 0, 0, 0); \
        accu[m][n] = __builtin_amdgcn_mfma_f32_16x16x32_bf16(a[m], bu[n], accu[m][n], 0, 0, 0); \
      } \
  } while (0)
  #define SGB_STEP(T, CB, IB, DOISS) do { \
    if (DOISS) SGB_ISSUE((T)+2, IB); \
    SGB_COMPUTE(CB); \
    if (DOISS) { WAIT_VM4; } else { WAIT_VM0; } \
    __syncthreads(); \
  } while (0)

  SGB_ISSUE(0, 0);
  SGB_ISSUE(1, 1);
  WAIT_VM4;
  __syncthreads();

  for (int tt = 0; tt < 20; ++tt) {
    int t = tt * 3;
    SGB_STEP(t,   0, 2, 1);
    SGB_STEP(t+1, 1, 0, 1);
    SGB_STEP(t+2, 2, 1, 1);
  }
  SGB_STEP(60, 0, 2, 1);
  SGB_STEP(61, 1, 0, 1);
  SGB_STEP(62, 2, 0, 0);
  SGB_COMPUTE(0);
  #undef SGB_ISSUE
  #undef SGB_COMPUTE
  #undef SGB_STEP

  #pragma unroll
  for (int m = 0; m < 4; ++m) {
    #pragma unroll
    for (int j = 0; j < 4; ++j) {
      int rl = wr*64 + m*16 + lg*4 + j;
      size_t base = (size_t)(m0 + rl) * SDIM + n0 + wc*32;
      #pragma unroll
      for (int n = 0; n < 2; ++n) {
        float gv = accg[m][n][j];
        float uv = accu[m][n][j];
        float sv = gv / (1.f + __expf(-gv));
        sact[base + n*16 + lm] = f2b(sv * uv);
      }
    }
  }
}

// shared down: 3-buf depth-2, STORES y
__global__ __launch_bounds__(256) void shared_down_b(
    const ushort* __restrict__ sact, const ushort* __restrict__ sdb, float* __restrict__ y)
{
  __shared__ ushort A[3][128*32];
  __shared__ ushort Bd[3][128*32];

  int bid = blockIdx.x;
  int wid = (bid & 7) * 32 + (bid >> 3);
  int mt = wid & 15;
  int nt = wid >> 4;
  int m0 = mt * 128;
  int n0 = nt * 128;
  int tid = threadIdx.x, lane = tid & 63, w = tid >> 6;

  int csrc = (lane & 3) ^ ((lane >> 3) & 3);
  const ushort* asrc[2];
  const ushort* bsrc[2];
  #pragma unroll
  for (int j = 0; j < 2; ++j) {
    int r = (2*w + j)*16 + (lane >> 2);
    asrc[j] = sact + (size_t)(m0 + r) * SDIM + csrc * 8;
    bsrc[j] = sdb + (size_t)(n0 + r) * SDIM + csrc * 8;
  }

  int lm = lane & 15, lg = lane >> 4;
  int wr = w >> 1, wc = w & 1;
  int asw = (lm >> 1) & 3;

  f32x4 acc[4][4];
  #pragma unroll
  for (int m = 0; m < 4; ++m)
    #pragma unroll
    for (int n = 0; n < 4; ++n) acc[m][n] = f32x4{0,0,0,0};

  #define SDB_ISSUE(T, BUF) do { \
    GLOAD_LDS16(asrc[0] + (T)*32, &A[BUF][(2*w)*512]); \
    GLOAD_LDS16(asrc[1] + (T)*32, &A[BUF][(2*w+1)*512]); \
    GLOAD_LDS16(bsrc[0] + (T)*32, &Bd[BUF][(2*w)*512]); \
    GLOAD_LDS16(bsrc[1] + (T)*32, &Bd[BUF][(2*w+1)*512]); \
  } while (0)
  #define SDB_COMPUTE(BUF) do { \
    bf16x8 a[4], b[4]; \
    _Pragma("unroll") \
    for (int m = 0; m < 4; ++m) \
      a[m] = *(const bf16x8*)&A[BUF][(wr*64 + m*16 + lm)*32 + (lg ^ asw)*8]; \
    _Pragma("unroll") \
    for (int n = 0; n < 4; ++n) { \
      int row = wc*64 + n*16 + lm; \
      b[n] = *(const bf16x8*)&Bd[BUF][row*32 + (lg ^ asw)*8]; \
    } \
    _Pragma("unroll") \
    for (int m = 0; m < 4; ++m) \
      _Pragma("unroll") \
      for (int n = 0; n < 4; ++n) \
        acc[m][n] = __builtin_amdgcn_mfma_f32_16x16x32_bf16(a[m], b[n], acc[m][n], 0, 0, 0); \
  } while (0)
  #define SDB_STEP(T, CB, IB, DOISS) do { \
    if (DOISS) SDB_ISSUE((T)+2, IB); \
    SDB_COMPUTE(CB); \
    if (DOISS) { WAIT_VM4; } else { WAIT_VM0; } \
    __syncthreads(); \
  } while (0)

  SDB_ISSUE(0, 0);
  SDB_ISSUE(1, 1);
  WAIT_VM4;
  __syncthreads();

  for (int tt = 0; tt < 20; ++tt) {
    int t = tt * 3;
    SDB_STEP(t,   0, 2, 1);
    SDB_STEP(t+1, 1, 0, 1);
    SDB_STEP(t+2, 2, 1, 1);
  }
  SDB_STEP(60, 0, 2, 1);
  SDB_STEP(61, 1, 0, 1);
  SDB_STEP(62, 2, 0, 0);
  SDB_COMPUTE(0);
  #undef SDB_ISSUE
  #undef SDB_COMPUTE
  #undef SDB_STEP

  #pragma unroll
  for (int m = 0; m < 4; ++m) {
    #pragma unroll
    for (int j = 0; j < 4; ++j) {
      int rl = wr*64 + m*16 + lg*4 + j;
      size_t base = (size_t)(m0 + rl) * HD + n0 + wc*64;
      #pragma unroll
      for (int n = 0; n < 4; ++n)
        y[base + n*16 + lm] = acc[m][n][j];     // store, not +=
    }
  }
}

// ---------------- launch ----------------
extern "C" void kernel_launch(void* const* d_in, const int* in_sizes, int n_in,
                              void* d_out, int out_size, void* d_ws, size_t ws_size,
                              hipStream_t stream) {
  const float* x     = (const float*)d_in[0];
  const float* wgate = (const float*)d_in[1];
  const float* wg    = (const float*)d_in[2];
  const float* wu    = (const float*)d_in[3];
  const float* wd    = (const float*)d_in[4];
  const float* sg    = (const float*)d_in[5];
  const float* su    = (const float*)d_in[6];
  const float* sd    = (const float*)d_in[7];
  float* y = (float*)d_out;
  char* ws = (char*)d_ws;

  ushort* xb   = (ushort*)(ws + 0);
  ushort* act  = (ushort*)(ws + 8388608);
  ushort* sact = (ushort*)(ws + 33554432);
  int*    tidx = (int*)  (ws + 41943040);
  float*  tw   = (float*)(ws + 41992192);
  int*    ptok = (int*)  (ws + 42041344);
  float*  pw   = (float*)(ws + 42090496);
  int*    cnt  = (int*)  (ws + 42139648);
  int*    curc = (int*)  (ws + 42139776);
  int*    offs = (int*)  (ws + 42139904);
  int*    tl_e = (int*)  (ws + 42140160);
  int*    tl_m = (int*)  (ws + 42140672);
  int*    ntl  = (int*)  (ws + 42141184);
  ushort* wgt  = (ushort*)(ws + 50331648);    // 128 MB [E][F][H]
  ushort* wut  = (ushort*)(ws + 184549376);   // 128 MB
  ushort* wdt  = (ushort*)(ws + 318767104);   // 128 MB [E][H][F]
  ushort* sgb  = (ushort*)(ws + 452984832);   // 8 MB
  ushort* sub  = (ushort*)(ws + 461373440);
  ushort* sdb  = (ushort*)(ws + 469762048);

  hipMemsetAsync(cnt, 0, 512, stream);

  cvt_kernel<<<dim3(4096), dim3(256), 0, stream>>>(x, xb);
  gating_kernel<<<dim3(TT), dim3(64), 0, stream>>>(x, wgate, tidx, tw, cnt);
  scan_kernel<<<dim3(1), dim3(64), 0, stream>>>(cnt, offs, tl_e, tl_m, ntl);
  fill_kernel<<<dim3(48), dim3(256), 0, stream>>>(tidx, tw, offs, curc, ptok, pw);

  tconv<<<dim3(512, NEXP), dim3(256), 0, stream>>>(wg, wgt, HD, FD);   // [H][F] -> [F][H]
  tconv<<<dim3(512, NEXP), dim3(256), 0, stream>>>(wu, wut, HD, FD);
  tconv<<<dim3(512, NEXP), dim3(256), 0, stream>>>(wd, wdt, FD, HD);   // [F][H] -> [H][F]
  fconv<<<dim3(4096), dim3(256), 0, stream>>>(sg, sgb);
  fconv<<<dim3(4096), dim3(256), 0, stream>>>(su, sub);
  fconv<<<dim3(4096), dim3(256), 0, stream>>>(sd, sdb);

  // shared first (shared_down stores y), then routed down accumulates atomically
  shared_gu_b<<<dim3(512), dim3(256), 0, stream>>>(xb, sgb, sub, sact);
  shared_down_b<<<dim3(256), dim3(256), 0, stream>>>(sact, sdb, y);
  gu_routed_b<<<dim3(2048), dim3(256), 0, stream>>>(xb, wgt, wut, ptok, pw, cnt, offs,
                                                    tl_e, tl_m, ntl, act);
  down_routed_b<<<dim3(2048), dim3(256), 0, stream>>>(act, wdt, ptok, cnt, offs,
                                                      tl_e, tl_m, ntl, y);
}

// Round 9
// 836.209 us; speedup vs baseline: 1.0886x; 1.0141x over previous
//
#include <hip/hip_runtime.h>

#define HD   2048
#define FD   1024
#define NEXP 32
#define TOPK 6
#define TT   2048
#define SDIM 2048
#define NPAIR (TT*TOPK)

typedef __bf16 bf16x8 __attribute__((ext_vector_type(8)));
typedef float  f32x4  __attribute__((ext_vector_type(4)));

#define GLOAD_LDS16(g, l) __builtin_amdgcn_global_load_lds( \
    (const __attribute__((address_space(1))) void*)(g),     \
    (__attribute__((address_space(3))) void*)(l), 16, 0, 0)

#define WAIT_VM4  asm volatile("s_waitcnt vmcnt(4)" ::: "memory")
#define WAIT_VM0  asm volatile("s_waitcnt vmcnt(0)" ::: "memory")
// raw barrier: does NOT drain vmcnt (unlike __syncthreads) — T4 prerequisite
#define BAR() do { __builtin_amdgcn_s_barrier(); } while (0)

__device__ __forceinline__ ushort f2b(float f) {
  __bf16 h = (__bf16)f;
  union { __bf16 h; ushort u; } v; v.h = h;
  return v.u;
}

// bijective XCD swizzle over nact active blocks (m204)
__device__ __forceinline__ int xcd_swz(int bid, int nact) {
  int xcd = bid & 7, i = bid >> 3;
  int q = nact >> 3, r = nact & 7;
  int base = (xcd < r) ? xcd * (q + 1) : r * (q + 1) + (xcd - r) * q;
  return base + i;
}

// ---------------- gating (fp32 exact) ----------------
__device__ __forceinline__ void argmax32(float &v, int &i) {
  #pragma unroll
  for (int m = 16; m >= 1; m >>= 1) {
    float ov = __shfl_xor(v, m, 32);
    int   oi = __shfl_xor(i, m, 32);
    if (ov > v || (ov == v && oi < i)) { v = ov; i = oi; }
  }
}

__global__ __launch_bounds__(64) void gating_kernel(
    const float* __restrict__ x, const float* __restrict__ wgate,
    int* __restrict__ topk_idx, float* __restrict__ topk_w, int* __restrict__ cnt)
{
  int t = blockIdx.x;
  int l = threadIdx.x;
  int e = l & 31;
  int half = l >> 5;
  const float* xr = x + (size_t)t * HD + half * (HD/2);
  const float* wr = wgate + (size_t)e * HD + half * (HD/2);
  float acc = 0.f;
  for (int i = 0; i < HD/2; i += 4) {
    float4 a = *(const float4*)(xr + i);
    float4 b = *(const float4*)(wr + i);
    acc += a.x*b.x + a.y*b.y + a.z*b.z + a.w*b.w;
  }
  acc += __shfl_xor(acc, 32);
  float logit = acc;
  float mx = logit;
  #pragma unroll
  for (int m = 16; m >= 1; m >>= 1) mx = fmaxf(mx, __shfl_xor(mx, m, 32));
  float p = __expf(logit - mx);
  float s = p;
  #pragma unroll
  for (int m = 16; m >= 1; m >>= 1) s += __shfl_xor(s, m, 32);
  float score = p / s;
  float gs = score;
  gs = fmaxf(gs, __shfl_xor(gs, 1, 32));
  gs = fmaxf(gs, __shfl_xor(gs, 2, 32));
  int g = e >> 2;
  float gw = gs;
  bool ingroup = false;
  for (int r = 0; r < 3; ++r) {
    float v = gw; int gi = g;
    argmax32(v, gi);
    if (g == gi) { ingroup = true; gw = -1.f; }
  }
  float ms = ingroup ? score : 0.f;
  int myrank = -1;
  float denom = 1e-20f;
  float mw = ms;
  for (int r = 0; r < 6; ++r) {
    float v = mw; int ei = e;
    argmax32(v, ei);
    denom += v;
    if (e == ei) { myrank = r; mw = -1.f; }
  }
  if (l < 32 && myrank >= 0) {
    topk_idx[t*TOPK + myrank] = e;
    topk_w  [t*TOPK + myrank] = score / denom;
    atomicAdd(&cnt[e], 1);
  }
}

__global__ void scan_kernel(const int* __restrict__ cnt, int* __restrict__ offs,
                            int* __restrict__ tl_e, int* __restrict__ tl_m, int* __restrict__ ntl) {
  if (threadIdx.x == 0) {
    int o = 0, nt = 0;
    for (int e = 0; e < NEXP; ++e) {
      offs[e] = o;
      for (int m = 0; m < cnt[e]; m += 128) { tl_e[nt] = e; tl_m[nt] = m; ++nt; }
      o += cnt[e];
    }
    ntl[0] = nt;
  }
}

__global__ void fill_kernel(const int* __restrict__ topk_idx, const float* __restrict__ topk_w,
                            const int* __restrict__ offs, int* __restrict__ cur,
                            int* __restrict__ pair_tok, float* __restrict__ pair_w)
{
  int idx = blockIdx.x * blockDim.x + threadIdx.x;
  if (idx >= NPAIR) return;
  int e = topk_idx[idx];
  int p = offs[e] + atomicAdd(&cur[e], 1);
  pair_tok[p] = idx / TOPK;
  pair_w[p]   = topk_w[idx];
}

__global__ void cvt_kernel(const float* __restrict__ x, ushort* __restrict__ xb) {
  int i = blockIdx.x * blockDim.x + threadIdx.x;
  float4 v = ((const float4*)x)[i];
  ((ushort4*)xb)[i] = make_ushort4(f2b(v.x), f2b(v.y), f2b(v.z), f2b(v.w));
}

__global__ __launch_bounds__(256) void fconv(const float* __restrict__ in, ushort* __restrict__ out) {
  int i = blockIdx.x * blockDim.x + threadIdx.x;
  float4 v = ((const float4*)in)[i];
  ((ushort4*)out)[i] = make_ushort4(f2b(v.x), f2b(v.y), f2b(v.z), f2b(v.w));
}

// transpose-convert: in [R][C] fp32 -> out [C][R] bf16. 64x64 tiles.
#define TSTR 76
__global__ __launch_bounds__(256) void tconv(const float* __restrict__ in, ushort* __restrict__ out,
                                             int R, int C) {
  __shared__ ushort T[64*TSTR];
  int tiles_c = C >> 6;
  int bt = blockIdx.x;
  int r0 = (bt / tiles_c) << 6;
  int c0 = (bt % tiles_c) << 6;
  const float* src = in + (size_t)blockIdx.y * R * C;
  ushort* dst = out + (size_t)blockIdx.y * R * C;
  int t = threadIdx.x;
  int row = (t >> 4) << 2;
  int col4 = (t & 15) << 2;
  float vv[4][4];
  #pragma unroll
  for (int i = 0; i < 4; ++i) {
    float4 v = *(const float4*)(src + (size_t)(r0 + row + i) * C + c0 + col4);
    vv[i][0] = v.x; vv[i][1] = v.y; vv[i][2] = v.z; vv[i][3] = v.w;
  }
  #pragma unroll
  for (int cc = 0; cc < 4; ++cc)
    *(ushort4*)&T[(col4 + cc)*TSTR + row] =
      make_ushort4(f2b(vv[0][cc]), f2b(vv[1][cc]), f2b(vv[2][cc]), f2b(vv[3][cc]));
  __syncthreads();
  int oc = t >> 2;
  int ok = (t & 3) << 4;
  ushort4 a0 = *(const ushort4*)&T[oc*TSTR + ok];
  ushort4 a1 = *(const ushort4*)&T[oc*TSTR + ok + 4];
  ushort4 a2 = *(const ushort4*)&T[oc*TSTR + ok + 8];
  ushort4 a3 = *(const ushort4*)&T[oc*TSTR + ok + 12];
  ushort* d = dst + (size_t)(c0 + oc) * R + r0 + ok;
  *(ushort4*)(d)      = a0;
  *(ushort4*)(d + 4)  = a1;
  *(ushort4*)(d + 8)  = a2;
  *(ushort4*)(d + 12) = a3;
}

// ============ all-bf16 GEMMs, depth-2 counted-vmcnt, RAW barriers ============

// routed gate+up: BM=128 BN=64(x2) BK=32, 3-buf LDS, vmcnt(4)
__global__ __launch_bounds__(256) void gu_routed_b(
    const ushort* __restrict__ xb, const ushort* __restrict__ wgt, const ushort* __restrict__ wut,
    const int* __restrict__ pair_tok, const float* __restrict__ pair_w,
    const int* __restrict__ cnt, const int* __restrict__ offs,
    const int* __restrict__ tl_e, const int* __restrict__ tl_m, const int* __restrict__ ntl,
    ushort* __restrict__ act)
{
  __shared__ ushort A[3][128*32];
  __shared__ ushort Bg[3][64*32];
  __shared__ ushort Bu[3][64*32];

  int nact = ntl[0] * 16;
  int bid = blockIdx.x;
  if (bid >= nact) return;
  int wid = xcd_swz(bid, nact);
  int tile = wid >> 4;
  int nt = wid & 15;
  int e  = tl_e[tile];
  int m0 = tl_m[tile];
  int ce = cnt[e];
  int oe = offs[e];
  int n0 = nt * 64;
  int tid = threadIdx.x, lane = tid & 63, w = tid >> 6;

  int csrc = (lane & 3) ^ ((lane >> 3) & 3);
  const ushort* asrc[2];
  #pragma unroll
  for (int j = 0; j < 2; ++j) {
    int r = (2*w + j)*16 + (lane >> 2);
    int pi = min(m0 + r, ce - 1);
    asrc[j] = xb + (size_t)pair_tok[oe + pi] * HD + csrc * 8;
  }
  int brow = w*16 + (lane >> 2);
  const ushort* bgsrc = wgt + ((size_t)e * FD + n0 + brow) * HD + csrc * 8;
  const ushort* busrc = wut + ((size_t)e * FD + n0 + brow) * HD + csrc * 8;

  int lm = lane & 15, lg = lane >> 4;
  int wr = w >> 1, wc = w & 1;
  int asw = (lm >> 1) & 3;

  f32x4 accg[4][2], accu[4][2];
  #pragma unroll
  for (int m = 0; m < 4; ++m)
    #pragma unroll
    for (int n = 0; n < 2; ++n) { accg[m][n] = f32x4{0,0,0,0}; accu[m][n] = f32x4{0,0,0,0}; }

  #define GUB_ISSUE(T, BUF) do { \
    GLOAD_LDS16(asrc[0] + (T)*32, &A[BUF][(2*w)*512]); \
    GLOAD_LDS16(asrc[1] + (T)*32, &A[BUF][(2*w+1)*512]); \
    GLOAD_LDS16(bgsrc + (T)*32, &Bg[BUF][w*512]); \
    GLOAD_LDS16(busrc + (T)*32, &Bu[BUF][w*512]); \
  } while (0)
  #define GUB_COMPUTE(BUF) do { \
    bf16x8 a[4], bg[2], bu[2]; \
    _Pragma("unroll") \
    for (int m = 0; m < 4; ++m) \
      a[m] = *(const bf16x8*)&A[BUF][(wr*64 + m*16 + lm)*32 + (lg ^ asw)*8]; \
    _Pragma("unroll") \
    for (int n = 0; n < 2; ++n) { \
      int row = wc*32 + n*16 + lm; \
      bg[n] = *(const bf16x8*)&Bg[BUF][row*32 + (lg ^ asw)*8]; \
      bu[n] = *(const bf16x8*)&Bu[BUF][row*32 + (lg ^ asw)*8]; \
    } \
    _Pragma("unroll") \
    for (int m = 0; m < 4; ++m) \
      _Pragma("unroll") \
      for (int n = 0; n < 2; ++n) { \
        accg[m][n] = __builtin_amdgcn_mfma_f32_16x16x32_bf16(a[m], bg[n], accg[m][n], 0, 0, 0); \
        accu[m][n] = __builtin_amdgcn_mfma_f32_16x16x32_bf16(a[m], bu[n], accu[m][n], 0, 0, 0); \
      } \
  } while (0)
  #define GUB_STEP(T, CB, IB, DOISS) do { \
    if (DOISS) GUB_ISSUE((T)+2, IB); \
    GUB_COMPUTE(CB); \
    if (DOISS) { WAIT_VM4; } else { WAIT_VM0; } \
    BAR(); \
  } while (0)

  GUB_ISSUE(0, 0);
  GUB_ISSUE(1, 1);
  WAIT_VM4;
  BAR();

  for (int tt = 0; tt < 20; ++tt) {
    int t = tt * 3;
    GUB_STEP(t,   0, 2, 1);
    GUB_STEP(t+1, 1, 0, 1);
    GUB_STEP(t+2, 2, 1, 1);
  }
  GUB_STEP(60, 0, 2, 1);
  GUB_STEP(61, 1, 0, 1);
  GUB_STEP(62, 2, 0, 0);
  GUB_COMPUTE(0);     // t=63
  #undef GUB_ISSUE
  #undef GUB_COMPUTE
  #undef GUB_STEP

  #pragma unroll
  for (int m = 0; m < 4; ++m) {
    #pragma unroll
    for (int j = 0; j < 4; ++j) {
      int rl = wr*64 + m*16 + lg*4 + j;
      int pi = m0 + rl;
      if (pi >= ce) continue;
      float pwv = pair_w[oe + pi];
      size_t base = (size_t)(oe + pi) * FD + n0 + wc*32;
      #pragma unroll
      for (int n = 0; n < 2; ++n) {
        float gv = accg[m][n][j];
        float uv = accu[m][n][j];
        float sv = gv / (1.f + __expf(-gv));
        act[base + n*16 + lm] = f2b(sv * uv * pwv);
      }
    }
  }
}

// routed down: BM=128 BN=128 BK=32, 3-buf, atomic scatter (y pre-seeded)
__global__ __launch_bounds__(256) void down_routed_b(
    const ushort* __restrict__ act, const ushort* __restrict__ wdt,
    const int* __restrict__ pair_tok, const int* __restrict__ cnt, const int* __restrict__ offs,
    const int* __restrict__ tl_e, const int* __restrict__ tl_m, const int* __restrict__ ntl,
    float* __restrict__ y)
{
  __shared__ ushort A[3][128*32];
  __shared__ ushort Bd[3][128*32];

  int nact = ntl[0] * 16;
  int bid = blockIdx.x;
  if (bid >= nact) return;
  int wid = xcd_swz(bid, nact);
  int tile = wid >> 4;
  int nt = wid & 15;
  int e  = tl_e[tile];
  int m0 = tl_m[tile];
  int ce = cnt[e];
  int oe = offs[e];
  int n0 = nt * 128;
  int tid = threadIdx.x, lane = tid & 63, w = tid >> 6;

  int csrc = (lane & 3) ^ ((lane >> 3) & 3);
  const ushort* asrc[2];
  const ushort* bsrc[2];
  #pragma unroll
  for (int j = 0; j < 2; ++j) {
    int r = (2*w + j)*16 + (lane >> 2);
    int pi = min(m0 + r, ce - 1);
    asrc[j] = act + (size_t)(oe + pi) * FD + csrc * 8;
    bsrc[j] = wdt + ((size_t)e * HD + n0 + r) * FD + csrc * 8;
  }

  int lm = lane & 15, lg = lane >> 4;
  int wr = w >> 1, wc = w & 1;
  int asw = (lm >> 1) & 3;

  f32x4 acc[4][4];
  #pragma unroll
  for (int m = 0; m < 4; ++m)
    #pragma unroll
    for (int n = 0; n < 4; ++n) acc[m][n] = f32x4{0,0,0,0};

  #define DNB_ISSUE(T, BUF) do { \
    GLOAD_LDS16(asrc[0] + (T)*32, &A[BUF][(2*w)*512]); \
    GLOAD_LDS16(asrc[1] + (T)*32, &A[BUF][(2*w+1)*512]); \
    GLOAD_LDS16(bsrc[0] + (T)*32, &Bd[BUF][(2*w)*512]); \
    GLOAD_LDS16(bsrc[1] + (T)*32, &Bd[BUF][(2*w+1)*512]); \
  } while (0)
  #define DNB_COMPUTE(BUF) do { \
    bf16x8 a[4], b[4]; \
    _Pragma("unroll") \
    for (int m = 0; m < 4; ++m) \
      a[m] = *(const bf16x8*)&A[BUF][(wr*64 + m*16 + lm)*32 + (lg ^ asw)*8]; \
    _Pragma("unroll") \
    for (int n = 0; n < 4; ++n) { \
      int row = wc*64 + n*16 + lm; \
      b[n] = *(const bf16x8*)&Bd[BUF][row*32 + (lg ^ asw)*8]; \
    } \
    _Pragma("unroll") \
    for (int m = 0; m < 4; ++m) \
      _Pragma("unroll") \
      for (int n = 0; n < 4; ++n) \
        acc[m][n] = __builtin_amdgcn_mfma_f32_16x16x32_bf16(a[m], b[n], acc[m][n], 0, 0, 0); \
  } while (0)
  #define DNB_STEP(T, CB, IB, DOISS) do { \
    if (DOISS) DNB_ISSUE((T)+2, IB); \
    DNB_COMPUTE(CB); \
    if (DOISS) { WAIT_VM4; } else { WAIT_VM0; } \
    BAR(); \
  } while (0)

  DNB_ISSUE(0, 0);
  DNB_ISSUE(1, 1);
  WAIT_VM4;
  BAR();

  for (int tt = 0; tt < 10; ++tt) {
    int t = tt * 3;
    DNB_STEP(t,   0, 2, 1);
    DNB_STEP(t+1, 1, 0, 1);
    DNB_STEP(t+2, 2, 1, 1);
  }
  DNB_STEP(30, 0, 0, 0);
  DNB_COMPUTE(1);    // t=31
  #undef DNB_ISSUE
  #undef DNB_COMPUTE
  #undef DNB_STEP

  #pragma unroll
  for (int m = 0; m < 4; ++m) {
    #pragma unroll
    for (int j = 0; j < 4; ++j) {
      int rl = wr*64 + m*16 + lg*4 + j;
      int pi = m0 + rl;
      if (pi >= ce) continue;
      int tok = pair_tok[oe + pi];
      size_t base = (size_t)tok * HD + n0 + wc*64;
      #pragma unroll
      for (int n = 0; n < 4; ++n)
        atomicAdd(&y[base + n*16 + lm], acc[m][n][j]);
    }
  }
}

// shared gate+up: 3-buf depth-2
__global__ __launch_bounds__(256) void shared_gu_b(
    const ushort* __restrict__ xb, const ushort* __restrict__ sgb, const ushort* __restrict__ sub,
    ushort* __restrict__ sact)
{
  __shared__ ushort A[3][128*32];
  __shared__ ushort Bg[3][64*32];
  __shared__ ushort Bu[3][64*32];

  int bid = blockIdx.x;
  int wid = (bid & 7) * 64 + (bid >> 3);
  int mt = wid & 15;
  int nt = wid >> 4;
  int m0 = mt * 128;
  int n0 = nt * 64;
  int tid = threadIdx.x, lane = tid & 63, w = tid >> 6;

  int csrc = (lane & 3) ^ ((lane >> 3) & 3);
  const ushort* asrc[2];
  #pragma unroll
  for (int j = 0; j < 2; ++j) {
    int r = (2*w + j)*16 + (lane >> 2);
    asrc[j] = xb + (size_t)(m0 + r) * HD + csrc * 8;
  }
  int brow = w*16 + (lane >> 2);
  const ushort* bgsrc = sgb + (size_t)(n0 + brow) * HD + csrc * 8;
  const ushort* busrc = sub + (size_t)(n0 + brow) * HD + csrc * 8;

  int lm = lane & 15, lg = lane >> 4;
  int wr = w >> 1, wc = w & 1;
  int asw = (lm >> 1) & 3;

  f32x4 accg[4][2], accu[4][2];
  #pragma unroll
  for (int m = 0; m < 4; ++m)
    #pragma unroll
    for (int n = 0; n < 2; ++n) { accg[m][n] = f32x4{0,0,0,0}; accu[m][n] = f32x4{0,0,0,0}; }

  #define SGB_ISSUE(T, BUF) do { \
    GLOAD_LDS16(asrc[0] + (T)*32, &A[BUF][(2*w)*512]); \
    GLOAD_LDS16(asrc[1] + (T)*32, &A[BUF][(2*w+1)*512]); \
    GLOAD_LDS16(bgsrc + (T)*32, &Bg[BUF][w*512]); \
    GLOAD_LDS16(busrc + (T)*32, &Bu[BUF][w*512]); \
  } while (0)
  #define SGB_COMPUTE(BUF) do { \
    bf16x8 a[4], bg[2], bu[2]; \
    _Pragma("unroll") \
    for (int m = 0; m < 4; ++m) \
      a[m] = *(const bf16x8*)&A[BUF][(wr*64 + m*16 + lm)*32 + (lg ^ asw)*8]; \
    _Pragma("unroll") \
    for (int n = 0; n < 2; ++n) { \
      int row = wc*32 + n*16 + lm; \
      bg[n] = *(const bf16x8*)&Bg[BUF][row*32 + (lg ^ asw)*8]; \
      bu[n] = *(const bf16x8*)&Bu[BUF][row*32 + (lg ^ asw)*8]; \
    } \
    _Pragma("unroll") \
    for (int m = 0; m < 4; ++m) \
      _Pragma("unroll") \
      for (int n = 0; n < 2; ++n) { \
        accg[m][n] = __builtin_amdgcn_mfma_f32_16x16x32_bf16(a[m], bg[n], accg[m][n], 0, 0, 0); \
        accu[m][n] = __builtin_amdgcn_mfma_f32_16x16x32_bf16(a[m], bu[n], accu[m][n], 0, 0, 0); \
      } \
  } while (0)
  #define SGB_STEP(T, CB, IB, DOISS) do { \
    if (DOISS) SGB_ISSUE((T)+2, IB); \
    SGB_COMPUTE(CB); \
    if (DOISS) { WAIT_VM4; } else { WAIT_VM0; } \
    BAR(); \
  } while (0)

  SGB_ISSUE(0, 0);
  SGB_ISSUE(1, 1);
  WAIT_VM4;
  BAR();

  for (int tt = 0; tt < 20; ++tt) {
    int t = tt * 3;
    SGB_STEP(t,   0, 2, 1);
    SGB_STEP(t+1, 1, 0, 1);
    SGB_STEP(t+2, 2, 1, 1);
  }
  SGB_STEP(60, 0, 2, 1);
  SGB_STEP(61, 1, 0, 1);
  SGB_STEP(62, 2, 0, 0);
  SGB_COMPUTE(0);
  #undef SGB_ISSUE
  #undef SGB_COMPUTE
  #undef SGB_STEP

  #pragma unroll
  for (int m = 0; m < 4; ++m) {
    #pragma unroll
    for (int j = 0; j < 4; ++j) {
      int rl = wr*64 + m*16 + lg*4 + j;
      size_t base = (size_t)(m0 + rl) * SDIM + n0 + wc*32;
      #pragma unroll
      for (int n = 0; n < 2; ++n) {
        float gv = accg[m][n][j];
        float uv = accu[m][n][j];
        float sv = gv / (1.f + __expf(-gv));
        sact[base + n*16 + lm] = f2b(sv * uv);
      }
    }
  }
}

// shared down: 3-buf depth-2, STORES y
__global__ __launch_bounds__(256) void shared_down_b(
    const ushort* __restrict__ sact, const ushort* __restrict__ sdb, float* __restrict__ y)
{
  __shared__ ushort A[3][128*32];
  __shared__ ushort Bd[3][128*32];

  int bid = blockIdx.x;
  int wid = (bid & 7) * 32 + (bid >> 3);
  int mt = wid & 15;
  int nt = wid >> 4;
  int m0 = mt * 128;
  int n0 = nt * 128;
  int tid = threadIdx.x, lane = tid & 63, w = tid >> 6;

  int csrc = (lane & 3) ^ ((lane >> 3) & 3);
  const ushort* asrc[2];
  const ushort* bsrc[2];
  #pragma unroll
  for (int j = 0; j < 2; ++j) {
    int r = (2*w + j)*16 + (lane >> 2);
    asrc[j] = sact + (size_t)(m0 + r) * SDIM + csrc * 8;
    bsrc[j] = sdb + (size_t)(n0 + r) * SDIM + csrc * 8;
  }

  int lm = lane & 15, lg = lane >> 4;
  int wr = w >> 1, wc = w & 1;
  int asw = (lm >> 1) & 3;

  f32x4 acc[4][4];
  #pragma unroll
  for (int m = 0; m < 4; ++m)
    #pragma unroll
    for (int n = 0; n < 4; ++n) acc[m][n] = f32x4{0,0,0,0};

  #define SDB_ISSUE(T, BUF) do { \
    GLOAD_LDS16(asrc[0] + (T)*32, &A[BUF][(2*w)*512]); \
    GLOAD_LDS16(asrc[1] + (T)*32, &A[BUF][(2*w+1)*512]); \
    GLOAD_LDS16(bsrc[0] + (T)*32, &Bd[BUF][(2*w)*512]); \
    GLOAD_LDS16(bsrc[1] + (T)*32, &Bd[BUF][(2*w+1)*512]); \
  } while (0)
  #define SDB_COMPUTE(BUF) do { \
    bf16x8 a[4], b[4]; \
    _Pragma("unroll") \
    for (int m = 0; m < 4; ++m) \
      a[m] = *(const bf16x8*)&A[BUF][(wr*64 + m*16 + lm)*32 + (lg ^ asw)*8]; \
    _Pragma("unroll") \
    for (int n = 0; n < 4; ++n) { \
      int row = wc*64 + n*16 + lm; \
      b[n] = *(const bf16x8*)&Bd[BUF][row*32 + (lg ^ asw)*8]; \
    } \
    _Pragma("unroll") \
    for (int m = 0; m < 4; ++m) \
      _Pragma("unroll") \
      for (int n = 0; n < 4; ++n) \
        acc[m][n] = __builtin_amdgcn_mfma_f32_16x16x32_bf16(a[m], b[n], acc[m][n], 0, 0, 0); \
  } while (0)
  #define SDB_STEP(T, CB, IB, DOISS) do { \
    if (DOISS) SDB_ISSUE((T)+2, IB); \
    SDB_COMPUTE(CB); \
    if (DOISS) { WAIT_VM4; } else { WAIT_VM0; } \
    BAR(); \
  } while (0)

  SDB_ISSUE(0, 0);
  SDB_ISSUE(1, 1);
  WAIT_VM4;
  BAR();

  for (int tt = 0; tt < 20; ++tt) {
    int t = tt * 3;
    SDB_STEP(t,   0, 2, 1);
    SDB_STEP(t+1, 1, 0, 1);
    SDB_STEP(t+2, 2, 1, 1);
  }
  SDB_STEP(60, 0, 2, 1);
  SDB_STEP(61, 1, 0, 1);
  SDB_STEP(62, 2, 0, 0);
  SDB_COMPUTE(0);
  #undef SDB_ISSUE
  #undef SDB_COMPUTE
  #undef SDB_STEP

  #pragma unroll
  for (int m = 0; m < 4; ++m) {
    #pragma unroll
    for (int j = 0; j < 4; ++j) {
      int rl = wr*64 + m*16 + lg*4 + j;
      size_t base = (size_t)(m0 + rl) * HD + n0 + wc*64;
      #pragma unroll
      for (int n = 0; n < 4; ++n)
        y[base + n*16 + lm] = acc[m][n][j];     // store, not +=
    }
  }
}

// ---------------- launch ----------------
extern "C" void kernel_launch(void* const* d_in, const int* in_sizes, int n_in,
                              void* d_out, int out_size, void* d_ws, size_t ws_size,
                              hipStream_t stream) {
  const float* x     = (const float*)d_in[0];
  const float* wgate = (const float*)d_in[1];
  const float* wg    = (const float*)d_in[2];
  const float* wu    = (const float*)d_in[3];
  const float* wd    = (const float*)d_in[4];
  const float* sg    = (const float*)d_in[5];
  const float* su    = (const float*)d_in[6];
  const float* sd    = (const float*)d_in[7];
  float* y = (float*)d_out;
  char* ws = (char*)d_ws;

  ushort* xb   = (ushort*)(ws + 0);
  ushort* act  = (ushort*)(ws + 8388608);
  ushort* sact = (ushort*)(ws + 33554432);
  int*    tidx = (int*)  (ws + 41943040);
  float*  tw   = (float*)(ws + 41992192);
  int*    ptok = (int*)  (ws + 42041344);
  float*  pw   = (float*)(ws + 42090496);
  int*    cnt  = (int*)  (ws + 42139648);
  int*    curc = (int*)  (ws + 42139776);
  int*    offs = (int*)  (ws + 42139904);
  int*    tl_e = (int*)  (ws + 42140160);
  int*    tl_m = (int*)  (ws + 42140672);
  int*    ntl  = (int*)  (ws + 42141184);
  ushort* wgt  = (ushort*)(ws + 50331648);    // 128 MB [E][F][H]
  ushort* wut  = (ushort*)(ws + 184549376);   // 128 MB
  ushort* wdt  = (ushort*)(ws + 318767104);   // 128 MB [E][H][F]
  ushort* sgb  = (ushort*)(ws + 452984832);   // 8 MB
  ushort* sub  = (ushort*)(ws + 461373440);
  ushort* sdb  = (ushort*)(ws + 469762048);

  hipMemsetAsync(cnt, 0, 512, stream);

  cvt_kernel<<<dim3(4096), dim3(256), 0, stream>>>(x, xb);
  gating_kernel<<<dim3(TT), dim3(64), 0, stream>>>(x, wgate, tidx, tw, cnt);
  scan_kernel<<<dim3(1), dim3(64), 0, stream>>>(cnt, offs, tl_e, tl_m, ntl);
  fill_kernel<<<dim3(48), dim3(256), 0, stream>>>(tidx, tw, offs, curc, ptok, pw);

  tconv<<<dim3(512, NEXP), dim3(256), 0, stream>>>(wg, wgt, HD, FD);   // [H][F] -> [F][H]
  tconv<<<dim3(512, NEXP), dim3(256), 0, stream>>>(wu, wut, HD, FD);
  tconv<<<dim3(512, NEXP), dim3(256), 0, stream>>>(wd, wdt, FD, HD);   // [F][H] -> [H][F]
  fconv<<<dim3(4096), dim3(256), 0, stream>>>(sg, sgb);
  fconv<<<dim3(4096), dim3(256), 0, stream>>>(su, sub);
  fconv<<<dim3(4096), dim3(256), 0, stream>>>(sd, sdb);

  // shared first (shared_down stores y), then routed down accumulates atomically
  shared_gu_b<<<dim3(512), dim3(256), 0, stream>>>(xb, sgb, sub, sact);
  shared_down_b<<<dim3(256), dim3(256), 0, stream>>>(sact, sdb, y);
  gu_routed_b<<<dim3(2048), dim3(256), 0, stream>>>(xb, wgt, wut, ptok, pw, cnt, offs,
                                                    tl_e, tl_m, ntl, act);
  down_routed_b<<<dim3(2048), dim3(256), 0, stream>>>(act, wdt, ptok, cnt, offs,
                                                      tl_e, tl_m, ntl, y);
}

// Round 12
// 753.268 us; speedup vs baseline: 1.2085x; 1.1101x over previous
//
#include <hip/hip_runtime.h>

#define HD   2048
#define FD   1024
#define NEXP 32
#define TOPK 6
#define TT   2048
#define SDIM 2048
#define NPAIR (TT*TOPK)

typedef __bf16 bf16x8 __attribute__((ext_vector_type(8)));
typedef float  f32x4  __attribute__((ext_vector_type(4)));

#define GLOAD_LDS16(g, l) __builtin_amdgcn_global_load_lds( \
    (const __attribute__((address_space(1))) void*)(g),     \
    (__attribute__((address_space(3))) void*)(l), 16, 0, 0)

#define WAIT_VM4  asm volatile("s_waitcnt vmcnt(4)" ::: "memory")
#define WAIT_VM3  asm volatile("s_waitcnt vmcnt(3)" ::: "memory")
#define WAIT_VM0  asm volatile("s_waitcnt vmcnt(0)" ::: "memory")
// raw barrier: does NOT drain vmcnt (unlike __syncthreads) — T4 prerequisite
#define BAR() do { __builtin_amdgcn_s_barrier(); } while (0)

__device__ __forceinline__ ushort f2b(float f) {
  __bf16 h = (__bf16)f;
  union { __bf16 h; ushort u; } v; v.h = h;
  return v.u;
}

// bijective XCD swizzle over nact active blocks (m204)
__device__ __forceinline__ int xcd_swz(int bid, int nact) {
  int xcd = bid & 7, i = bid >> 3;
  int q = nact >> 3, r = nact & 7;
  int base = (xcd < r) ? xcd * (q + 1) : r * (q + 1) + (xcd - r) * q;
  return base + i;
}

// ---------------- gating (fp32 exact) ----------------
__device__ __forceinline__ void argmax32(float &v, int &i) {
  #pragma unroll
  for (int m = 16; m >= 1; m >>= 1) {
    float ov = __shfl_xor(v, m, 32);
    int   oi = __shfl_xor(i, m, 32);
    if (ov > v || (ov == v && oi < i)) { v = ov; i = oi; }
  }
}

__global__ __launch_bounds__(64) void gating_kernel(
    const float* __restrict__ x, const float* __restrict__ wgate,
    int* __restrict__ topk_idx, float* __restrict__ topk_w, int* __restrict__ cnt)
{
  int t = blockIdx.x;
  int l = threadIdx.x;
  int e = l & 31;
  int half = l >> 5;
  const float* xr = x + (size_t)t * HD + half * (HD/2);
  const float* wr = wgate + (size_t)e * HD + half * (HD/2);
  float acc = 0.f;
  for (int i = 0; i < HD/2; i += 4) {
    float4 a = *(const float4*)(xr + i);
    float4 b = *(const float4*)(wr + i);
    acc += a.x*b.x + a.y*b.y + a.z*b.z + a.w*b.w;
  }
  acc += __shfl_xor(acc, 32);
  float logit = acc;
  float mx = logit;
  #pragma unroll
  for (int m = 16; m >= 1; m >>= 1) mx = fmaxf(mx, __shfl_xor(mx, m, 32));
  float p = __expf(logit - mx);
  float s = p;
  #pragma unroll
  for (int m = 16; m >= 1; m >>= 1) s += __shfl_xor(s, m, 32);
  float score = p / s;
  float gs = score;
  gs = fmaxf(gs, __shfl_xor(gs, 1, 32));
  gs = fmaxf(gs, __shfl_xor(gs, 2, 32));
  int g = e >> 2;
  float gw = gs;
  bool ingroup = false;
  for (int r = 0; r < 3; ++r) {
    float v = gw; int gi = g;
    argmax32(v, gi);
    if (g == gi) { ingroup = true; gw = -1.f; }
  }
  float ms = ingroup ? score : 0.f;
  int myrank = -1;
  float denom = 1e-20f;
  float mw = ms;
  for (int r = 0; r < 6; ++r) {
    float v = mw; int ei = e;
    argmax32(v, ei);
    denom += v;
    if (e == ei) { myrank = r; mw = -1.f; }
  }
  if (l < 32 && myrank >= 0) {
    topk_idx[t*TOPK + myrank] = e;
    topk_w  [t*TOPK + myrank] = score / denom;
    atomicAdd(&cnt[e], 1);
  }
}

// tiles of 256 rows
__global__ void scan_kernel(const int* __restrict__ cnt, int* __restrict__ offs,
                            int* __restrict__ tl_e, int* __restrict__ tl_m, int* __restrict__ ntl) {
  if (threadIdx.x == 0) {
    int o = 0, nt = 0;
    for (int e = 0; e < NEXP; ++e) {
      offs[e] = o;
      for (int m = 0; m < cnt[e]; m += 256) { tl_e[nt] = e; tl_m[nt] = m; ++nt; }
      o += cnt[e];
    }
    ntl[0] = nt;
  }
}

__global__ void fill_kernel(const int* __restrict__ topk_idx, const float* __restrict__ topk_w,
                            const int* __restrict__ offs, int* __restrict__ cur,
                            int* __restrict__ pair_tok, float* __restrict__ pair_w)
{
  int idx = blockIdx.x * blockDim.x + threadIdx.x;
  if (idx >= NPAIR) return;
  int e = topk_idx[idx];
  int p = offs[e] + atomicAdd(&cur[e], 1);
  pair_tok[p] = idx / TOPK;
  pair_w[p]   = topk_w[idx];
}

__global__ void cvt_kernel(const float* __restrict__ x, ushort* __restrict__ xb) {
  int i = blockIdx.x * blockDim.x + threadIdx.x;
  float4 v = ((const float4*)x)[i];
  ((ushort4*)xb)[i] = make_ushort4(f2b(v.x), f2b(v.y), f2b(v.z), f2b(v.w));
}

__global__ __launch_bounds__(256) void fconv(const float* __restrict__ in, ushort* __restrict__ out) {
  int i = blockIdx.x * blockDim.x + threadIdx.x;
  float4 v = ((const float4*)in)[i];
  ((ushort4*)out)[i] = make_ushort4(f2b(v.x), f2b(v.y), f2b(v.z), f2b(v.w));
}

// transpose-convert: in [R][C] fp32 -> out [C][R] bf16. 64x64 tiles, coalesced writes.
#define TSTR 76
__global__ __launch_bounds__(256) void tconv(const float* __restrict__ in, ushort* __restrict__ out,
                                             int R, int C) {
  __shared__ ushort T[64*TSTR];
  int tiles_c = C >> 6;
  int bt = blockIdx.x;
  int r0 = (bt / tiles_c) << 6;
  int c0 = (bt % tiles_c) << 6;
  const float* src = in + (size_t)blockIdx.y * R * C;
  ushort* dst = out + (size_t)blockIdx.y * R * C;
  int t = threadIdx.x;
  int row = (t >> 4) << 2;      // 0..60 step 4
  int col4 = (t & 15) << 2;     // 0..60 step 4
  float vv[4][4];
  #pragma unroll
  for (int i = 0; i < 4; ++i) {
    float4 v = *(const float4*)(src + (size_t)(r0 + row + i) * C + c0 + col4);
    vv[i][0] = v.x; vv[i][1] = v.y; vv[i][2] = v.z; vv[i][3] = v.w;
  }
  #pragma unroll
  for (int cc = 0; cc < 4; ++cc)
    *(ushort4*)&T[(col4 + cc)*TSTR + row] =
      make_ushort4(f2b(vv[0][cc]), f2b(vv[1][cc]), f2b(vv[2][cc]), f2b(vv[3][cc]));
  __syncthreads();
  // write phase: 512 items of 8 ushorts (16B); item = oc*8 + seg
  #pragma unroll
  for (int p = 0; p < 2; ++p) {
    int item = t + p*256;
    int oc = item >> 3, seg = item & 7;
    ushort4 a = *(const ushort4*)&T[oc*TSTR + seg*8];
    ushort4 b = *(const ushort4*)&T[oc*TSTR + seg*8 + 4];
    ushort* d = dst + (size_t)(c0 + oc) * R + r0 + seg*8;
    *(ushort4*)(d)     = a;
    *(ushort4*)(d + 4) = b;
  }
}

// ===== routed GEMMs: BM=256, 512 thr / 8 waves, 3-buf depth-2, counted vmcnt, raw barriers =====

// routed gate+up: BM=256 BN=64(x2) BK=32; 3 loads/thread/step
__global__ __launch_bounds__(512, 4) void gu_routed_b(
    const ushort* __restrict__ xb, const ushort* __restrict__ wgt, const ushort* __restrict__ wut,
    const int* __restrict__ pair_tok, const float* __restrict__ pair_w,
    const int* __restrict__ cnt, const int* __restrict__ offs,
    const int* __restrict__ tl_e, const int* __restrict__ tl_m, const int* __restrict__ ntl,
    ushort* __restrict__ act)
{
  __shared__ ushort A[3][256*32];
  __shared__ ushort Bg[3][64*32];
  __shared__ ushort Bu[3][64*32];

  int nact = ntl[0] * 16;
  int bid = blockIdx.x;
  if (bid >= nact) return;
  int wid = xcd_swz(bid, nact);
  int tile = wid >> 4;
  int nt = wid & 15;
  int e  = tl_e[tile];
  int m0 = tl_m[tile];
  int ce = cnt[e];
  int oe = offs[e];
  int n0 = nt * 64;
  int tid = threadIdx.x, lane = tid & 63, w = tid >> 6;

  int csrc = (lane & 3) ^ ((lane >> 3) & 3);
  const ushort* asrc[2];
  #pragma unroll
  for (int j = 0; j < 2; ++j) {
    int r = (2*w + j)*16 + (lane >> 2);
    int pi = min(m0 + r, ce - 1);
    asrc[j] = xb + (size_t)pair_tok[oe + pi] * HD + csrc * 8;
  }
  int tsel = w >> 2;            // waves 0-3 gate, 4-7 up (wave-uniform)
  int bw = w & 3;               // 16-row group within B tile
  const ushort* bsrc = (tsel ? wut : wgt) +
      ((size_t)e * FD + n0 + bw*16 + (lane >> 2)) * HD + csrc * 8;
  ushort* bdst0 = tsel ? &Bu[0][bw*512] : &Bg[0][bw*512];
  ushort* bdst1 = tsel ? &Bu[1][bw*512] : &Bg[1][bw*512];
  ushort* bdst2 = tsel ? &Bu[2][bw*512] : &Bg[2][bw*512];

  int lm = lane & 15, lg = lane >> 4;
  int wr = w >> 1, wc = w & 1;
  int asw = (lm >> 1) & 3;

  f32x4 accg[4][2], accu[4][2];
  #pragma unroll
  for (int m = 0; m < 4; ++m)
    #pragma unroll
    for (int n = 0; n < 2; ++n) { accg[m][n] = f32x4{0,0,0,0}; accu[m][n] = f32x4{0,0,0,0}; }

  #define GUB_ISSUE(T, BUF, BD) do { \
    GLOAD_LDS16(asrc[0] + (T)*32, &A[BUF][(2*w)*512]); \
    GLOAD_LDS16(asrc[1] + (T)*32, &A[BUF][(2*w+1)*512]); \
    GLOAD_LDS16(bsrc + (T)*32, BD); \
  } while (0)
  #define GUB_COMPUTE(BUF) do { \
    bf16x8 a[4], bg[2], bu[2]; \
    _Pragma("unroll") \
    for (int m = 0; m < 4; ++m) \
      a[m] = *(const bf16x8*)&A[BUF][(wr*64 + m*16 + lm)*32 + (lg ^ asw)*8]; \
    _Pragma("unroll") \
    for (int n = 0; n < 2; ++n) { \
      int row = wc*32 + n*16 + lm; \
      bg[n] = *(const bf16x8*)&Bg[BUF][row*32 + (lg ^ asw)*8]; \
      bu[n] = *(const bf16x8*)&Bu[BUF][row*32 + (lg ^ asw)*8]; \
    } \
    _Pragma("unroll") \
    for (int m = 0; m < 4; ++m) \
      _Pragma("unroll") \
      for (int n = 0; n < 2; ++n) { \
        accg[m][n] = __builtin_amdgcn_mfma_f32_16x16x32_bf16(a[m], bg[n], accg[m][n], 0, 0, 0); \
        accu[m][n] = __builtin_amdgcn_mfma_f32_16x16x32_bf16(a[m], bu[n], accu[m][n], 0, 0, 0); \
      } \
  } while (0)

  GUB_ISSUE(0, 0, bdst0);
  GUB_ISSUE(1, 1, bdst1);
  WAIT_VM3;
  BAR();

  // steady: compute t=0..59; issue 2..61
  for (int tt = 0; tt < 20; ++tt) {
    int t = tt * 3;
    GUB_ISSUE(t+2, 2, bdst2); GUB_COMPUTE(0); WAIT_VM3; BAR();
    GUB_ISSUE(t+3, 0, bdst0); GUB_COMPUTE(1); WAIT_VM3; BAR();
    GUB_ISSUE(t+4, 1, bdst1); GUB_COMPUTE(2); WAIT_VM3; BAR();
  }
  GUB_ISSUE(62, 2, bdst2); GUB_COMPUTE(0); WAIT_VM3; BAR();   // t=60
  GUB_ISSUE(63, 0, bdst0); GUB_COMPUTE(1); WAIT_VM3; BAR();   // t=61
  GUB_COMPUTE(2); WAIT_VM0; BAR();                            // t=62
  GUB_COMPUTE(0);                                             // t=63
  #undef GUB_ISSUE
  #undef GUB_COMPUTE

  #pragma unroll
  for (int m = 0; m < 4; ++m) {
    #pragma unroll
    for (int j = 0; j < 4; ++j) {
      int rl = wr*64 + m*16 + lg*4 + j;
      int pi = m0 + rl;
      if (pi >= ce) continue;
      float pwv = pair_w[oe + pi];
      size_t base = (size_t)(oe + pi) * FD + n0 + wc*32;
      #pragma unroll
      for (int n = 0; n < 2; ++n) {
        float gv = accg[m][n][j];
        float uv = accu[m][n][j];
        float sv = gv / (1.f + __expf(-gv));
        act[base + n*16 + lm] = f2b(sv * uv * pwv);
      }
    }
  }
}

// routed down: BM=256 BN=128 BK=32; 3 loads/thread/step; atomic scatter (y pre-seeded)
__global__ __launch_bounds__(512, 4) void down_routed_b(
    const ushort* __restrict__ act, const ushort* __restrict__ wdt,
    const int* __restrict__ pair_tok, const int* __restrict__ cnt, const int* __restrict__ offs,
    const int* __restrict__ tl_e, const int* __restrict__ tl_m, const int* __restrict__ ntl,
    float* __restrict__ y)
{
  __shared__ ushort A[3][256*32];
  __shared__ ushort Bd[3][128*32];

  int nact = ntl[0] * 16;
  int bid = blockIdx.x;
  if (bid >= nact) return;
  int wid = xcd_swz(bid, nact);
  int tile = wid >> 4;
  int nt = wid & 15;
  int e  = tl_e[tile];
  int m0 = tl_m[tile];
  int ce = cnt[e];
  int oe = offs[e];
  int n0 = nt * 128;
  int tid = threadIdx.x, lane = tid & 63, w = tid >> 6;

  int csrc = (lane & 3) ^ ((lane >> 3) & 3);
  const ushort* asrc[2];
  #pragma unroll
  for (int j = 0; j < 2; ++j) {
    int r = (2*w + j)*16 + (lane >> 2);
    int pi = min(m0 + r, ce - 1);
    asrc[j] = act + (size_t)(oe + pi) * FD + csrc * 8;
  }
  const ushort* bsrc = wdt + ((size_t)e * HD + n0 + w*16 + (lane >> 2)) * FD + csrc * 8;

  int lm = lane & 15, lg = lane >> 4;
  int wr = w >> 1, wc = w & 1;
  int asw = (lm >> 1) & 3;

  f32x4 acc[4][4];
  #pragma unroll
  for (int m = 0; m < 4; ++m)
    #pragma unroll
    for (int n = 0; n < 4; ++n) acc[m][n] = f32x4{0,0,0,0};

  #define DNB_ISSUE(T, BUF) do { \
    GLOAD_LDS16(asrc[0] + (T)*32, &A[BUF][(2*w)*512]); \
    GLOAD_LDS16(asrc[1] + (T)*32, &A[BUF][(2*w+1)*512]); \
    GLOAD_LDS16(bsrc + (T)*32, &Bd[BUF][w*512]); \
  } while (0)
  #define DNB_COMPUTE(BUF) do { \
    bf16x8 a[4], b[4]; \
    _Pragma("unroll") \
    for (int m = 0; m < 4; ++m) \
      a[m] = *(const bf16x8*)&A[BUF][(wr*64 + m*16 + lm)*32 + (lg ^ asw)*8]; \
    _Pragma("unroll") \
    for (int n = 0; n < 4; ++n) { \
      int row = wc*64 + n*16 + lm; \
      b[n] = *(const bf16x8*)&Bd[BUF][row*32 + (lg ^ asw)*8]; \
    } \
    _Pragma("unroll") \
    for (int m = 0; m < 4; ++m) \
      _Pragma("unroll") \
      for (int n = 0; n < 4; ++n) \
        acc[m][n] = __builtin_amdgcn_mfma_f32_16x16x32_bf16(a[m], b[n], acc[m][n], 0, 0, 0); \
  } while (0)

  DNB_ISSUE(0, 0);
  DNB_ISSUE(1, 1);
  WAIT_VM3;
  BAR();

  // 32 K-steps: compute t=0..29 in loop; issues 2..31 (tt=9 issues 29,30,31)
  for (int tt = 0; tt < 10; ++tt) {
    int t = tt * 3;
    DNB_ISSUE(t+2, 2); DNB_COMPUTE(0); WAIT_VM3; BAR();
    DNB_ISSUE(t+3, 0); DNB_COMPUTE(1); WAIT_VM3; BAR();
    DNB_ISSUE(t+4, 1); DNB_COMPUTE(2); WAIT_VM3; BAR();
  }
  DNB_COMPUTE(0); WAIT_VM0; BAR();   // t=30 (buf0; step-30 loads covered by final VM3)
  DNB_COMPUTE(1);                    // t=31 (buf1; step-31 loads drained by VM0)
  #undef DNB_ISSUE
  #undef DNB_COMPUTE

  #pragma unroll
  for (int m = 0; m < 4; ++m) {
    #pragma unroll
    for (int j = 0; j < 4; ++j) {
      int rl = wr*64 + m*16 + lg*4 + j;
      int pi = m0 + rl;
      if (pi >= ce) continue;
      int tok = pair_tok[oe + pi];
      size_t base = (size_t)tok * HD + n0 + wc*64;
      #pragma unroll
      for (int n = 0; n < 4; ++n)
        atomicAdd(&y[base + n*16 + lm], acc[m][n][j]);
    }
  }
}

// shared gate+up: R9-proven 3-buf depth-2, BM=128, 256 thr
__global__ __launch_bounds__(256) void shared_gu_b(
    const ushort* __restrict__ xb, const ushort* __restrict__ sgb, const ushort* __restrict__ sub,
    ushort* __restrict__ sact)
{
  __shared__ ushort A[3][128*32];
  __shared__ ushort Bg[3][64*32];
  __shared__ ushort Bu[3][64*32];

  int bid = blockIdx.x;
  int wid = (bid & 7) * 64 + (bid >> 3);
  int mt = wid & 15;
  int nt = wid >> 4;
  int m0 = mt * 128;
  int n0 = nt * 64;
  int tid = threadIdx.x, lane = tid & 63, w = tid >> 6;

  int csrc = (lane & 3) ^ ((lane >> 3) & 3);
  const ushort* asrc[2];
  #pragma unroll
  for (int j = 0; j < 2; ++j) {
    int r = (2*w + j)*16 + (lane >> 2);
    asrc[j] = xb + (size_t)(m0 + r) * HD + csrc * 8;
  }
  int brow = w*16 + (lane >> 2);
  const ushort* bgsrc = sgb + (size_t)(n0 + brow) * HD + csrc * 8;
  const ushort* busrc = sub + (size_t)(n0 + brow) * HD + csrc * 8;

  int lm = lane & 15, lg = lane >> 4;
  int wr = w >> 1, wc = w & 1;
  int asw = (lm >> 1) & 3;

  f32x4 accg[4][2], accu[4][2];
  #pragma unroll
  for (int m = 0; m < 4; ++m)
    #pragma unroll
    for (int n = 0; n < 2; ++n) { accg[m][n] = f32x4{0,0,0,0}; accu[m][n] = f32x4{0,0,0,0}; }

  #define SGB_ISSUE(T, BUF) do { \
    GLOAD_LDS16(asrc[0] + (T)*32, &A[BUF][(2*w)*512]); \
    GLOAD_LDS16(asrc[1] + (T)*32, &A[BUF][(2*w+1)*512]); \
    GLOAD_LDS16(bgsrc + (T)*32, &Bg[BUF][w*512]); \
    GLOAD_LDS16(busrc + (T)*32, &Bu[BUF][w*512]); \
  } while (0)
  #define SGB_COMPUTE(BUF) do { \
    bf16x8 a[4], bg[2], bu[2]; \
    _Pragma("unroll") \
    for (int m = 0; m < 4; ++m) \
      a[m] = *(const bf16x8*)&A[BUF][(wr*64 + m*16 + lm)*32 + (lg ^ asw)*8]; \
    _Pragma("unroll") \
    for (int n = 0; n < 2; ++n) { \
      int row = wc*32 + n*16 + lm; \
      bg[n] = *(const bf16x8*)&Bg[BUF][row*32 + (lg ^ asw)*8]; \
      bu[n] = *(const bf16x8*)&Bu[BUF][row*32 + (lg ^ asw)*8]; \
    } \
    _Pragma("unroll") \
    for (int m = 0; m < 4; ++m) \
      _Pragma("unroll") \
      for (int n = 0; n < 2; ++n) { \
        accg[m][n] = __builtin_amdgcn_mfma_f32_16x16x32_bf16(a[m], bg[n], accg[m][n], 0, 0, 0); \
        accu[m][n] = __builtin_amdgcn_mfma_f32_16x16x32_bf16(a[m], bu[n], accu[m][n], 0, 0, 0); \
      } \
  } while (0)

  SGB_ISSUE(0, 0);
  SGB_ISSUE(1, 1);
  WAIT_VM4;
  BAR();

  for (int tt = 0; tt < 20; ++tt) {
    int t = tt * 3;
    SGB_ISSUE(t+2, 2); SGB_COMPUTE(0); WAIT_VM4; BAR();
    SGB_ISSUE(t+3, 0); SGB_COMPUTE(1); WAIT_VM4; BAR();
    SGB_ISSUE(t+4, 1); SGB_COMPUTE(2); WAIT_VM4; BAR();
  }
  SGB_ISSUE(62, 2); SGB_COMPUTE(0); WAIT_VM4; BAR();   // t=60
  SGB_ISSUE(63, 0); SGB_COMPUTE(1); WAIT_VM4; BAR();   // t=61
  SGB_COMPUTE(2); WAIT_VM0; BAR();                     // t=62
  SGB_COMPUTE(0);                                      // t=63
  #undef SGB_ISSUE
  #undef SGB_COMPUTE

  #pragma unroll
  for (int m = 0; m < 4; ++m) {
    #pragma unroll
    for (int j = 0; j < 4; ++j) {
      int rl = wr*64 + m*16 + lg*4 + j;
      size_t base = (size_t)(m0 + rl) * SDIM + n0 + wc*32;
      #pragma unroll
      for (int n = 0; n < 2; ++n) {
        float gv = accg[m][n][j];
        float uv = accu[m][n][j];
        float sv = gv / (1.f + __expf(-gv));
        sact[base + n*16 + lm] = f2b(sv * uv);
      }
    }
  }
}

// shared down: R9-proven 3-buf depth-2, STORES y
__global__ __launch_bounds__(256) void shared_down_b(
    const ushort* __restrict__ sact, const ushort* __restrict__ sdb, float* __restrict__ y)
{
  __shared__ ushort A[3][128*32];
  __shared__ ushort Bd[3][128*32];

  int bid = blockIdx.x;
  int wid = (bid & 7) * 32 + (bid >> 3);
  int mt = wid & 15;
  int nt = wid >> 4;
  int m0 = mt * 128;
  int n0 = nt * 128;
  int tid = threadIdx.x, lane = tid & 63, w = tid >> 6;

  int csrc = (lane & 3) ^ ((lane >> 3) & 3);
  const ushort* asrc[2];
  const ushort* bsrc[2];
  #pragma unroll
  for (int j = 0; j < 2; ++j) {
    int r = (2*w + j)*16 + (lane >> 2);
    asrc[j] = sact + (size_t)(m0 + r) * SDIM + csrc * 8;
    bsrc[j] = sdb + (size_t)(n0 + r) * SDIM + csrc * 8;
  }

  int lm = lane & 15, lg = lane >> 4;
  int wr = w >> 1, wc = w & 1;
  int asw = (lm >> 1) & 3;

  f32x4 acc[4][4];
  #pragma unroll
  for (int m = 0; m < 4; ++m)
    #pragma unroll
    for (int n = 0; n < 4; ++n) acc[m][n] = f32x4{0,0,0,0};

  #define SDB_ISSUE(T, BUF) do { \
    GLOAD_LDS16(asrc[0] + (T)*32, &A[BUF][(2*w)*512]); \
    GLOAD_LDS16(asrc[1] + (T)*32, &A[BUF][(2*w+1)*512]); \
    GLOAD_LDS16(bsrc[0] + (T)*32, &Bd[BUF][(2*w)*512]); \
    GLOAD_LDS16(bsrc[1] + (T)*32, &Bd[BUF][(2*w+1)*512]); \
  } while (0)
  #define SDB_COMPUTE(BUF) do { \
    bf16x8 a[4], b[4]; \
    _Pragma("unroll") \
    for (int m = 0; m < 4; ++m) \
      a[m] = *(const bf16x8*)&A[BUF][(wr*64 + m*16 + lm)*32 + (lg ^ asw)*8]; \
    _Pragma("unroll") \
    for (int n = 0; n < 4; ++n) { \
      int row = wc*64 + n*16 + lm; \
      b[n] = *(const bf16x8*)&Bd[BUF][row*32 + (lg ^ asw)*8]; \
    } \
    _Pragma("unroll") \
    for (int m = 0; m < 4; ++m) \
      _Pragma("unroll") \
      for (int n = 0; n < 4; ++n) \
        acc[m][n] = __builtin_amdgcn_mfma_f32_16x16x32_bf16(a[m], b[n], acc[m][n], 0, 0, 0); \
  } while (0)

  SDB_ISSUE(0, 0);
  SDB_ISSUE(1, 1);
  WAIT_VM4;
  BAR();

  for (int tt = 0; tt < 20; ++tt) {
    int t = tt * 3;
    SDB_ISSUE(t+2, 2); SDB_COMPUTE(0); WAIT_VM4; BAR();
    SDB_ISSUE(t+3, 0); SDB_COMPUTE(1); WAIT_VM4; BAR();
    SDB_ISSUE(t+4, 1); SDB_COMPUTE(2); WAIT_VM4; BAR();
  }
  SDB_ISSUE(62, 2); SDB_COMPUTE(0); WAIT_VM4; BAR();   // t=60
  SDB_ISSUE(63, 0); SDB_COMPUTE(1); WAIT_VM4; BAR();   // t=61
  SDB_COMPUTE(2); WAIT_VM0; BAR();                     // t=62
  SDB_COMPUTE(0);                                      // t=63
  #undef SDB_ISSUE
  #undef SDB_COMPUTE

  #pragma unroll
  for (int m = 0; m < 4; ++m) {
    #pragma unroll
    for (int j = 0; j < 4; ++j) {
      int rl = wr*64 + m*16 + lg*4 + j;
      size_t base = (size_t)(m0 + rl) * HD + n0 + wc*64;
      #pragma unroll
      for (int n = 0; n < 4; ++n)
        y[base + n*16 + lm] = acc[m][n][j];     // store, not +=
    }
  }
}

// ---------------- launch ----------------
extern "C" void kernel_launch(void* const* d_in, const int* in_sizes, int n_in,
                              void* d_out, int out_size, void* d_ws, size_t ws_size,
                              hipStream_t stream) {
  const float* x     = (const float*)d_in[0];
  const float* wgate = (const float*)d_in[1];
  const float* wg    = (const float*)d_in[2];
  const float* wu    = (const float*)d_in[3];
  const float* wd    = (const float*)d_in[4];
  const float* sg    = (const float*)d_in[5];
  const float* su    = (const float*)d_in[6];
  const float* sd    = (const float*)d_in[7];
  float* y = (float*)d_out;
  char* ws = (char*)d_ws;

  ushort* xb   = (ushort*)(ws + 0);
  ushort* act  = (ushort*)(ws + 8388608);
  ushort* sact = (ushort*)(ws + 33554432);
  int*    tidx = (int*)  (ws + 41943040);
  float*  tw   = (float*)(ws + 41992192);
  int*    ptok = (int*)  (ws + 42041344);
  float*  pw   = (float*)(ws + 42090496);
  int*    cnt  = (int*)  (ws + 42139648);
  int*    curc = (int*)  (ws + 42139776);
  int*    offs = (int*)  (ws + 42139904);
  int*    tl_e = (int*)  (ws + 42140160);
  int*    tl_m = (int*)  (ws + 42140672);
  int*    ntl  = (int*)  (ws + 42141184);
  ushort* wgt  = (ushort*)(ws + 50331648);    // 128 MB [E][F][H]
  ushort* wut  = (ushort*)(ws + 184549376);   // 128 MB
  ushort* wdt  = (ushort*)(ws + 318767104);   // 128 MB [E][H][F]
  ushort* sgb  = (ushort*)(ws + 452984832);   // 8 MB
  ushort* sub  = (ushort*)(ws + 461373440);
  ushort* sdb  = (ushort*)(ws + 469762048);

  hipMemsetAsync(cnt, 0, 512, stream);

  cvt_kernel<<<dim3(4096), dim3(256), 0, stream>>>(x, xb);
  gating_kernel<<<dim3(TT), dim3(64), 0, stream>>>(x, wgate, tidx, tw, cnt);
  scan_kernel<<<dim3(1), dim3(64), 0, stream>>>(cnt, offs, tl_e, tl_m, ntl);
  fill_kernel<<<dim3(48), dim3(256), 0, stream>>>(tidx, tw, offs, curc, ptok, pw);

  tconv<<<dim3(512, NEXP), dim3(256), 0, stream>>>(wg, wgt, HD, FD);   // [H][F] -> [F][H]
  tconv<<<dim3(512, NEXP), dim3(256), 0, stream>>>(wu, wut, HD, FD);
  tconv<<<dim3(512, NEXP), dim3(256), 0, stream>>>(wd, wdt, FD, HD);   // [F][H] -> [H][F]
  fconv<<<dim3(4096), dim3(256), 0, stream>>>(sg, sgb);
  fconv<<<dim3(4096), dim3(256), 0, stream>>>(su, sub);
  fconv<<<dim3(4096), dim3(256), 0, stream>>>(sd, sdb);

  // shared first (shared_down stores y), then routed down accumulates atomically
  shared_gu_b<<<dim3(512), dim3(256), 0, stream>>>(xb, sgb, sub, sact);
  shared_down_b<<<dim3(256), dim3(256), 0, stream>>>(sact, sdb, y);
  // max tiles: sum ceil(cnt/256) <= 32 + 12288/256 = 80 -> nact <= 1280
  gu_routed_b<<<dim3(1280), dim3(512), 0, stream>>>(xb, wgt, wut, ptok, pw, cnt, offs,
                                                    tl_e, tl_m, ntl, act);
  down_routed_b<<<dim3(1280), dim3(512), 0, stream>>>(act, wdt, ptok, cnt, offs,
                                                      tl_e, tl_m, ntl, y);
}

// Round 13
// 727.796 us; speedup vs baseline: 1.2508x; 1.0350x over previous
//
#include <hip/hip_runtime.h>

#define HD   2048
#define FD   1024
#define NEXP 32
#define TOPK 6
#define TT   2048
#define SDIM 2048
#define NPAIR (TT*TOPK)

typedef __bf16 bf16x8 __attribute__((ext_vector_type(8)));
typedef float  f32x4  __attribute__((ext_vector_type(4)));

#define GLOAD_LDS16(g, l) __builtin_amdgcn_global_load_lds( \
    (const __attribute__((address_space(1))) void*)(g),     \
    (__attribute__((address_space(3))) void*)(l), 16, 0, 0)

#define WAIT_VM3  asm volatile("s_waitcnt vmcnt(3)" ::: "memory")
#define WAIT_VM0  asm volatile("s_waitcnt vmcnt(0)" ::: "memory")
// raw barrier: does NOT drain vmcnt (unlike __syncthreads)
#define BAR() do { __builtin_amdgcn_s_barrier(); } while (0)

__device__ __forceinline__ ushort f2b(float f) {
  __bf16 h = (__bf16)f;
  union { __bf16 h; ushort u; } v; v.h = h;
  return v.u;
}
__device__ __forceinline__ float b2f(ushort u) {
  union { unsigned u; float f; } v; v.u = (unsigned)u << 16;
  return v.f;
}

// bijective XCD swizzle over nact active blocks (m204)
__device__ __forceinline__ int xcd_swz(int bid, int nact) {
  int xcd = bid & 7, i = bid >> 3;
  int q = nact >> 3, r = nact & 7;
  int base = (xcd < r) ? xcd * (q + 1) : r * (q + 1) + (xcd - r) * q;
  return base + i;
}

// ---------------- gating (fp32 exact) ----------------
__device__ __forceinline__ void argmax32(float &v, int &i) {
  #pragma unroll
  for (int m = 16; m >= 1; m >>= 1) {
    float ov = __shfl_xor(v, m, 32);
    int   oi = __shfl_xor(i, m, 32);
    if (ov > v || (ov == v && oi < i)) { v = ov; i = oi; }
  }
}

__global__ __launch_bounds__(64) void gating_kernel(
    const float* __restrict__ x, const float* __restrict__ wgate,
    int* __restrict__ topk_idx, float* __restrict__ topk_w, int* __restrict__ cnt)
{
  int t = blockIdx.x;
  int l = threadIdx.x;
  int e = l & 31;
  int half = l >> 5;
  const float* xr = x + (size_t)t * HD + half * (HD/2);
  const float* wr = wgate + (size_t)e * HD + half * (HD/2);
  float acc = 0.f;
  for (int i = 0; i < HD/2; i += 4) {
    float4 a = *(const float4*)(xr + i);
    float4 b = *(const float4*)(wr + i);
    acc += a.x*b.x + a.y*b.y + a.z*b.z + a.w*b.w;
  }
  acc += __shfl_xor(acc, 32);
  float logit = acc;
  float mx = logit;
  #pragma unroll
  for (int m = 16; m >= 1; m >>= 1) mx = fmaxf(mx, __shfl_xor(mx, m, 32));
  float p = __expf(logit - mx);
  float s = p;
  #pragma unroll
  for (int m = 16; m >= 1; m >>= 1) s += __shfl_xor(s, m, 32);
  float score = p / s;
  float gs = score;
  gs = fmaxf(gs, __shfl_xor(gs, 1, 32));
  gs = fmaxf(gs, __shfl_xor(gs, 2, 32));
  int g = e >> 2;
  float gw = gs;
  bool ingroup = false;
  for (int r = 0; r < 3; ++r) {
    float v = gw; int gi = g;
    argmax32(v, gi);
    if (g == gi) { ingroup = true; gw = -1.f; }
  }
  float ms = ingroup ? score : 0.f;
  int myrank = -1;
  float denom = 1e-20f;
  float mw = ms;
  for (int r = 0; r < 6; ++r) {
    float v = mw; int ei = e;
    argmax32(v, ei);
    denom += v;
    if (e == ei) { myrank = r; mw = -1.f; }
  }
  if (l < 32 && myrank >= 0) {
    topk_idx[t*TOPK + myrank] = e;
    topk_w  [t*TOPK + myrank] = score / denom;
    atomicAdd(&cnt[e], 1);
  }
}

// tiles of 256 rows
__global__ void scan_kernel(const int* __restrict__ cnt, int* __restrict__ offs,
                            int* __restrict__ tl_e, int* __restrict__ tl_m, int* __restrict__ ntl) {
  if (threadIdx.x == 0) {
    int o = 0, nt = 0;
    for (int e = 0; e < NEXP; ++e) {
      offs[e] = o;
      for (int m = 0; m < cnt[e]; m += 256) { tl_e[nt] = e; tl_m[nt] = m; ++nt; }
      o += cnt[e];
    }
    ntl[0] = nt;
  }
}

__global__ void fill_kernel(const int* __restrict__ topk_idx, const float* __restrict__ topk_w,
                            const int* __restrict__ offs, int* __restrict__ cur,
                            int* __restrict__ pair_tok, float* __restrict__ pair_w,
                            int* __restrict__ inv)
{
  int idx = blockIdx.x * blockDim.x + threadIdx.x;
  if (idx >= NPAIR) return;
  int e = topk_idx[idx];
  int p = offs[e] + atomicAdd(&cur[e], 1);
  pair_tok[p] = idx / TOPK;
  pair_w[p]   = topk_w[idx];
  inv[idx]    = p;
}

__global__ void cvt_kernel(const float* __restrict__ x, ushort* __restrict__ xb) {
  int i = blockIdx.x * blockDim.x + threadIdx.x;
  float4 v = ((const float4*)x)[i];
  ((ushort4*)xb)[i] = make_ushort4(f2b(v.x), f2b(v.y), f2b(v.z), f2b(v.w));
}

__global__ __launch_bounds__(256) void fconv(const float* __restrict__ in, ushort* __restrict__ out) {
  int i = blockIdx.x * blockDim.x + threadIdx.x;
  float4 v = ((const float4*)in)[i];
  ((ushort4*)out)[i] = make_ushort4(f2b(v.x), f2b(v.y), f2b(v.z), f2b(v.w));
}

// transpose-convert: in [R][C] fp32 -> out [C][R] bf16. 64x64 tiles, coalesced writes.
#define TSTR 76
__global__ __launch_bounds__(256) void tconv(const float* __restrict__ in, ushort* __restrict__ out,
                                             int R, int C) {
  __shared__ ushort T[64*TSTR];
  int tiles_c = C >> 6;
  int bt = blockIdx.x;
  int r0 = (bt / tiles_c) << 6;
  int c0 = (bt % tiles_c) << 6;
  const float* src = in + (size_t)blockIdx.y * R * C;
  ushort* dst = out + (size_t)blockIdx.y * R * C;
  int t = threadIdx.x;
  int row = (t >> 4) << 2;
  int col4 = (t & 15) << 2;
  float vv[4][4];
  #pragma unroll
  for (int i = 0; i < 4; ++i) {
    float4 v = *(const float4*)(src + (size_t)(r0 + row + i) * C + c0 + col4);
    vv[i][0] = v.x; vv[i][1] = v.y; vv[i][2] = v.z; vv[i][3] = v.w;
  }
  #pragma unroll
  for (int cc = 0; cc < 4; ++cc)
    *(ushort4*)&T[(col4 + cc)*TSTR + row] =
      make_ushort4(f2b(vv[0][cc]), f2b(vv[1][cc]), f2b(vv[2][cc]), f2b(vv[3][cc]));
  __syncthreads();
  #pragma unroll
  for (int p = 0; p < 2; ++p) {
    int item = t + p*256;
    int oc = item >> 3, seg = item & 7;
    ushort4 a = *(const ushort4*)&T[oc*TSTR + seg*8];
    ushort4 b = *(const ushort4*)&T[oc*TSTR + seg*8 + 4];
    ushort* d = dst + (size_t)(c0 + oc) * R + r0 + seg*8;
    *(ushort4*)(d)     = a;
    *(ushort4*)(d + 4) = b;
  }
}

// combine: y[t] += sum_r pairout[inv[t*6+r]]
__global__ __launch_bounds__(256) void combine_kernel(
    const ushort* __restrict__ pairout, const int* __restrict__ inv, float* __restrict__ y)
{
  int t = blockIdx.x;
  int h0 = threadIdx.x * 8;
  const int* iv = inv + t*TOPK;
  float* yr = y + (size_t)t * HD + h0;
  float4 y0 = *(const float4*)(yr);
  float4 y1 = *(const float4*)(yr + 4);
  float acc[8] = {y0.x, y0.y, y0.z, y0.w, y1.x, y1.y, y1.z, y1.w};
  #pragma unroll
  for (int r = 0; r < TOPK; ++r) {
    int p = iv[r];
    const ushort* pr = pairout + (size_t)p * HD + h0;
    ushort4 a = *(const ushort4*)(pr);
    ushort4 b = *(const ushort4*)(pr + 4);
    acc[0] += b2f(a.x); acc[1] += b2f(a.y); acc[2] += b2f(a.z); acc[3] += b2f(a.w);
    acc[4] += b2f(b.x); acc[5] += b2f(b.y); acc[6] += b2f(b.z); acc[7] += b2f(b.w);
  }
  *(float4*)(yr)     = make_float4(acc[0], acc[1], acc[2], acc[3]);
  *(float4*)(yr + 4) = make_float4(acc[4], acc[5], acc[6], acc[7]);
}

// ===== GEMMs: BM=256, 512 thr / 8 waves, 3-buf depth-2, counted vmcnt, raw barriers =====

// routed gate+up: BM=256 BN=64(x2) BK=32
__global__ __launch_bounds__(512, 4) void gu_routed_b(
    const ushort* __restrict__ xb, const ushort* __restrict__ wgt, const ushort* __restrict__ wut,
    const int* __restrict__ pair_tok, const float* __restrict__ pair_w,
    const int* __restrict__ cnt, const int* __restrict__ offs,
    const int* __restrict__ tl_e, const int* __restrict__ tl_m, const int* __restrict__ ntl,
    ushort* __restrict__ act)
{
  __shared__ ushort A[3][256*32];
  __shared__ ushort Bg[3][64*32];
  __shared__ ushort Bu[3][64*32];

  int nact = ntl[0] * 16;
  int bid = blockIdx.x;
  if (bid >= nact) return;
  int wid = xcd_swz(bid, nact);
  int tile = wid >> 4;
  int nt = wid & 15;
  int e  = tl_e[tile];
  int m0 = tl_m[tile];
  int ce = cnt[e];
  int oe = offs[e];
  int n0 = nt * 64;
  int tid = threadIdx.x, lane = tid & 63, w = tid >> 6;

  int csrc = (lane & 3) ^ ((lane >> 3) & 3);
  const ushort* asrc[2];
  #pragma unroll
  for (int j = 0; j < 2; ++j) {
    int r = (2*w + j)*16 + (lane >> 2);
    int pi = min(m0 + r, ce - 1);
    asrc[j] = xb + (size_t)pair_tok[oe + pi] * HD + csrc * 8;
  }
  int tsel = w >> 2;
  int bw = w & 3;
  const ushort* bsrc = (tsel ? wut : wgt) +
      ((size_t)e * FD + n0 + bw*16 + (lane >> 2)) * HD + csrc * 8;
  ushort* bdst0 = tsel ? &Bu[0][bw*512] : &Bg[0][bw*512];
  ushort* bdst1 = tsel ? &Bu[1][bw*512] : &Bg[1][bw*512];
  ushort* bdst2 = tsel ? &Bu[2][bw*512] : &Bg[2][bw*512];

  int lm = lane & 15, lg = lane >> 4;
  int wr = w >> 1, wc = w & 1;
  int asw = (lm >> 1) & 3;

  f32x4 accg[4][2], accu[4][2];
  #pragma unroll
  for (int m = 0; m < 4; ++m)
    #pragma unroll
    for (int n = 0; n < 2; ++n) { accg[m][n] = f32x4{0,0,0,0}; accu[m][n] = f32x4{0,0,0,0}; }

  #define GUB_ISSUE(T, BUF, BD) do { \
    GLOAD_LDS16(asrc[0] + (T)*32, &A[BUF][(2*w)*512]); \
    GLOAD_LDS16(asrc[1] + (T)*32, &A[BUF][(2*w+1)*512]); \
    GLOAD_LDS16(bsrc + (T)*32, BD); \
  } while (0)
  #define GUB_COMPUTE(BUF) do { \
    bf16x8 a[4], bg[2], bu[2]; \
    _Pragma("unroll") \
    for (int m = 0; m < 4; ++m) \
      a[m] = *(const bf16x8*)&A[BUF][(wr*64 + m*16 + lm)*32 + (lg ^ asw)*8]; \
    _Pragma("unroll") \
    for (int n = 0; n < 2; ++n) { \
      int row = wc*32 + n*16 + lm; \
      bg[n] = *(const bf16x8*)&Bg[BUF][row*32 + (lg ^ asw)*8]; \
      bu[n] = *(const bf16x8*)&Bu[BUF][row*32 + (lg ^ asw)*8]; \
    } \
    _Pragma("unroll") \
    for (int m = 0; m < 4; ++m) \
      _Pragma("unroll") \
      for (int n = 0; n < 2; ++n) { \
        accg[m][n] = __builtin_amdgcn_mfma_f32_16x16x32_bf16(a[m], bg[n], accg[m][n], 0, 0, 0); \
        accu[m][n] = __builtin_amdgcn_mfma_f32_16x16x32_bf16(a[m], bu[n], accu[m][n], 0, 0, 0); \
      } \
  } while (0)

  GUB_ISSUE(0, 0, bdst0);
  GUB_ISSUE(1, 1, bdst1);
  WAIT_VM3;
  BAR();

  for (int tt = 0; tt < 20; ++tt) {
    int t = tt * 3;
    GUB_ISSUE(t+2, 2, bdst2); GUB_COMPUTE(0); WAIT_VM3; BAR();
    GUB_ISSUE(t+3, 0, bdst0); GUB_COMPUTE(1); WAIT_VM3; BAR();
    GUB_ISSUE(t+4, 1, bdst1); GUB_COMPUTE(2); WAIT_VM3; BAR();
  }
  GUB_ISSUE(62, 2, bdst2); GUB_COMPUTE(0); WAIT_VM3; BAR();   // t=60
  GUB_ISSUE(63, 0, bdst0); GUB_COMPUTE(1); WAIT_VM3; BAR();   // t=61
  GUB_COMPUTE(2); WAIT_VM0; BAR();                            // t=62
  GUB_COMPUTE(0);                                             // t=63
  #undef GUB_ISSUE
  #undef GUB_COMPUTE

  #pragma unroll
  for (int m = 0; m < 4; ++m) {
    #pragma unroll
    for (int j = 0; j < 4; ++j) {
      int rl = wr*64 + m*16 + lg*4 + j;
      int pi = m0 + rl;
      if (pi >= ce) continue;
      float pwv = pair_w[oe + pi];
      size_t base = (size_t)(oe + pi) * FD + n0 + wc*32;
      #pragma unroll
      for (int n = 0; n < 2; ++n) {
        float gv = accg[m][n][j];
        float uv = accu[m][n][j];
        float sv = gv / (1.f + __expf(-gv));
        act[base + n*16 + lm] = f2b(sv * uv * pwv);
      }
    }
  }
}

// routed down: BM=256 BN=128 BK=32; stores bf16 pair rows (no atomics)
__global__ __launch_bounds__(512, 4) void down_routed_b(
    const ushort* __restrict__ act, const ushort* __restrict__ wdt,
    const int* __restrict__ cnt, const int* __restrict__ offs,
    const int* __restrict__ tl_e, const int* __restrict__ tl_m, const int* __restrict__ ntl,
    ushort* __restrict__ pairout)
{
  __shared__ ushort A[3][256*32];
  __shared__ ushort Bd[3][128*32];

  int nact = ntl[0] * 16;
  int bid = blockIdx.x;
  if (bid >= nact) return;
  int wid = xcd_swz(bid, nact);
  int tile = wid >> 4;
  int nt = wid & 15;
  int e  = tl_e[tile];
  int m0 = tl_m[tile];
  int ce = cnt[e];
  int oe = offs[e];
  int n0 = nt * 128;
  int tid = threadIdx.x, lane = tid & 63, w = tid >> 6;

  int csrc = (lane & 3) ^ ((lane >> 3) & 3);
  const ushort* asrc[2];
  #pragma unroll
  for (int j = 0; j < 2; ++j) {
    int r = (2*w + j)*16 + (lane >> 2);
    int pi = min(m0 + r, ce - 1);
    asrc[j] = act + (size_t)(oe + pi) * FD + csrc * 8;
  }
  const ushort* bsrc = wdt + ((size_t)e * HD + n0 + w*16 + (lane >> 2)) * FD + csrc * 8;

  int lm = lane & 15, lg = lane >> 4;
  int wr = w >> 1, wc = w & 1;
  int asw = (lm >> 1) & 3;

  f32x4 acc[4][4];
  #pragma unroll
  for (int m = 0; m < 4; ++m)
    #pragma unroll
    for (int n = 0; n < 4; ++n) acc[m][n] = f32x4{0,0,0,0};

  #define DNB_ISSUE(T, BUF) do { \
    GLOAD_LDS16(asrc[0] + (T)*32, &A[BUF][(2*w)*512]); \
    GLOAD_LDS16(asrc[1] + (T)*32, &A[BUF][(2*w+1)*512]); \
    GLOAD_LDS16(bsrc + (T)*32, &Bd[BUF][w*512]); \
  } while (0)
  #define DNB_COMPUTE(BUF) do { \
    bf16x8 a[4], b[4]; \
    _Pragma("unroll") \
    for (int m = 0; m < 4; ++m) \
      a[m] = *(const bf16x8*)&A[BUF][(wr*64 + m*16 + lm)*32 + (lg ^ asw)*8]; \
    _Pragma("unroll") \
    for (int n = 0; n < 4; ++n) { \
      int row = wc*64 + n*16 + lm; \
      b[n] = *(const bf16x8*)&Bd[BUF][row*32 + (lg ^ asw)*8]; \
    } \
    _Pragma("unroll") \
    for (int m = 0; m < 4; ++m) \
      _Pragma("unroll") \
      for (int n = 0; n < 4; ++n) \
        acc[m][n] = __builtin_amdgcn_mfma_f32_16x16x32_bf16(a[m], b[n], acc[m][n], 0, 0, 0); \
  } while (0)

  DNB_ISSUE(0, 0);
  DNB_ISSUE(1, 1);
  WAIT_VM3;
  BAR();

  // 32 K-steps: compute t=0..29 in loop; issues 2..31 (tt=9 issues 29,30,31)
  for (int tt = 0; tt < 10; ++tt) {
    int t = tt * 3;
    DNB_ISSUE(t+2, 2); DNB_COMPUTE(0); WAIT_VM3; BAR();
    DNB_ISSUE(t+3, 0); DNB_COMPUTE(1); WAIT_VM3; BAR();
    DNB_ISSUE(t+4, 1); DNB_COMPUTE(2); WAIT_VM3; BAR();
  }
  DNB_COMPUTE(0); WAIT_VM0; BAR();   // t=30
  DNB_COMPUTE(1);                    // t=31
  #undef DNB_ISSUE
  #undef DNB_COMPUTE

  #pragma unroll
  for (int m = 0; m < 4; ++m) {
    #pragma unroll
    for (int j = 0; j < 4; ++j) {
      int rl = wr*64 + m*16 + lg*4 + j;
      int pi = m0 + rl;
      if (pi >= ce) continue;
      size_t base = (size_t)(oe + pi) * HD + n0 + wc*64;
      #pragma unroll
      for (int n = 0; n < 4; ++n)
        pairout[base + n*16 + lm] = f2b(acc[m][n][j]);
    }
  }
}

// shared gate+up: BM=256, 512 thr (same pipeline as gu_routed_b, direct rows)
__global__ __launch_bounds__(512, 4) void shared_gu_b(
    const ushort* __restrict__ xb, const ushort* __restrict__ sgb, const ushort* __restrict__ sub,
    ushort* __restrict__ sact)
{
  __shared__ ushort A[3][256*32];
  __shared__ ushort Bg[3][64*32];
  __shared__ ushort Bu[3][64*32];

  int bid = blockIdx.x;
  int wid = (bid & 7) * 32 + (bid >> 3);   // 256 blocks
  int mt = wid & 7;
  int nt = wid >> 3;        // 0..31
  int m0 = mt * 256;
  int n0 = nt * 64;
  int tid = threadIdx.x, lane = tid & 63, w = tid >> 6;

  int csrc = (lane & 3) ^ ((lane >> 3) & 3);
  const ushort* asrc[2];
  #pragma unroll
  for (int j = 0; j < 2; ++j) {
    int r = (2*w + j)*16 + (lane >> 2);
    asrc[j] = xb + (size_t)(m0 + r) * HD + csrc * 8;
  }
  int tsel = w >> 2;
  int bw = w & 3;
  const ushort* bsrc = (tsel ? sub : sgb) + (size_t)(n0 + bw*16 + (lane >> 2)) * HD + csrc * 8;
  ushort* bdst0 = tsel ? &Bu[0][bw*512] : &Bg[0][bw*512];
  ushort* bdst1 = tsel ? &Bu[1][bw*512] : &Bg[1][bw*512];
  ushort* bdst2 = tsel ? &Bu[2][bw*512] : &Bg[2][bw*512];

  int lm = lane & 15, lg = lane >> 4;
  int wr = w >> 1, wc = w & 1;
  int asw = (lm >> 1) & 3;

  f32x4 accg[4][2], accu[4][2];
  #pragma unroll
  for (int m = 0; m < 4; ++m)
    #pragma unroll
    for (int n = 0; n < 2; ++n) { accg[m][n] = f32x4{0,0,0,0}; accu[m][n] = f32x4{0,0,0,0}; }

  #define SGB_ISSUE(T, BUF, BD) do { \
    GLOAD_LDS16(asrc[0] + (T)*32, &A[BUF][(2*w)*512]); \
    GLOAD_LDS16(asrc[1] + (T)*32, &A[BUF][(2*w+1)*512]); \
    GLOAD_LDS16(bsrc + (T)*32, BD); \
  } while (0)
  #define SGB_COMPUTE(BUF) do { \
    bf16x8 a[4], bg[2], bu[2]; \
    _Pragma("unroll") \
    for (int m = 0; m < 4; ++m) \
      a[m] = *(const bf16x8*)&A[BUF][(wr*64 + m*16 + lm)*32 + (lg ^ asw)*8]; \
    _Pragma("unroll") \
    for (int n = 0; n < 2; ++n) { \
      int row = wc*32 + n*16 + lm; \
      bg[n] = *(const bf16x8*)&Bg[BUF][row*32 + (lg ^ asw)*8]; \
      bu[n] = *(const bf16x8*)&Bu[BUF][row*32 + (lg ^ asw)*8]; \
    } \
    _Pragma("unroll") \
    for (int m = 0; m < 4; ++m) \
      _Pragma("unroll") \
      for (int n = 0; n < 2; ++n) { \
        accg[m][n] = __builtin_amdgcn_mfma_f32_16x16x32_bf16(a[m], bg[n], accg[m][n], 0, 0, 0); \
        accu[m][n] = __builtin_amdgcn_mfma_f32_16x16x32_bf16(a[m], bu[n], accu[m][n], 0, 0, 0); \
      } \
  } while (0)

  SGB_ISSUE(0, 0, bdst0);
  SGB_ISSUE(1, 1, bdst1);
  WAIT_VM3;
  BAR();

  for (int tt = 0; tt < 20; ++tt) {
    int t = tt * 3;
    SGB_ISSUE(t+2, 2, bdst2); SGB_COMPUTE(0); WAIT_VM3; BAR();
    SGB_ISSUE(t+3, 0, bdst0); SGB_COMPUTE(1); WAIT_VM3; BAR();
    SGB_ISSUE(t+4, 1, bdst1); SGB_COMPUTE(2); WAIT_VM3; BAR();
  }
  SGB_ISSUE(62, 2, bdst2); SGB_COMPUTE(0); WAIT_VM3; BAR();   // t=60
  SGB_ISSUE(63, 0, bdst0); SGB_COMPUTE(1); WAIT_VM3; BAR();   // t=61
  SGB_COMPUTE(2); WAIT_VM0; BAR();                            // t=62
  SGB_COMPUTE(0);                                             // t=63
  #undef SGB_ISSUE
  #undef SGB_COMPUTE

  #pragma unroll
  for (int m = 0; m < 4; ++m) {
    #pragma unroll
    for (int j = 0; j < 4; ++j) {
      int rl = wr*64 + m*16 + lg*4 + j;
      size_t base = (size_t)(m0 + rl) * SDIM + n0 + wc*32;
      #pragma unroll
      for (int n = 0; n < 2; ++n) {
        float gv = accg[m][n][j];
        float uv = accu[m][n][j];
        float sv = gv / (1.f + __expf(-gv));
        sact[base + n*16 + lm] = f2b(sv * uv);
      }
    }
  }
}

// shared down: BM=256, 512 thr, K=SDIM (64 steps), STORES y
__global__ __launch_bounds__(512, 4) void shared_down_b(
    const ushort* __restrict__ sact, const ushort* __restrict__ sdb, float* __restrict__ y)
{
  __shared__ ushort A[3][256*32];
  __shared__ ushort Bd[3][128*32];

  int bid = blockIdx.x;
  int wid = (bid & 7) * 16 + (bid >> 3);   // 128 blocks
  int mt = wid & 7;
  int nt = wid >> 3;        // 0..15
  int m0 = mt * 256;
  int n0 = nt * 128;
  int tid = threadIdx.x, lane = tid & 63, w = tid >> 6;

  int csrc = (lane & 3) ^ ((lane >> 3) & 3);
  const ushort* asrc[2];
  #pragma unroll
  for (int j = 0; j < 2; ++j) {
    int r = (2*w + j)*16 + (lane >> 2);
    asrc[j] = sact + (size_t)(m0 + r) * SDIM + csrc * 8;
  }
  const ushort* bsrc = sdb + (size_t)(n0 + w*16 + (lane >> 2)) * SDIM + csrc * 8;

  int lm = lane & 15, lg = lane >> 4;
  int wr = w >> 1, wc = w & 1;
  int asw = (lm >> 1) & 3;

  f32x4 acc[4][4];
  #pragma unroll
  for (int m = 0; m < 4; ++m)
    #pragma unroll
    for (int n = 0; n < 4; ++n) acc[m][n] = f32x4{0,0,0,0};

  #define SDB_ISSUE(T, BUF) do { \
    GLOAD_LDS16(asrc[0] + (T)*32, &A[BUF][(2*w)*512]); \
    GLOAD_LDS16(asrc[1] + (T)*32, &A[BUF][(2*w+1)*512]); \
    GLOAD_LDS16(bsrc + (T)*32, &Bd[BUF][w*512]); \
  } while (0)
  #define SDB_COMPUTE(BUF) do { \
    bf16x8 a[4], b[4]; \
    _Pragma("unroll") \
    for (int m = 0; m < 4; ++m) \
      a[m] = *(const bf16x8*)&A[BUF][(wr*64 + m*16 + lm)*32 + (lg ^ asw)*8]; \
    _Pragma("unroll") \
    for (int n = 0; n < 4; ++n) { \
      int row = wc*64 + n*16 + lm; \
      b[n] = *(const bf16x8*)&Bd[BUF][row*32 + (lg ^ asw)*8]; \
    } \
    _Pragma("unroll") \
    for (int m = 0; m < 4; ++m) \
      _Pragma("unroll") \
      for (int n = 0; n < 4; ++n) \
        acc[m][n] = __builtin_amdgcn_mfma_f32_16x16x32_bf16(a[m], b[n], acc[m][n], 0, 0, 0); \
  } while (0)

  SDB_ISSUE(0, 0);
  SDB_ISSUE(1, 1);
  WAIT_VM3;
  BAR();

  for (int tt = 0; tt < 20; ++tt) {
    int t = tt * 3;
    SDB_ISSUE(t+2, 2); SDB_COMPUTE(0); WAIT_VM3; BAR();
    SDB_ISSUE(t+3, 0); SDB_COMPUTE(1); WAIT_VM3; BAR();
    SDB_ISSUE(t+4, 1); SDB_COMPUTE(2); WAIT_VM3; BAR();
  }
  SDB_ISSUE(62, 2); SDB_COMPUTE(0); WAIT_VM3; BAR();   // t=60
  SDB_ISSUE(63, 0); SDB_COMPUTE(1); WAIT_VM3; BAR();   // t=61
  SDB_COMPUTE(2); WAIT_VM0; BAR();                     // t=62
  SDB_COMPUTE(0);                                      // t=63
  #undef SDB_ISSUE
  #undef SDB_COMPUTE

  #pragma unroll
  for (int m = 0; m < 4; ++m) {
    #pragma unroll
    for (int j = 0; j < 4; ++j) {
      int rl = wr*64 + m*16 + lg*4 + j;
      size_t base = (size_t)(m0 + rl) * HD + n0 + wc*64;
      #pragma unroll
      for (int n = 0; n < 4; ++n)
        y[base + n*16 + lm] = acc[m][n][j];     // store (combine adds routed)
    }
  }
}

// ---------------- launch ----------------
extern "C" void kernel_launch(void* const* d_in, const int* in_sizes, int n_in,
                              void* d_out, int out_size, void* d_ws, size_t ws_size,
                              hipStream_t stream) {
  const float* x     = (const float*)d_in[0];
  const float* wgate = (const float*)d_in[1];
  const float* wg    = (const float*)d_in[2];
  const float* wu    = (const float*)d_in[3];
  const float* wd    = (const float*)d_in[4];
  const float* sg    = (const float*)d_in[5];
  const float* su    = (const float*)d_in[6];
  const float* sd    = (const float*)d_in[7];
  float* y = (float*)d_out;
  char* ws = (char*)d_ws;

  ushort* xb   = (ushort*)(ws + 0);
  ushort* act  = (ushort*)(ws + 8388608);
  ushort* sact = (ushort*)(ws + 33554432);
  int*    tidx = (int*)  (ws + 41943040);
  float*  tw   = (float*)(ws + 41992192);
  int*    ptok = (int*)  (ws + 42041344);
  float*  pw   = (float*)(ws + 42090496);
  int*    cnt  = (int*)  (ws + 42139648);
  int*    curc = (int*)  (ws + 42139776);
  int*    offs = (int*)  (ws + 42139904);
  int*    tl_e = (int*)  (ws + 42140160);
  int*    tl_m = (int*)  (ws + 42140672);
  int*    ntl  = (int*)  (ws + 42141184);
  int*    inv  = (int*)  (ws + 42141440);     // 49152 B
  ushort* wgt  = (ushort*)(ws + 50331648);    // 128 MB [E][F][H]
  ushort* wut  = (ushort*)(ws + 184549376);   // 128 MB
  ushort* wdt  = (ushort*)(ws + 318767104);   // 128 MB [E][H][F]
  ushort* sgb  = (ushort*)(ws + 452984832);   // 8 MB
  ushort* sub  = (ushort*)(ws + 461373440);
  ushort* sdb  = (ushort*)(ws + 469762048);
  // pairout ALIASES wgt: gu (last reader of wgt) completes before down writes it
  ushort* pairout = wgt;                       // 50,331,648 B needed < 128 MB

  hipMemsetAsync(cnt, 0, 512, stream);

  cvt_kernel<<<dim3(4096), dim3(256), 0, stream>>>(x, xb);
  gating_kernel<<<dim3(TT), dim3(64), 0, stream>>>(x, wgate, tidx, tw, cnt);
  scan_kernel<<<dim3(1), dim3(64), 0, stream>>>(cnt, offs, tl_e, tl_m, ntl);
  fill_kernel<<<dim3(48), dim3(256), 0, stream>>>(tidx, tw, offs, curc, ptok, pw, inv);

  tconv<<<dim3(512, NEXP), dim3(256), 0, stream>>>(wg, wgt, HD, FD);   // [H][F] -> [F][H]
  tconv<<<dim3(512, NEXP), dim3(256), 0, stream>>>(wu, wut, HD, FD);
  tconv<<<dim3(512, NEXP), dim3(256), 0, stream>>>(wd, wdt, FD, HD);   // [F][H] -> [H][F]
  fconv<<<dim3(4096), dim3(256), 0, stream>>>(sg, sgb);
  fconv<<<dim3(4096), dim3(256), 0, stream>>>(su, sub);
  fconv<<<dim3(4096), dim3(256), 0, stream>>>(sd, sdb);

  shared_gu_b<<<dim3(256), dim3(512), 0, stream>>>(xb, sgb, sub, sact);
  shared_down_b<<<dim3(128), dim3(512), 0, stream>>>(sact, sdb, y);
  gu_routed_b<<<dim3(1280), dim3(512), 0, stream>>>(xb, wgt, wut, ptok, pw, cnt, offs,
                                                    tl_e, tl_m, ntl, act);
  down_routed_b<<<dim3(1280), dim3(512), 0, stream>>>(act, wdt, cnt, offs,
                                                      tl_e, tl_m, ntl, pairout);
  combine_kernel<<<dim3(TT), dim3(256), 0, stream>>>(pairout, inv, y);
}